// Round 17
// baseline (1832.103 us; speedup 1.0000x reference)
//
#include <hip/hip_runtime.h>
#include <hip/hip_bf16.h>
#include <math.h>

// LIFGatedRouter: out = (gate * silu(x@Wu^T)) @ Wd^T
// R17: gate GEMM thread tile 8x4 -> 8x8 (128x128 block tile) to halve LDS
// bytes per FMA (was LDS-BW-bound at 69% VALU). Staging via global_load_lds
// from pre-transposed xT/WgT (R16). Per-element gate DAG BIT-EXACT
// (ascending fmaf chain, __fadd_rn fold at k=128,...,896 — R13-verified).
// Scan numpy-ufunc unchanged. up/down split-bf16 MFMA unchanged.

namespace {

constexpr int B_ = 4;
constexpr int T_ = 2048;
constexpr int D_ = 1024;
constexpr int F_ = 4096;
constexpr int TC = 512;
constexpr int NCHUNK = T_ / TC;      // 4
constexpr int MC = B_ * TC;          // 2048 chunk-local rows
constexpr int LDK = 40;              // MFMA LDS row stride (bf16), 32+8 pad

typedef __attribute__((ext_vector_type(8))) short bf16x8;
typedef __attribute__((ext_vector_type(4))) float f32x4;

__device__ __forceinline__ float silu_f(float u) {
  return u / (1.0f + expf(-u));
}

__device__ __forceinline__ int map_row(int r, int t0) {
  return (r >> 9) * T_ + t0 + (r & (TC - 1));   // TC == 512
}

__device__ __forceinline__ unsigned short bf16_rn(float x) {
  unsigned int u = __float_as_uint(x);
  u += 0x7FFF + ((u >> 16) & 1);
  return (unsigned short)(u >> 16);
}
__device__ __forceinline__ float bf16_f(unsigned short h) {
  unsigned int u = ((unsigned int)h) << 16;
  return __uint_as_float(u);
}

// async global(per-lane addr) -> LDS(wave-uniform base + lane*16)
__device__ __forceinline__ void async_copy16(const float* g, float* l) {
  __builtin_amdgcn_global_load_lds(
      (const __attribute__((address_space(1))) void*)g,
      (__attribute__((address_space(3))) void*)l, 16, 0, 0);
}

// ---------------------------------------------------------------------------
// transpose kernels (pure copies — fp-neutral)
// ---------------------------------------------------------------------------
__global__ __launch_bounds__(256)
void transpose_wg(const float* __restrict__ Wg, float* __restrict__ WgT) {
  __shared__ float tile[32][33];
  const int tx = threadIdx.x & 31, ty = threadIdx.x >> 5;  // 32x8
  const int d0 = blockIdx.x * 32, f0 = blockIdx.y * 32;
#pragma unroll
  for (int i = 0; i < 4; ++i)
    tile[ty + i * 8][tx] = Wg[(size_t)(f0 + ty + i * 8) * D_ + d0 + tx];
  __syncthreads();
#pragma unroll
  for (int i = 0; i < 4; ++i)
    WgT[(size_t)(d0 + ty + i * 8) * F_ + f0 + tx] = tile[tx][ty + i * 8];
}

__global__ __launch_bounds__(256)
void transpose_x(const float* __restrict__ x, float* __restrict__ xT, int t0) {
  __shared__ float tile[32][33];
  const int tx = threadIdx.x & 31, ty = threadIdx.x >> 5;  // 32x8
  const int d0 = blockIdx.x * 32, r0 = blockIdx.y * 32;
#pragma unroll
  for (int i = 0; i < 4; ++i)
    tile[ty + i * 8][tx] =
        x[(size_t)map_row(r0 + ty + i * 8, t0) * D_ + d0 + tx];
  __syncthreads();
#pragma unroll
  for (int i = 0; i < 4; ++i)
    xT[(size_t)(d0 + ty + i * 8) * MC + r0 + tx] = tile[tx][ty + i * 8];
}

// ---------------------------------------------------------------------------
// K1: gate GEMM — bit-exact DAG; 128x128 tile, 8x8/thread, BK=32,
// global_load_lds staging, linear LDS.
// G[r,c] = chain(xT[:,r], WgT[:,c]): ascending-k fmaf, fold every 128.
// Thread cols: {tx*4..+3} and {64+tx*4..+3} (16B-stride b-reads: 2-way=free).
// ---------------------------------------------------------------------------
#pragma clang fp contract(off)
__global__ __launch_bounds__(256)
void gemm_gate_np(const float* __restrict__ xT, const float* __restrict__ WgT,
                  float* __restrict__ G) {
  __shared__ float As[32 * 128];
  __shared__ float Bs[32 * 128];
  const int tid = threadIdx.x;
  const int lane = tid & 63;
  const int w = tid >> 6;          // wave id
  const int tx = tid & 15;         // N quads
  const int ty = tid >> 4;         // M: 16*8 = 128
  const int row0 = blockIdx.y * 128;
  const int col0 = blockIdx.x * 128;

  const int lr = (lane & 31) * 4;  // f32 col within a 128-wide k-row
  const int lh = lane >> 5;        // which k-row within a 1KB issue

  float acc[8][8];
  float csum[8][8];
#pragma unroll
  for (int i = 0; i < 8; ++i)
#pragma unroll
    for (int j = 0; j < 8; ++j) { acc[i][j] = 0.0f; csum[i][j] = 0.0f; }

  for (int kb = 0; kb < 8; ++kb) {        // 8 fold-blocks of 128 k
    if (kb != 0) {                        // fold at k = 128,256,...,896
#pragma unroll
      for (int i = 0; i < 8; ++i)
#pragma unroll
        for (int j = 0; j < 8; ++j) {
          csum[i][j] = __fadd_rn(csum[i][j], acc[i][j]);
          acc[i][j] = 0.0f;
        }
    }
    for (int sub = 0; sub < 4; ++sub) {   // 4 K-tiles of 32 per fold-block
      const int kt = kb * 128 + sub * 32;
      __syncthreads();
#pragma unroll
      for (int t = 0; t < 4; ++t) {
        const int ii = w * 4 + t;         // 0..15: covers k-rows 2ii, 2ii+1
        const int kr = kt + ii * 2 + lh;
        async_copy16(&xT[(size_t)kr * MC + row0 + lr], &As[ii * 256]);
        async_copy16(&WgT[(size_t)kr * F_ + col0 + lr], &Bs[ii * 256]);
      }
      __syncthreads();   // drains vmcnt — tiles ready
#pragma unroll
      for (int kk = 0; kk < 32; ++kk) {   // ascending k
        const float4 a0 = *reinterpret_cast<const float4*>(&As[kk * 128 + ty * 8]);
        const float4 a1 = *reinterpret_cast<const float4*>(&As[kk * 128 + ty * 8 + 4]);
        const float4 b0 = *reinterpret_cast<const float4*>(&Bs[kk * 128 + tx * 4]);
        const float4 b1 = *reinterpret_cast<const float4*>(&Bs[kk * 128 + tx * 4 + 64]);
        const float av[8] = {a0.x, a0.y, a0.z, a0.w, a1.x, a1.y, a1.z, a1.w};
        const float bv[8] = {b0.x, b0.y, b0.z, b0.w, b1.x, b1.y, b1.z, b1.w};
#pragma unroll
        for (int i = 0; i < 8; ++i)
#pragma unroll
          for (int j = 0; j < 8; ++j)
            acc[i][j] = __builtin_fmaf(av[i], bv[j], acc[i][j]);
      }
    }
  }

#pragma unroll
  for (int i = 0; i < 8; ++i) {
    const int r = row0 + ty * 8 + i;
    float4 v0, v1;
    v0.x = __fadd_rn(csum[i][0], acc[i][0]);
    v0.y = __fadd_rn(csum[i][1], acc[i][1]);
    v0.z = __fadd_rn(csum[i][2], acc[i][2]);
    v0.w = __fadd_rn(csum[i][3], acc[i][3]);
    v1.x = __fadd_rn(csum[i][4], acc[i][4]);
    v1.y = __fadd_rn(csum[i][5], acc[i][5]);
    v1.z = __fadd_rn(csum[i][6], acc[i][6]);
    v1.w = __fadd_rn(csum[i][7], acc[i][7]);
    *reinterpret_cast<float4*>(&G[(size_t)r * F_ + col0 + tx * 4]) = v0;
    *reinterpret_cast<float4*>(&G[(size_t)r * F_ + col0 + 64 + tx * 4]) = v1;
  }
}
#pragma clang fp contract(fast)

// ---------------------------------------------------------------------------
// K2: LIF scan — numpy f32 ufunc semantics (bit-exact), batched loads.
// ---------------------------------------------------------------------------
#pragma clang fp contract(off)
__global__ __launch_bounds__(64)
void lif_scan(const float* __restrict__ G, unsigned char* __restrict__ S8,
              float* __restrict__ state, const float* __restrict__ theta,
              int t0) {
  const int j = blockIdx.x * 64 + threadIdx.x;
  const int f = j & (F_ - 1);
  const int b = j >> 12;
  float m = (t0 == 0) ? 0.0f : state[j];
  const float th = theta[f];
  const size_t base = (size_t)b * TC * F_ + f;
  for (int tb = 0; tb < TC; tb += 16) {
    float g[16];
#pragma unroll
    for (int u = 0; u < 16; ++u) g[u] = G[base + (size_t)(tb + u) * F_];
#pragma unroll
    for (int u = 0; u < 16; ++u) {
      const float bm = __fmul_rn(0.8f, m);
      m = __fadd_rn(bm, g[u]);
      const float s = (m >= 1.0f) ? 1.0f : 0.0f;
      const float r = __fmul_rn(th, s);
      m = __fsub_rn(m, r);
      S8[base + (size_t)(tb + u) * F_] = (unsigned char)s;
    }
  }
  state[j] = m;
}
#pragma clang fp contract(fast)

// ---------------------------------------------------------------------------
// weight split: f32 -> (hi, lo) bf16
// ---------------------------------------------------------------------------
__global__ __launch_bounds__(256)
void split_f32(const float* __restrict__ src, unsigned short* __restrict__ hi,
               unsigned short* __restrict__ lo, int n4) {
  int i = blockIdx.x * 256 + threadIdx.x;
  const int stride = gridDim.x * 256;
  for (; i < n4; i += stride) {
    const float4 v = reinterpret_cast<const float4*>(src)[i];
    ushort4 h, l;
    h.x = bf16_rn(v.x); l.x = bf16_rn(v.x - bf16_f(h.x));
    h.y = bf16_rn(v.y); l.y = bf16_rn(v.y - bf16_f(h.y));
    h.z = bf16_rn(v.z); l.z = bf16_rn(v.z - bf16_f(h.z));
    h.w = bf16_rn(v.w); l.w = bf16_rn(v.w - bf16_f(h.w));
    reinterpret_cast<ushort4*>(hi)[i] = h;
    reinterpret_cast<ushort4*>(lo)[i] = l;
  }
}

// x chunk split with row mapping
__global__ __launch_bounds__(256)
void split_x(const float* __restrict__ x, unsigned short* __restrict__ Xh,
             unsigned short* __restrict__ Xl, int t0) {
  const int i = blockIdx.x * 256 + threadIdx.x;   // float4 index, MC*D/4
  const int r = i >> 8;                            // D/4 == 256
  const int q = i & 255;
  const float4 v = *reinterpret_cast<const float4*>(
      &x[(size_t)map_row(r, t0) * D_ + q * 4]);
  ushort4 h, l;
  h.x = bf16_rn(v.x); l.x = bf16_rn(v.x - bf16_f(h.x));
  h.y = bf16_rn(v.y); l.y = bf16_rn(v.y - bf16_f(h.y));
  h.z = bf16_rn(v.z); l.z = bf16_rn(v.z - bf16_f(h.z));
  h.w = bf16_rn(v.w); l.w = bf16_rn(v.w - bf16_f(h.w));
  *reinterpret_cast<ushort4*>(&Xh[(size_t)r * D_ + q * 4]) = h;
  *reinterpret_cast<ushort4*>(&Xl[(size_t)r * D_ + q * 4]) = l;
}

// ---------------------------------------------------------------------------
// K3: up = x @ Wu^T via split-bf16 MFMA; epilogue h = spike*silu(up) -> hi/lo.
// ---------------------------------------------------------------------------
__global__ __launch_bounds__(256)
void up_mfma(const unsigned short* __restrict__ Xh,
             const unsigned short* __restrict__ Xl,
             const unsigned short* __restrict__ Wh,
             const unsigned short* __restrict__ Wl,
             const unsigned char* __restrict__ S8,
             unsigned short* __restrict__ Hh, unsigned short* __restrict__ Hl) {
  __shared__ unsigned short Ah[128 * LDK], Al[128 * LDK];
  __shared__ unsigned short Bh[128 * LDK], Bl[128 * LDK];
  const int tid = threadIdx.x;
  const int lane = tid & 63;
  const int w = tid >> 6;
  const int wr = (w >> 1) * 64;
  const int wc = (w & 1) * 64;
  const int brow = blockIdx.y * 128;
  const int bcol = blockIdx.x * 128;

  f32x4 acc[4][4];
#pragma unroll
  for (int i = 0; i < 4; ++i)
#pragma unroll
    for (int j = 0; j < 4; ++j) acc[i][j] = (f32x4)0.0f;

  for (int k0 = 0; k0 < D_; k0 += 32) {
    __syncthreads();
#pragma unroll
    for (int s = 0; s < 2; ++s) {
      const int v = tid + s * 256;
      const int row = v >> 2, q = v & 3;
      *reinterpret_cast<uint4*>(&Ah[row * LDK + q * 8]) =
          *reinterpret_cast<const uint4*>(
              &Xh[(size_t)(brow + row) * D_ + k0 + q * 8]);
      *reinterpret_cast<uint4*>(&Al[row * LDK + q * 8]) =
          *reinterpret_cast<const uint4*>(
              &Xl[(size_t)(brow + row) * D_ + k0 + q * 8]);
      *reinterpret_cast<uint4*>(&Bh[row * LDK + q * 8]) =
          *reinterpret_cast<const uint4*>(
              &Wh[(size_t)(bcol + row) * D_ + k0 + q * 8]);
      *reinterpret_cast<uint4*>(&Bl[row * LDK + q * 8]) =
          *reinterpret_cast<const uint4*>(
              &Wl[(size_t)(bcol + row) * D_ + k0 + q * 8]);
    }
    __syncthreads();
    const int fr = lane & 15;
    const int kq = (lane >> 4) * 8;
    bf16x8 ah[4], al[4], bh[4], bl[4];
#pragma unroll
    for (int i = 0; i < 4; ++i) {
      ah[i] = *reinterpret_cast<const bf16x8*>(&Ah[(wr + i * 16 + fr) * LDK + kq]);
      al[i] = *reinterpret_cast<const bf16x8*>(&Al[(wr + i * 16 + fr) * LDK + kq]);
      bh[i] = *reinterpret_cast<const bf16x8*>(&Bh[(wc + i * 16 + fr) * LDK + kq]);
      bl[i] = *reinterpret_cast<const bf16x8*>(&Bl[(wc + i * 16 + fr) * LDK + kq]);
    }
#pragma unroll
    for (int i = 0; i < 4; ++i)
#pragma unroll
      for (int j = 0; j < 4; ++j) {
        acc[i][j] = __builtin_amdgcn_mfma_f32_16x16x32_bf16(ah[i], bh[j], acc[i][j], 0, 0, 0);
        acc[i][j] = __builtin_amdgcn_mfma_f32_16x16x32_bf16(ah[i], bl[j], acc[i][j], 0, 0, 0);
        acc[i][j] = __builtin_amdgcn_mfma_f32_16x16x32_bf16(al[i], bh[j], acc[i][j], 0, 0, 0);
      }
  }

  const int fr = lane & 15;
  const int rg = (lane >> 4) * 4;
#pragma unroll
  for (int i = 0; i < 4; ++i)
#pragma unroll
    for (int j = 0; j < 4; ++j) {
      const int c = bcol + wc + j * 16 + fr;
#pragma unroll
      for (int r = 0; r < 4; ++r) {
        const int rl = brow + wr + i * 16 + rg + r;
        const float up = acc[i][j][r];
        const float h = S8[(size_t)rl * F_ + c] ? silu_f(up) : 0.0f;
        const unsigned short hh = bf16_rn(h);
        Hh[(size_t)rl * F_ + c] = hh;
        Hl[(size_t)rl * F_ + c] = bf16_rn(h - bf16_f(hh));
      }
    }
}

// ---------------------------------------------------------------------------
// K4: out = h @ Wd^T via split-bf16 MFMA. Tile 128x64, wave tile 64x32.
// ---------------------------------------------------------------------------
__global__ __launch_bounds__(256)
void down_mfma(const unsigned short* __restrict__ Hh,
               const unsigned short* __restrict__ Hl,
               const unsigned short* __restrict__ Wh,
               const unsigned short* __restrict__ Wl,
               float* __restrict__ out, int t0) {
  __shared__ unsigned short Ah[128 * LDK], Al[128 * LDK];
  __shared__ unsigned short Bh[64 * LDK], Bl[64 * LDK];
  const int tid = threadIdx.x;
  const int lane = tid & 63;
  const int w = tid >> 6;
  const int wr = (w >> 1) * 64;
  const int wc = (w & 1) * 32;
  const int brow = blockIdx.y * 128;
  const int bcol = blockIdx.x * 64;

  f32x4 acc[4][2];
#pragma unroll
  for (int i = 0; i < 4; ++i)
#pragma unroll
    for (int j = 0; j < 2; ++j) acc[i][j] = (f32x4)0.0f;

  for (int k0 = 0; k0 < F_; k0 += 32) {
    __syncthreads();
#pragma unroll
    for (int s = 0; s < 2; ++s) {
      const int v = tid + s * 256;
      const int row = v >> 2, q = v & 3;
      *reinterpret_cast<uint4*>(&Ah[row * LDK + q * 8]) =
          *reinterpret_cast<const uint4*>(
              &Hh[(size_t)(brow + row) * F_ + k0 + q * 8]);
      *reinterpret_cast<uint4*>(&Al[row * LDK + q * 8]) =
          *reinterpret_cast<const uint4*>(
              &Hl[(size_t)(brow + row) * F_ + k0 + q * 8]);
    }
    {
      const int row = tid >> 2, q = tid & 3;
      *reinterpret_cast<uint4*>(&Bh[row * LDK + q * 8]) =
          *reinterpret_cast<const uint4*>(
              &Wh[(size_t)(bcol + row) * F_ + k0 + q * 8]);
      *reinterpret_cast<uint4*>(&Bl[row * LDK + q * 8]) =
          *reinterpret_cast<const uint4*>(
              &Wl[(size_t)(bcol + row) * F_ + k0 + q * 8]);
    }
    __syncthreads();
    const int fr = lane & 15;
    const int kq = (lane >> 4) * 8;
    bf16x8 ah[4], al[4], bh[2], bl[2];
#pragma unroll
    for (int i = 0; i < 4; ++i) {
      ah[i] = *reinterpret_cast<const bf16x8*>(&Ah[(wr + i * 16 + fr) * LDK + kq]);
      al[i] = *reinterpret_cast<const bf16x8*>(&Al[(wr + i * 16 + fr) * LDK + kq]);
    }
#pragma unroll
    for (int j = 0; j < 2; ++j) {
      bh[j] = *reinterpret_cast<const bf16x8*>(&Bh[(wc + j * 16 + fr) * LDK + kq]);
      bl[j] = *reinterpret_cast<const bf16x8*>(&Bl[(wc + j * 16 + fr) * LDK + kq]);
    }
#pragma unroll
    for (int i = 0; i < 4; ++i)
#pragma unroll
      for (int j = 0; j < 2; ++j) {
        acc[i][j] = __builtin_amdgcn_mfma_f32_16x16x32_bf16(ah[i], bh[j], acc[i][j], 0, 0, 0);
        acc[i][j] = __builtin_amdgcn_mfma_f32_16x16x32_bf16(ah[i], bl[j], acc[i][j], 0, 0, 0);
        acc[i][j] = __builtin_amdgcn_mfma_f32_16x16x32_bf16(al[i], bh[j], acc[i][j], 0, 0, 0);
      }
  }

  const int fr = lane & 15;
  const int rg = (lane >> 4) * 4;
#pragma unroll
  for (int i = 0; i < 4; ++i)
#pragma unroll
    for (int j = 0; j < 2; ++j) {
      const int c = bcol + wc + j * 16 + fr;
#pragma unroll
      for (int r = 0; r < 4; ++r) {
        const int rl = brow + wr + i * 16 + rg + r;
        out[(size_t)map_row(rl, t0) * D_ + c] = acc[i][j][r];
      }
    }
}

}  // namespace

extern "C" void kernel_launch(void* const* d_in, const int* in_sizes, int n_in,
                              void* d_out, int out_size, void* d_ws,
                              size_t ws_size, hipStream_t stream) {
  const float* x = (const float*)d_in[0];
  const float* Wg = (const float*)d_in[1];
  const float* Wu = (const float*)d_in[2];
  const float* Wd = (const float*)d_in[3];
  const float* theta = (const float*)d_in[4];
  float* out = (float*)d_out;

  // ws layout (100.73 MB; R1 proved >= 100.79 MB available)
  char* ws = (char*)d_ws;
  const size_t wu_b = (size_t)F_ * D_ * 2;            // 8.39 MB
  unsigned short* Wu_hi = (unsigned short*)ws;
  unsigned short* Wu_lo = (unsigned short*)(ws + wu_b);
  unsigned short* Wd_hi = (unsigned short*)(ws + 2 * wu_b);
  unsigned short* Wd_lo = (unsigned short*)(ws + 3 * wu_b);
  float* WgT = (float*)(ws + 4 * wu_b);                        // 16.78 MB
  char* xbase = ws + 4 * wu_b + (size_t)F_ * D_ * 4;
  unsigned short* Xh = (unsigned short*)xbase;                 // 4.19 MB
  unsigned short* Xl = (unsigned short*)(xbase + (size_t)MC * D_ * 2);
  char* gbase = xbase + (size_t)MC * D_ * 4;
  float* G = (float*)gbase;                                    // 33.55 MB
  unsigned short* Hh = (unsigned short*)gbase;                 // overlays G
  unsigned short* Hl = (unsigned short*)(gbase + (size_t)MC * F_ * 2);
  char* s8xt = gbase + (size_t)MC * F_ * 4;                    // 8.39 MB shared
  float* xT = (float*)s8xt;          // alive: transpose_x -> gate
  unsigned char* S8 = (unsigned char*)s8xt;  // alive: scan -> up (disjoint)
  float* state = (float*)(s8xt + (size_t)MC * D_ * 4);         // 64 KB

  const dim3 blk(256);
  hipLaunchKernelGGL(split_f32, dim3(1024), blk, 0, stream, Wu, Wu_hi, Wu_lo,
                     F_ * D_ / 4);
  hipLaunchKernelGGL(split_f32, dim3(1024), blk, 0, stream, Wd, Wd_hi, Wd_lo,
                     D_ * F_ / 4);
  hipLaunchKernelGGL(transpose_wg, dim3(D_ / 32, F_ / 32), blk, 0, stream,
                     Wg, WgT);

  const dim3 g_tx(D_ / 32, MC / 32);     // (32, 64)
  const dim3 g_gt(F_ / 128, MC / 128);   // (32, 16) -> 512 blocks
  const dim3 g_sc(B_ * F_ / 64);         // 256 blocks x 64
  const dim3 g_sx(MC * D_ / 4 / 256);    // 2048 blocks
  const dim3 g_up(F_ / 128, MC / 128);   // (32, 16)
  const dim3 g_dn(D_ / 64, MC / 128);    // (16, 16)

  for (int c = 0; c < NCHUNK; ++c) {
    const int t0 = c * TC;
    hipLaunchKernelGGL(transpose_x, g_tx, blk, 0, stream, x, xT, t0);
    hipLaunchKernelGGL(split_x, g_sx, blk, 0, stream, x, Xh, Xl, t0);
    hipLaunchKernelGGL(gemm_gate_np, g_gt, blk, 0, stream, xT, WgT, G);
    hipLaunchKernelGGL(lif_scan, g_sc, dim3(64), 0, stream, G, S8, state,
                       theta, t0);
    hipLaunchKernelGGL(up_mfma, g_up, blk, 0, stream, Xh, Xl, Wu_hi, Wu_lo,
                       S8, Hh, Hl);
    hipLaunchKernelGGL(down_mfma, g_dn, blk, 0, stream, Hh, Hl, Wd_hi, Wd_lo,
                       out, t0);
  }
}

// Round 18
// 1804.050 us; speedup vs baseline: 1.0155x; 1.0155x over previous
//
#include <hip/hip_runtime.h>
#include <hip/hip_bf16.h>
#include <math.h>

// LIFGatedRouter: out = (gate * silu(x@Wu^T)) @ Wd^T
// R18: gate = R16 structure (128x64 tile, 8x4/thread, BK=32, global_load_lds)
// + DOUBLE-BUFFERED LDS: prefetch tile t+1 during compute of tile t, single
// barrier per tile (hides staging latency that R16 exposed every tile).
// Per-element gate DAG BIT-EXACT (ascending fmaf chain, __fadd_rn fold at
// k=128,...,896 — R13-verified). Scan numpy-ufunc unchanged. up/down
// split-bf16 MFMA unchanged from R16.

namespace {

constexpr int B_ = 4;
constexpr int T_ = 2048;
constexpr int D_ = 1024;
constexpr int F_ = 4096;
constexpr int TC = 512;
constexpr int NCHUNK = T_ / TC;      // 4
constexpr int MC = B_ * TC;          // 2048 chunk-local rows
constexpr int LDK = 40;              // MFMA LDS row stride (bf16), 32+8 pad

typedef __attribute__((ext_vector_type(8))) short bf16x8;
typedef __attribute__((ext_vector_type(4))) float f32x4;

__device__ __forceinline__ float silu_f(float u) {
  return u / (1.0f + expf(-u));
}

__device__ __forceinline__ int map_row(int r, int t0) {
  return (r >> 9) * T_ + t0 + (r & (TC - 1));   // TC == 512
}

__device__ __forceinline__ unsigned short bf16_rn(float x) {
  unsigned int u = __float_as_uint(x);
  u += 0x7FFF + ((u >> 16) & 1);
  return (unsigned short)(u >> 16);
}
__device__ __forceinline__ float bf16_f(unsigned short h) {
  unsigned int u = ((unsigned int)h) << 16;
  return __uint_as_float(u);
}

// async global(per-lane addr) -> LDS(wave-uniform base + lane*16)
__device__ __forceinline__ void async_copy16(const float* g, float* l) {
  __builtin_amdgcn_global_load_lds(
      (const __attribute__((address_space(1))) void*)g,
      (__attribute__((address_space(3))) void*)l, 16, 0, 0);
}

// ---------------------------------------------------------------------------
// transpose kernels (pure copies — fp-neutral)
// ---------------------------------------------------------------------------
__global__ __launch_bounds__(256)
void transpose_wg(const float* __restrict__ Wg, float* __restrict__ WgT) {
  __shared__ float tile[32][33];
  const int tx = threadIdx.x & 31, ty = threadIdx.x >> 5;  // 32x8
  const int d0 = blockIdx.x * 32, f0 = blockIdx.y * 32;
#pragma unroll
  for (int i = 0; i < 4; ++i)
    tile[ty + i * 8][tx] = Wg[(size_t)(f0 + ty + i * 8) * D_ + d0 + tx];
  __syncthreads();
#pragma unroll
  for (int i = 0; i < 4; ++i)
    WgT[(size_t)(d0 + ty + i * 8) * F_ + f0 + tx] = tile[tx][ty + i * 8];
}

__global__ __launch_bounds__(256)
void transpose_x(const float* __restrict__ x, float* __restrict__ xT, int t0) {
  __shared__ float tile[32][33];
  const int tx = threadIdx.x & 31, ty = threadIdx.x >> 5;  // 32x8
  const int d0 = blockIdx.x * 32, r0 = blockIdx.y * 32;
#pragma unroll
  for (int i = 0; i < 4; ++i)
    tile[ty + i * 8][tx] =
        x[(size_t)map_row(r0 + ty + i * 8, t0) * D_ + d0 + tx];
  __syncthreads();
#pragma unroll
  for (int i = 0; i < 4; ++i)
    xT[(size_t)(d0 + ty + i * 8) * MC + r0 + tx] = tile[tx][ty + i * 8];
}

// ---------------------------------------------------------------------------
// K1: gate GEMM — bit-exact DAG; 128x64 tile, 8x4/thread, BK=32,
// double-buffered global_load_lds staging, one barrier per tile.
// G[r,c] = chain(xT[:,r], WgT[:,c]): ascending-k fmaf, fold every 128.
// ---------------------------------------------------------------------------
#pragma clang fp contract(off)
__global__ __launch_bounds__(256)
void gemm_gate_np(const float* __restrict__ xT, const float* __restrict__ WgT,
                  float* __restrict__ G) {
  __shared__ float As[2][32 * 128];
  __shared__ float Bs[2][32 * 64];
  const int tid = threadIdx.x;
  const int lane = tid & 63;
  const int w = tid >> 6;          // wave id (uniform per wave)
  const int tx = tid & 15;         // N: 16*4 = 64
  const int ty = tid >> 4;         // M: 16*8 = 128
  const int row0 = blockIdx.y * 128;
  const int col0 = blockIdx.x * 64;

  float acc[8][4];
  float csum[8][4];
#pragma unroll
  for (int i = 0; i < 8; ++i)
#pragma unroll
    for (int j = 0; j < 4; ++j) { acc[i][j] = 0.0f; csum[i][j] = 0.0f; }

  // stage tile `kt32` (k-offset kt32*32) into buffer `buf`
  auto stage = [&](int kt32, int buf) {
    const int kt = kt32 * 32;
    // A tile: 32 k-rows x 128 f32 -> 4 wave-issues/wave (1KB each)
#pragma unroll
    for (int t = 0; t < 4; ++t) {
      const int ii = w * 4 + t;                   // 0..15
      const int kr = kt + ii * 2 + (lane >> 5);   // 2 k-rows per issue
      async_copy16(&xT[(size_t)kr * MC + row0 + (lane & 31) * 4],
                   &As[buf][ii * 256]);
    }
    // B tile: 32 k-rows x 64 f32 -> 2 wave-issues/wave
#pragma unroll
    for (int t = 0; t < 2; ++t) {
      const int ii = w * 2 + t;                   // 0..7
      const int kr = kt + ii * 4 + (lane >> 4);   // 4 k-rows per issue
      async_copy16(&WgT[(size_t)kr * F_ + col0 + (lane & 15) * 4],
                   &Bs[buf][ii * 256]);
    }
  };

  stage(0, 0);
  __syncthreads();   // drain prologue loads
  int cur = 0;

  for (int kt32 = 0; kt32 < 32; ++kt32) {
    if (kt32 != 0 && (kt32 & 3) == 0) {   // fold at k = 128,256,...,896
#pragma unroll
      for (int i = 0; i < 8; ++i)
#pragma unroll
        for (int j = 0; j < 4; ++j) {
          csum[i][j] = __fadd_rn(csum[i][j], acc[i][j]);
          acc[i][j] = 0.0f;
        }
    }
    if (kt32 + 1 < 32) stage(kt32 + 1, cur ^ 1);   // prefetch next tile
#pragma unroll
    for (int kk = 0; kk < 32; ++kk) {   // ascending k
      const float4 a0 = *reinterpret_cast<const float4*>(&As[cur][kk * 128 + ty * 8]);
      const float4 a1 = *reinterpret_cast<const float4*>(&As[cur][kk * 128 + ty * 8 + 4]);
      const float4 b0 = *reinterpret_cast<const float4*>(&Bs[cur][kk * 64 + tx * 4]);
      const float av[8] = {a0.x, a0.y, a0.z, a0.w, a1.x, a1.y, a1.z, a1.w};
      const float bv[4] = {b0.x, b0.y, b0.z, b0.w};
#pragma unroll
      for (int i = 0; i < 8; ++i)
#pragma unroll
        for (int j = 0; j < 4; ++j)
          acc[i][j] = __builtin_fmaf(av[i], bv[j], acc[i][j]);
    }
    __syncthreads();   // next-tile loads done; previous buffer reusable
    cur ^= 1;
  }

#pragma unroll
  for (int i = 0; i < 8; ++i) {
    const int r = row0 + ty * 8 + i;
    float4 v;
    v.x = __fadd_rn(csum[i][0], acc[i][0]);
    v.y = __fadd_rn(csum[i][1], acc[i][1]);
    v.z = __fadd_rn(csum[i][2], acc[i][2]);
    v.w = __fadd_rn(csum[i][3], acc[i][3]);
    *reinterpret_cast<float4*>(&G[(size_t)r * F_ + col0 + tx * 4]) = v;
  }
}
#pragma clang fp contract(fast)

// ---------------------------------------------------------------------------
// K2: LIF scan — numpy f32 ufunc semantics (bit-exact), batched loads.
// ---------------------------------------------------------------------------
#pragma clang fp contract(off)
__global__ __launch_bounds__(64)
void lif_scan(const float* __restrict__ G, unsigned char* __restrict__ S8,
              float* __restrict__ state, const float* __restrict__ theta,
              int t0) {
  const int j = blockIdx.x * 64 + threadIdx.x;
  const int f = j & (F_ - 1);
  const int b = j >> 12;
  float m = (t0 == 0) ? 0.0f : state[j];
  const float th = theta[f];
  const size_t base = (size_t)b * TC * F_ + f;
  for (int tb = 0; tb < TC; tb += 16) {
    float g[16];
#pragma unroll
    for (int u = 0; u < 16; ++u) g[u] = G[base + (size_t)(tb + u) * F_];
#pragma unroll
    for (int u = 0; u < 16; ++u) {
      const float bm = __fmul_rn(0.8f, m);
      m = __fadd_rn(bm, g[u]);
      const float s = (m >= 1.0f) ? 1.0f : 0.0f;
      const float r = __fmul_rn(th, s);
      m = __fsub_rn(m, r);
      S8[base + (size_t)(tb + u) * F_] = (unsigned char)s;
    }
  }
  state[j] = m;
}
#pragma clang fp contract(fast)

// ---------------------------------------------------------------------------
// weight split: f32 -> (hi, lo) bf16
// ---------------------------------------------------------------------------
__global__ __launch_bounds__(256)
void split_f32(const float* __restrict__ src, unsigned short* __restrict__ hi,
               unsigned short* __restrict__ lo, int n4) {
  int i = blockIdx.x * 256 + threadIdx.x;
  const int stride = gridDim.x * 256;
  for (; i < n4; i += stride) {
    const float4 v = reinterpret_cast<const float4*>(src)[i];
    ushort4 h, l;
    h.x = bf16_rn(v.x); l.x = bf16_rn(v.x - bf16_f(h.x));
    h.y = bf16_rn(v.y); l.y = bf16_rn(v.y - bf16_f(h.y));
    h.z = bf16_rn(v.z); l.z = bf16_rn(v.z - bf16_f(h.z));
    h.w = bf16_rn(v.w); l.w = bf16_rn(v.w - bf16_f(h.w));
    reinterpret_cast<ushort4*>(hi)[i] = h;
    reinterpret_cast<ushort4*>(lo)[i] = l;
  }
}

// x chunk split with row mapping
__global__ __launch_bounds__(256)
void split_x(const float* __restrict__ x, unsigned short* __restrict__ Xh,
             unsigned short* __restrict__ Xl, int t0) {
  const int i = blockIdx.x * 256 + threadIdx.x;   // float4 index, MC*D/4
  const int r = i >> 8;                            // D/4 == 256
  const int q = i & 255;
  const float4 v = *reinterpret_cast<const float4*>(
      &x[(size_t)map_row(r, t0) * D_ + q * 4]);
  ushort4 h, l;
  h.x = bf16_rn(v.x); l.x = bf16_rn(v.x - bf16_f(h.x));
  h.y = bf16_rn(v.y); l.y = bf16_rn(v.y - bf16_f(h.y));
  h.z = bf16_rn(v.z); l.z = bf16_rn(v.z - bf16_f(h.z));
  h.w = bf16_rn(v.w); l.w = bf16_rn(v.w - bf16_f(h.w));
  *reinterpret_cast<ushort4*>(&Xh[(size_t)r * D_ + q * 4]) = h;
  *reinterpret_cast<ushort4*>(&Xl[(size_t)r * D_ + q * 4]) = l;
}

// ---------------------------------------------------------------------------
// K3: up = x @ Wu^T via split-bf16 MFMA; epilogue h = spike*silu(up) -> hi/lo.
// ---------------------------------------------------------------------------
__global__ __launch_bounds__(256)
void up_mfma(const unsigned short* __restrict__ Xh,
             const unsigned short* __restrict__ Xl,
             const unsigned short* __restrict__ Wh,
             const unsigned short* __restrict__ Wl,
             const unsigned char* __restrict__ S8,
             unsigned short* __restrict__ Hh, unsigned short* __restrict__ Hl) {
  __shared__ unsigned short Ah[128 * LDK], Al[128 * LDK];
  __shared__ unsigned short Bh[128 * LDK], Bl[128 * LDK];
  const int tid = threadIdx.x;
  const int lane = tid & 63;
  const int w = tid >> 6;
  const int wr = (w >> 1) * 64;
  const int wc = (w & 1) * 64;
  const int brow = blockIdx.y * 128;
  const int bcol = blockIdx.x * 128;

  f32x4 acc[4][4];
#pragma unroll
  for (int i = 0; i < 4; ++i)
#pragma unroll
    for (int j = 0; j < 4; ++j) acc[i][j] = (f32x4)0.0f;

  for (int k0 = 0; k0 < D_; k0 += 32) {
    __syncthreads();
#pragma unroll
    for (int s = 0; s < 2; ++s) {
      const int v = tid + s * 256;
      const int row = v >> 2, q = v & 3;
      *reinterpret_cast<uint4*>(&Ah[row * LDK + q * 8]) =
          *reinterpret_cast<const uint4*>(
              &Xh[(size_t)(brow + row) * D_ + k0 + q * 8]);
      *reinterpret_cast<uint4*>(&Al[row * LDK + q * 8]) =
          *reinterpret_cast<const uint4*>(
              &Xl[(size_t)(brow + row) * D_ + k0 + q * 8]);
      *reinterpret_cast<uint4*>(&Bh[row * LDK + q * 8]) =
          *reinterpret_cast<const uint4*>(
              &Wh[(size_t)(bcol + row) * D_ + k0 + q * 8]);
      *reinterpret_cast<uint4*>(&Bl[row * LDK + q * 8]) =
          *reinterpret_cast<const uint4*>(
              &Wl[(size_t)(bcol + row) * D_ + k0 + q * 8]);
    }
    __syncthreads();
    const int fr = lane & 15;
    const int kq = (lane >> 4) * 8;
    bf16x8 ah[4], al[4], bh[4], bl[4];
#pragma unroll
    for (int i = 0; i < 4; ++i) {
      ah[i] = *reinterpret_cast<const bf16x8*>(&Ah[(wr + i * 16 + fr) * LDK + kq]);
      al[i] = *reinterpret_cast<const bf16x8*>(&Al[(wr + i * 16 + fr) * LDK + kq]);
      bh[i] = *reinterpret_cast<const bf16x8*>(&Bh[(wc + i * 16 + fr) * LDK + kq]);
      bl[i] = *reinterpret_cast<const bf16x8*>(&Bl[(wc + i * 16 + fr) * LDK + kq]);
    }
#pragma unroll
    for (int i = 0; i < 4; ++i)
#pragma unroll
      for (int j = 0; j < 4; ++j) {
        acc[i][j] = __builtin_amdgcn_mfma_f32_16x16x32_bf16(ah[i], bh[j], acc[i][j], 0, 0, 0);
        acc[i][j] = __builtin_amdgcn_mfma_f32_16x16x32_bf16(ah[i], bl[j], acc[i][j], 0, 0, 0);
        acc[i][j] = __builtin_amdgcn_mfma_f32_16x16x32_bf16(al[i], bh[j], acc[i][j], 0, 0, 0);
      }
  }

  const int fr = lane & 15;
  const int rg = (lane >> 4) * 4;
#pragma unroll
  for (int i = 0; i < 4; ++i)
#pragma unroll
    for (int j = 0; j < 4; ++j) {
      const int c = bcol + wc + j * 16 + fr;
#pragma unroll
      for (int r = 0; r < 4; ++r) {
        const int rl = brow + wr + i * 16 + rg + r;
        const float up = acc[i][j][r];
        const float h = S8[(size_t)rl * F_ + c] ? silu_f(up) : 0.0f;
        const unsigned short hh = bf16_rn(h);
        Hh[(size_t)rl * F_ + c] = hh;
        Hl[(size_t)rl * F_ + c] = bf16_rn(h - bf16_f(hh));
      }
    }
}

// ---------------------------------------------------------------------------
// K4: out = h @ Wd^T via split-bf16 MFMA. Tile 128x64, wave tile 64x32.
// ---------------------------------------------------------------------------
__global__ __launch_bounds__(256)
void down_mfma(const unsigned short* __restrict__ Hh,
               const unsigned short* __restrict__ Hl,
               const unsigned short* __restrict__ Wh,
               const unsigned short* __restrict__ Wl,
               float* __restrict__ out, int t0) {
  __shared__ unsigned short Ah[128 * LDK], Al[128 * LDK];
  __shared__ unsigned short Bh[64 * LDK], Bl[64 * LDK];
  const int tid = threadIdx.x;
  const int lane = tid & 63;
  const int w = tid >> 6;
  const int wr = (w >> 1) * 64;
  const int wc = (w & 1) * 32;
  const int brow = blockIdx.y * 128;
  const int bcol = blockIdx.x * 64;

  f32x4 acc[4][2];
#pragma unroll
  for (int i = 0; i < 4; ++i)
#pragma unroll
    for (int j = 0; j < 2; ++j) acc[i][j] = (f32x4)0.0f;

  for (int k0 = 0; k0 < F_; k0 += 32) {
    __syncthreads();
#pragma unroll
    for (int s = 0; s < 2; ++s) {
      const int v = tid + s * 256;
      const int row = v >> 2, q = v & 3;
      *reinterpret_cast<uint4*>(&Ah[row * LDK + q * 8]) =
          *reinterpret_cast<const uint4*>(
              &Hh[(size_t)(brow + row) * F_ + k0 + q * 8]);
      *reinterpret_cast<uint4*>(&Al[row * LDK + q * 8]) =
          *reinterpret_cast<const uint4*>(
              &Hl[(size_t)(brow + row) * F_ + k0 + q * 8]);
    }
    {
      const int row = tid >> 2, q = tid & 3;
      *reinterpret_cast<uint4*>(&Bh[row * LDK + q * 8]) =
          *reinterpret_cast<const uint4*>(
              &Wh[(size_t)(bcol + row) * F_ + k0 + q * 8]);
      *reinterpret_cast<uint4*>(&Bl[row * LDK + q * 8]) =
          *reinterpret_cast<const uint4*>(
              &Wl[(size_t)(bcol + row) * F_ + k0 + q * 8]);
    }
    __syncthreads();
    const int fr = lane & 15;
    const int kq = (lane >> 4) * 8;
    bf16x8 ah[4], al[4], bh[2], bl[2];
#pragma unroll
    for (int i = 0; i < 4; ++i) {
      ah[i] = *reinterpret_cast<const bf16x8*>(&Ah[(wr + i * 16 + fr) * LDK + kq]);
      al[i] = *reinterpret_cast<const bf16x8*>(&Al[(wr + i * 16 + fr) * LDK + kq]);
    }
#pragma unroll
    for (int j = 0; j < 2; ++j) {
      bh[j] = *reinterpret_cast<const bf16x8*>(&Bh[(wc + j * 16 + fr) * LDK + kq]);
      bl[j] = *reinterpret_cast<const bf16x8*>(&Bl[(wc + j * 16 + fr) * LDK + kq]);
    }
#pragma unroll
    for (int i = 0; i < 4; ++i)
#pragma unroll
      for (int j = 0; j < 2; ++j) {
        acc[i][j] = __builtin_amdgcn_mfma_f32_16x16x32_bf16(ah[i], bh[j], acc[i][j], 0, 0, 0);
        acc[i][j] = __builtin_amdgcn_mfma_f32_16x16x32_bf16(ah[i], bl[j], acc[i][j], 0, 0, 0);
        acc[i][j] = __builtin_amdgcn_mfma_f32_16x16x32_bf16(al[i], bh[j], acc[i][j], 0, 0, 0);
      }
  }

  const int fr = lane & 15;
  const int rg = (lane >> 4) * 4;
#pragma unroll
  for (int i = 0; i < 4; ++i)
#pragma unroll
    for (int j = 0; j < 2; ++j) {
      const int c = bcol + wc + j * 16 + fr;
#pragma unroll
      for (int r = 0; r < 4; ++r) {
        const int rl = brow + wr + i * 16 + rg + r;
        out[(size_t)map_row(rl, t0) * D_ + c] = acc[i][j][r];
      }
    }
}

}  // namespace

extern "C" void kernel_launch(void* const* d_in, const int* in_sizes, int n_in,
                              void* d_out, int out_size, void* d_ws,
                              size_t ws_size, hipStream_t stream) {
  const float* x = (const float*)d_in[0];
  const float* Wg = (const float*)d_in[1];
  const float* Wu = (const float*)d_in[2];
  const float* Wd = (const float*)d_in[3];
  const float* theta = (const float*)d_in[4];
  float* out = (float*)d_out;

  // ws layout (100.73 MB; R1 proved >= 100.79 MB available)
  char* ws = (char*)d_ws;
  const size_t wu_b = (size_t)F_ * D_ * 2;            // 8.39 MB
  unsigned short* Wu_hi = (unsigned short*)ws;
  unsigned short* Wu_lo = (unsigned short*)(ws + wu_b);
  unsigned short* Wd_hi = (unsigned short*)(ws + 2 * wu_b);
  unsigned short* Wd_lo = (unsigned short*)(ws + 3 * wu_b);
  float* WgT = (float*)(ws + 4 * wu_b);                        // 16.78 MB
  char* xbase = ws + 4 * wu_b + (size_t)F_ * D_ * 4;
  unsigned short* Xh = (unsigned short*)xbase;                 // 4.19 MB
  unsigned short* Xl = (unsigned short*)(xbase + (size_t)MC * D_ * 2);
  char* gbase = xbase + (size_t)MC * D_ * 4;
  float* G = (float*)gbase;                                    // 33.55 MB
  unsigned short* Hh = (unsigned short*)gbase;                 // overlays G
  unsigned short* Hl = (unsigned short*)(gbase + (size_t)MC * F_ * 2);
  char* s8xt = gbase + (size_t)MC * F_ * 4;                    // 8.39 MB shared
  float* xT = (float*)s8xt;          // alive: transpose_x -> gate
  unsigned char* S8 = (unsigned char*)s8xt;  // alive: scan -> up (disjoint)
  float* state = (float*)(s8xt + (size_t)MC * D_ * 4);         // 64 KB

  const dim3 blk(256);
  hipLaunchKernelGGL(split_f32, dim3(1024), blk, 0, stream, Wu, Wu_hi, Wu_lo,
                     F_ * D_ / 4);
  hipLaunchKernelGGL(split_f32, dim3(1024), blk, 0, stream, Wd, Wd_hi, Wd_lo,
                     D_ * F_ / 4);
  hipLaunchKernelGGL(transpose_wg, dim3(D_ / 32, F_ / 32), blk, 0, stream,
                     Wg, WgT);

  const dim3 g_tx(D_ / 32, MC / 32);     // (32, 64)
  const dim3 g_gt(F_ / 64, MC / 128);    // (64, 16) -> 1024 blocks
  const dim3 g_sc(B_ * F_ / 64);         // 256 blocks x 64
  const dim3 g_sx(MC * D_ / 4 / 256);    // 2048 blocks
  const dim3 g_up(F_ / 128, MC / 128);   // (32, 16)
  const dim3 g_dn(D_ / 64, MC / 128);    // (16, 16)

  for (int c = 0; c < NCHUNK; ++c) {
    const int t0 = c * TC;
    hipLaunchKernelGGL(transpose_x, g_tx, blk, 0, stream, x, xT, t0);
    hipLaunchKernelGGL(split_x, g_sx, blk, 0, stream, x, Xh, Xl, t0);
    hipLaunchKernelGGL(gemm_gate_np, g_gt, blk, 0, stream, xT, WgT, G);
    hipLaunchKernelGGL(lif_scan, g_sc, dim3(64), 0, stream, G, S8, state,
                       theta, t0);
    hipLaunchKernelGGL(up_mfma, g_up, blk, 0, stream, Xh, Xl, Wu_hi, Wu_lo,
                       S8, Hh, Hl);
    hipLaunchKernelGGL(down_mfma, g_dn, blk, 0, stream, Hh, Hl, Wd_hi, Wd_lo,
                       out, t0);
  }
}

// Round 19
// 1686.407 us; speedup vs baseline: 1.0864x; 1.0698x over previous
//
#include <hip/hip_runtime.h>
#include <hip/hip_bf16.h>
#include <math.h>

// LIFGatedRouter: out = (gate * silu(x@Wu^T)) @ Wd^T
// R19: gate = R16 structure (128x64 tile, 8x4/thread, BK=32, single-buffer
// global_load_lds staging) with the inner loop converted to v_pk_fma_f32
// (VOP3P packed: 2 IEEE FMAs/instr — bit-identical rounding to fmaf).
// Row-paired accumulators; B-scalar broadcast via op_sel (no dup movs).
// Per-element DAG BIT-EXACT (ascending-k fma chain, __fadd_rn fold at
// k=128,...,896 — R13-verified). Scan numpy-ufunc unchanged. up/down
// split-bf16 MFMA unchanged from R16.

namespace {

constexpr int B_ = 4;
constexpr int T_ = 2048;
constexpr int D_ = 1024;
constexpr int F_ = 4096;
constexpr int TC = 512;
constexpr int NCHUNK = T_ / TC;      // 4
constexpr int MC = B_ * TC;          // 2048 chunk-local rows
constexpr int LDK = 40;              // MFMA LDS row stride (bf16), 32+8 pad

typedef __attribute__((ext_vector_type(8))) short bf16x8;
typedef __attribute__((ext_vector_type(4))) float f32x4;
typedef __attribute__((ext_vector_type(2))) float f32x2;

// packed IEEE fma pair: acc.{lo,hi} += a.{lo,hi} * b.lo   (b lo-broadcast)
#define PK_FMA_LO(accv, av, bv)                                         \
  asm("v_pk_fma_f32 %0, %1, %2, %0 op_sel:[0,0,0] op_sel_hi:[1,0,1]"    \
      : "+v"(accv) : "v"(av), "v"(bv))
// packed IEEE fma pair: acc.{lo,hi} += a.{lo,hi} * b.hi   (b hi-broadcast)
#define PK_FMA_HI(accv, av, bv)                                         \
  asm("v_pk_fma_f32 %0, %1, %2, %0 op_sel:[0,1,0] op_sel_hi:[1,1,1]"    \
      : "+v"(accv) : "v"(av), "v"(bv))

__device__ __forceinline__ float silu_f(float u) {
  return u / (1.0f + expf(-u));
}

__device__ __forceinline__ int map_row(int r, int t0) {
  return (r >> 9) * T_ + t0 + (r & (TC - 1));   // TC == 512
}

__device__ __forceinline__ unsigned short bf16_rn(float x) {
  unsigned int u = __float_as_uint(x);
  u += 0x7FFF + ((u >> 16) & 1);
  return (unsigned short)(u >> 16);
}
__device__ __forceinline__ float bf16_f(unsigned short h) {
  unsigned int u = ((unsigned int)h) << 16;
  return __uint_as_float(u);
}

// async global(per-lane addr) -> LDS(wave-uniform base + lane*16)
__device__ __forceinline__ void async_copy16(const float* g, float* l) {
  __builtin_amdgcn_global_load_lds(
      (const __attribute__((address_space(1))) void*)g,
      (__attribute__((address_space(3))) void*)l, 16, 0, 0);
}

// ---------------------------------------------------------------------------
// transpose kernels (pure copies — fp-neutral)
// ---------------------------------------------------------------------------
__global__ __launch_bounds__(256)
void transpose_wg(const float* __restrict__ Wg, float* __restrict__ WgT) {
  __shared__ float tile[32][33];
  const int tx = threadIdx.x & 31, ty = threadIdx.x >> 5;  // 32x8
  const int d0 = blockIdx.x * 32, f0 = blockIdx.y * 32;
#pragma unroll
  for (int i = 0; i < 4; ++i)
    tile[ty + i * 8][tx] = Wg[(size_t)(f0 + ty + i * 8) * D_ + d0 + tx];
  __syncthreads();
#pragma unroll
  for (int i = 0; i < 4; ++i)
    WgT[(size_t)(d0 + ty + i * 8) * F_ + f0 + tx] = tile[tx][ty + i * 8];
}

__global__ __launch_bounds__(256)
void transpose_x(const float* __restrict__ x, float* __restrict__ xT, int t0) {
  __shared__ float tile[32][33];
  const int tx = threadIdx.x & 31, ty = threadIdx.x >> 5;  // 32x8
  const int d0 = blockIdx.x * 32, r0 = blockIdx.y * 32;
#pragma unroll
  for (int i = 0; i < 4; ++i)
    tile[ty + i * 8][tx] =
        x[(size_t)map_row(r0 + ty + i * 8, t0) * D_ + d0 + tx];
  __syncthreads();
#pragma unroll
  for (int i = 0; i < 4; ++i)
    xT[(size_t)(d0 + ty + i * 8) * MC + r0 + tx] = tile[tx][ty + i * 8];
}

// ---------------------------------------------------------------------------
// K1: gate GEMM — bit-exact DAG; 128x64 tile, 8x4/thread, BK=32,
// global_load_lds staging (R16 structure), v_pk_fma_f32 inner loop.
// G[r,c] = chain(xT[:,r], WgT[:,c]): ascending-k IEEE fma, fold every 128.
// accP[ip][j] = (acc[2ip][j], acc[2ip+1][j]) — row-paired.
// ---------------------------------------------------------------------------
#pragma clang fp contract(off)
__global__ __launch_bounds__(256)
void gemm_gate_np(const float* __restrict__ xT, const float* __restrict__ WgT,
                  float* __restrict__ G) {
  __shared__ float As[32 * 128];
  __shared__ float Bs[32 * 64];
  const int tid = threadIdx.x;
  const int lane = tid & 63;
  const int w = tid >> 6;          // wave id (uniform per wave)
  const int tx = tid & 15;         // N: 16*4 = 64
  const int ty = tid >> 4;         // M: 16*8 = 128
  const int row0 = blockIdx.y * 128;
  const int col0 = blockIdx.x * 64;

  f32x2 accP[4][4];   // [row-pair][col]
  f32x2 csumP[4][4];
#pragma unroll
  for (int i = 0; i < 4; ++i)
#pragma unroll
    for (int j = 0; j < 4; ++j) {
      accP[i][j] = (f32x2)0.0f;
      csumP[i][j] = (f32x2)0.0f;
    }

  for (int kt = 0; kt < D_; kt += 32) {
    if (kt != 0 && (kt & 127) == 0) {   // fold at k = 128,256,...,896
#pragma unroll
      for (int i = 0; i < 4; ++i)
#pragma unroll
        for (int j = 0; j < 4; ++j) {
          csumP[i][j].x = __fadd_rn(csumP[i][j].x, accP[i][j].x);
          csumP[i][j].y = __fadd_rn(csumP[i][j].y, accP[i][j].y);
          accP[i][j] = (f32x2)0.0f;
        }
    }
    __syncthreads();
    // A tile: 32 k-rows x 128 f32 = 16KB -> 4 wave-issues/wave (1KB each)
#pragma unroll
    for (int t = 0; t < 4; ++t) {
      const int ii = w * 4 + t;
      const int kr = kt + ii * 2 + (lane >> 5);
      async_copy16(&xT[(size_t)kr * MC + row0 + (lane & 31) * 4],
                   &As[ii * 256]);
    }
    // B tile: 32 k-rows x 64 f32 = 8KB -> 2 wave-issues/wave
#pragma unroll
    for (int t = 0; t < 2; ++t) {
      const int ii = w * 2 + t;
      const int kr = kt + ii * 4 + (lane >> 4);
      async_copy16(&WgT[(size_t)kr * F_ + col0 + (lane & 15) * 4],
                   &Bs[ii * 256]);
    }
    __syncthreads();   // drains vmcnt — tiles ready
#pragma unroll
    for (int kk = 0; kk < 32; ++kk) {   // ascending k
      const float4 a0 = *reinterpret_cast<const float4*>(&As[kk * 128 + ty * 8]);
      const float4 a1 = *reinterpret_cast<const float4*>(&As[kk * 128 + ty * 8 + 4]);
      const float4 b0 = *reinterpret_cast<const float4*>(&Bs[kk * 64 + tx * 4]);
      f32x2 ap[4];
      ap[0] = (f32x2){a0.x, a0.y};
      ap[1] = (f32x2){a0.z, a0.w};
      ap[2] = (f32x2){a1.x, a1.y};
      ap[3] = (f32x2){a1.z, a1.w};
      const f32x2 bp0 = (f32x2){b0.x, b0.y};
      const f32x2 bp1 = (f32x2){b0.z, b0.w};
#pragma unroll
      for (int ip = 0; ip < 4; ++ip) {
        PK_FMA_LO(accP[ip][0], ap[ip], bp0);   // col 0: b0.x
        PK_FMA_HI(accP[ip][1], ap[ip], bp0);   // col 1: b0.y
        PK_FMA_LO(accP[ip][2], ap[ip], bp1);   // col 2: b0.z
        PK_FMA_HI(accP[ip][3], ap[ip], bp1);   // col 3: b0.w
      }
    }
  }

#pragma unroll
  for (int ip = 0; ip < 4; ++ip) {
#pragma unroll
    for (int h = 0; h < 2; ++h) {
      const int r = row0 + ty * 8 + ip * 2 + h;
      float4 v;
      v.x = __fadd_rn(h ? csumP[ip][0].y : csumP[ip][0].x,
                      h ? accP[ip][0].y : accP[ip][0].x);
      v.y = __fadd_rn(h ? csumP[ip][1].y : csumP[ip][1].x,
                      h ? accP[ip][1].y : accP[ip][1].x);
      v.z = __fadd_rn(h ? csumP[ip][2].y : csumP[ip][2].x,
                      h ? accP[ip][2].y : accP[ip][2].x);
      v.w = __fadd_rn(h ? csumP[ip][3].y : csumP[ip][3].x,
                      h ? accP[ip][3].y : accP[ip][3].x);
      *reinterpret_cast<float4*>(&G[(size_t)r * F_ + col0 + tx * 4]) = v;
    }
  }
}
#pragma clang fp contract(fast)

// ---------------------------------------------------------------------------
// K2: LIF scan — numpy f32 ufunc semantics (bit-exact), batched loads.
// ---------------------------------------------------------------------------
#pragma clang fp contract(off)
__global__ __launch_bounds__(64)
void lif_scan(const float* __restrict__ G, unsigned char* __restrict__ S8,
              float* __restrict__ state, const float* __restrict__ theta,
              int t0) {
  const int j = blockIdx.x * 64 + threadIdx.x;
  const int f = j & (F_ - 1);
  const int b = j >> 12;
  float m = (t0 == 0) ? 0.0f : state[j];
  const float th = theta[f];
  const size_t base = (size_t)b * TC * F_ + f;
  for (int tb = 0; tb < TC; tb += 16) {
    float g[16];
#pragma unroll
    for (int u = 0; u < 16; ++u) g[u] = G[base + (size_t)(tb + u) * F_];
#pragma unroll
    for (int u = 0; u < 16; ++u) {
      const float bm = __fmul_rn(0.8f, m);
      m = __fadd_rn(bm, g[u]);
      const float s = (m >= 1.0f) ? 1.0f : 0.0f;
      const float r = __fmul_rn(th, s);
      m = __fsub_rn(m, r);
      S8[base + (size_t)(tb + u) * F_] = (unsigned char)s;
    }
  }
  state[j] = m;
}
#pragma clang fp contract(fast)

// ---------------------------------------------------------------------------
// weight split: f32 -> (hi, lo) bf16
// ---------------------------------------------------------------------------
__global__ __launch_bounds__(256)
void split_f32(const float* __restrict__ src, unsigned short* __restrict__ hi,
               unsigned short* __restrict__ lo, int n4) {
  int i = blockIdx.x * 256 + threadIdx.x;
  const int stride = gridDim.x * 256;
  for (; i < n4; i += stride) {
    const float4 v = reinterpret_cast<const float4*>(src)[i];
    ushort4 h, l;
    h.x = bf16_rn(v.x); l.x = bf16_rn(v.x - bf16_f(h.x));
    h.y = bf16_rn(v.y); l.y = bf16_rn(v.y - bf16_f(h.y));
    h.z = bf16_rn(v.z); l.z = bf16_rn(v.z - bf16_f(h.z));
    h.w = bf16_rn(v.w); l.w = bf16_rn(v.w - bf16_f(h.w));
    reinterpret_cast<ushort4*>(hi)[i] = h;
    reinterpret_cast<ushort4*>(lo)[i] = l;
  }
}

// x chunk split with row mapping
__global__ __launch_bounds__(256)
void split_x(const float* __restrict__ x, unsigned short* __restrict__ Xh,
             unsigned short* __restrict__ Xl, int t0) {
  const int i = blockIdx.x * 256 + threadIdx.x;   // float4 index, MC*D/4
  const int r = i >> 8;                            // D/4 == 256
  const int q = i & 255;
  const float4 v = *reinterpret_cast<const float4*>(
      &x[(size_t)map_row(r, t0) * D_ + q * 4]);
  ushort4 h, l;
  h.x = bf16_rn(v.x); l.x = bf16_rn(v.x - bf16_f(h.x));
  h.y = bf16_rn(v.y); l.y = bf16_rn(v.y - bf16_f(h.y));
  h.z = bf16_rn(v.z); l.z = bf16_rn(v.z - bf16_f(h.z));
  h.w = bf16_rn(v.w); l.w = bf16_rn(v.w - bf16_f(h.w));
  *reinterpret_cast<ushort4*>(&Xh[(size_t)r * D_ + q * 4]) = h;
  *reinterpret_cast<ushort4*>(&Xl[(size_t)r * D_ + q * 4]) = l;
}

// ---------------------------------------------------------------------------
// K3: up = x @ Wu^T via split-bf16 MFMA; epilogue h = spike*silu(up) -> hi/lo.
// ---------------------------------------------------------------------------
__global__ __launch_bounds__(256)
void up_mfma(const unsigned short* __restrict__ Xh,
             const unsigned short* __restrict__ Xl,
             const unsigned short* __restrict__ Wh,
             const unsigned short* __restrict__ Wl,
             const unsigned char* __restrict__ S8,
             unsigned short* __restrict__ Hh, unsigned short* __restrict__ Hl) {
  __shared__ unsigned short Ah[128 * LDK], Al[128 * LDK];
  __shared__ unsigned short Bh[128 * LDK], Bl[128 * LDK];
  const int tid = threadIdx.x;
  const int lane = tid & 63;
  const int w = tid >> 6;
  const int wr = (w >> 1) * 64;
  const int wc = (w & 1) * 64;
  const int brow = blockIdx.y * 128;
  const int bcol = blockIdx.x * 128;

  f32x4 acc[4][4];
#pragma unroll
  for (int i = 0; i < 4; ++i)
#pragma unroll
    for (int j = 0; j < 4; ++j) acc[i][j] = (f32x4)0.0f;

  for (int k0 = 0; k0 < D_; k0 += 32) {
    __syncthreads();
#pragma unroll
    for (int s = 0; s < 2; ++s) {
      const int v = tid + s * 256;
      const int row = v >> 2, q = v & 3;
      *reinterpret_cast<uint4*>(&Ah[row * LDK + q * 8]) =
          *reinterpret_cast<const uint4*>(
              &Xh[(size_t)(brow + row) * D_ + k0 + q * 8]);
      *reinterpret_cast<uint4*>(&Al[row * LDK + q * 8]) =
          *reinterpret_cast<const uint4*>(
              &Xl[(size_t)(brow + row) * D_ + k0 + q * 8]);
      *reinterpret_cast<uint4*>(&Bh[row * LDK + q * 8]) =
          *reinterpret_cast<const uint4*>(
              &Wh[(size_t)(bcol + row) * D_ + k0 + q * 8]);
      *reinterpret_cast<uint4*>(&Bl[row * LDK + q * 8]) =
          *reinterpret_cast<const uint4*>(
              &Wl[(size_t)(bcol + row) * D_ + k0 + q * 8]);
    }
    __syncthreads();
    const int fr = lane & 15;
    const int kq = (lane >> 4) * 8;
    bf16x8 ah[4], al[4], bh[4], bl[4];
#pragma unroll
    for (int i = 0; i < 4; ++i) {
      ah[i] = *reinterpret_cast<const bf16x8*>(&Ah[(wr + i * 16 + fr) * LDK + kq]);
      al[i] = *reinterpret_cast<const bf16x8*>(&Al[(wr + i * 16 + fr) * LDK + kq]);
      bh[i] = *reinterpret_cast<const bf16x8*>(&Bh[(wc + i * 16 + fr) * LDK + kq]);
      bl[i] = *reinterpret_cast<const bf16x8*>(&Bl[(wc + i * 16 + fr) * LDK + kq]);
    }
#pragma unroll
    for (int i = 0; i < 4; ++i)
#pragma unroll
      for (int j = 0; j < 4; ++j) {
        acc[i][j] = __builtin_amdgcn_mfma_f32_16x16x32_bf16(ah[i], bh[j], acc[i][j], 0, 0, 0);
        acc[i][j] = __builtin_amdgcn_mfma_f32_16x16x32_bf16(ah[i], bl[j], acc[i][j], 0, 0, 0);
        acc[i][j] = __builtin_amdgcn_mfma_f32_16x16x32_bf16(al[i], bh[j], acc[i][j], 0, 0, 0);
      }
  }

  const int fr = lane & 15;
  const int rg = (lane >> 4) * 4;
#pragma unroll
  for (int i = 0; i < 4; ++i)
#pragma unroll
    for (int j = 0; j < 4; ++j) {
      const int c = bcol + wc + j * 16 + fr;
#pragma unroll
      for (int r = 0; r < 4; ++r) {
        const int rl = brow + wr + i * 16 + rg + r;
        const float up = acc[i][j][r];
        const float h = S8[(size_t)rl * F_ + c] ? silu_f(up) : 0.0f;
        const unsigned short hh = bf16_rn(h);
        Hh[(size_t)rl * F_ + c] = hh;
        Hl[(size_t)rl * F_ + c] = bf16_rn(h - bf16_f(hh));
      }
    }
}

// ---------------------------------------------------------------------------
// K4: out = h @ Wd^T via split-bf16 MFMA. Tile 128x64, wave tile 64x32.
// ---------------------------------------------------------------------------
__global__ __launch_bounds__(256)
void down_mfma(const unsigned short* __restrict__ Hh,
               const unsigned short* __restrict__ Hl,
               const unsigned short* __restrict__ Wh,
               const unsigned short* __restrict__ Wl,
               float* __restrict__ out, int t0) {
  __shared__ unsigned short Ah[128 * LDK], Al[128 * LDK];
  __shared__ unsigned short Bh[64 * LDK], Bl[64 * LDK];
  const int tid = threadIdx.x;
  const int lane = tid & 63;
  const int w = tid >> 6;
  const int wr = (w >> 1) * 64;
  const int wc = (w & 1) * 32;
  const int brow = blockIdx.y * 128;
  const int bcol = blockIdx.x * 64;

  f32x4 acc[4][2];
#pragma unroll
  for (int i = 0; i < 4; ++i)
#pragma unroll
    for (int j = 0; j < 2; ++j) acc[i][j] = (f32x4)0.0f;

  for (int k0 = 0; k0 < F_; k0 += 32) {
    __syncthreads();
#pragma unroll
    for (int s = 0; s < 2; ++s) {
      const int v = tid + s * 256;
      const int row = v >> 2, q = v & 3;
      *reinterpret_cast<uint4*>(&Ah[row * LDK + q * 8]) =
          *reinterpret_cast<const uint4*>(
              &Hh[(size_t)(brow + row) * F_ + k0 + q * 8]);
      *reinterpret_cast<uint4*>(&Al[row * LDK + q * 8]) =
          *reinterpret_cast<const uint4*>(
              &Hl[(size_t)(brow + row) * F_ + k0 + q * 8]);
    }
    {
      const int row = tid >> 2, q = tid & 3;
      *reinterpret_cast<uint4*>(&Bh[row * LDK + q * 8]) =
          *reinterpret_cast<const uint4*>(
              &Wh[(size_t)(bcol + row) * F_ + k0 + q * 8]);
      *reinterpret_cast<uint4*>(&Bl[row * LDK + q * 8]) =
          *reinterpret_cast<const uint4*>(
              &Wl[(size_t)(bcol + row) * F_ + k0 + q * 8]);
    }
    __syncthreads();
    const int fr = lane & 15;
    const int kq = (lane >> 4) * 8;
    bf16x8 ah[4], al[4], bh[2], bl[2];
#pragma unroll
    for (int i = 0; i < 4; ++i) {
      ah[i] = *reinterpret_cast<const bf16x8*>(&Ah[(wr + i * 16 + fr) * LDK + kq]);
      al[i] = *reinterpret_cast<const bf16x8*>(&Al[(wr + i * 16 + fr) * LDK + kq]);
    }
#pragma unroll
    for (int j = 0; j < 2; ++j) {
      bh[j] = *reinterpret_cast<const bf16x8*>(&Bh[(wc + j * 16 + fr) * LDK + kq]);
      bl[j] = *reinterpret_cast<const bf16x8*>(&Bl[(wc + j * 16 + fr) * LDK + kq]);
    }
#pragma unroll
    for (int i = 0; i < 4; ++i)
#pragma unroll
      for (int j = 0; j < 2; ++j) {
        acc[i][j] = __builtin_amdgcn_mfma_f32_16x16x32_bf16(ah[i], bh[j], acc[i][j], 0, 0, 0);
        acc[i][j] = __builtin_amdgcn_mfma_f32_16x16x32_bf16(ah[i], bl[j], acc[i][j], 0, 0, 0);
        acc[i][j] = __builtin_amdgcn_mfma_f32_16x16x32_bf16(al[i], bh[j], acc[i][j], 0, 0, 0);
      }
  }

  const int fr = lane & 15;
  const int rg = (lane >> 4) * 4;
#pragma unroll
  for (int i = 0; i < 4; ++i)
#pragma unroll
    for (int j = 0; j < 2; ++j) {
      const int c = bcol + wc + j * 16 + fr;
#pragma unroll
      for (int r = 0; r < 4; ++r) {
        const int rl = brow + wr + i * 16 + rg + r;
        out[(size_t)map_row(rl, t0) * D_ + c] = acc[i][j][r];
      }
    }
}

}  // namespace

extern "C" void kernel_launch(void* const* d_in, const int* in_sizes, int n_in,
                              void* d_out, int out_size, void* d_ws,
                              size_t ws_size, hipStream_t stream) {
  const float* x = (const float*)d_in[0];
  const float* Wg = (const float*)d_in[1];
  const float* Wu = (const float*)d_in[2];
  const float* Wd = (const float*)d_in[3];
  const float* theta = (const float*)d_in[4];
  float* out = (float*)d_out;

  // ws layout (100.73 MB; R1 proved >= 100.79 MB available)
  char* ws = (char*)d_ws;
  const size_t wu_b = (size_t)F_ * D_ * 2;            // 8.39 MB
  unsigned short* Wu_hi = (unsigned short*)ws;
  unsigned short* Wu_lo = (unsigned short*)(ws + wu_b);
  unsigned short* Wd_hi = (unsigned short*)(ws + 2 * wu_b);
  unsigned short* Wd_lo = (unsigned short*)(ws + 3 * wu_b);
  float* WgT = (float*)(ws + 4 * wu_b);                        // 16.78 MB
  char* xbase = ws + 4 * wu_b + (size_t)F_ * D_ * 4;
  unsigned short* Xh = (unsigned short*)xbase;                 // 4.19 MB
  unsigned short* Xl = (unsigned short*)(xbase + (size_t)MC * D_ * 2);
  char* gbase = xbase + (size_t)MC * D_ * 4;
  float* G = (float*)gbase;                                    // 33.55 MB
  unsigned short* Hh = (unsigned short*)gbase;                 // overlays G
  unsigned short* Hl = (unsigned short*)(gbase + (size_t)MC * F_ * 2);
  char* s8xt = gbase + (size_t)MC * F_ * 4;                    // 8.39 MB shared
  float* xT = (float*)s8xt;          // alive: transpose_x -> gate
  unsigned char* S8 = (unsigned char*)s8xt;  // alive: scan -> up (disjoint)
  float* state = (float*)(s8xt + (size_t)MC * D_ * 4);         // 64 KB

  const dim3 blk(256);
  hipLaunchKernelGGL(split_f32, dim3(1024), blk, 0, stream, Wu, Wu_hi, Wu_lo,
                     F_ * D_ / 4);
  hipLaunchKernelGGL(split_f32, dim3(1024), blk, 0, stream, Wd, Wd_hi, Wd_lo,
                     D_ * F_ / 4);
  hipLaunchKernelGGL(transpose_wg, dim3(D_ / 32, F_ / 32), blk, 0, stream,
                     Wg, WgT);

  const dim3 g_tx(D_ / 32, MC / 32);     // (32, 64)
  const dim3 g_gt(F_ / 64, MC / 128);    // (64, 16) -> 1024 blocks
  const dim3 g_sc(B_ * F_ / 64);         // 256 blocks x 64
  const dim3 g_sx(MC * D_ / 4 / 256);    // 2048 blocks
  const dim3 g_up(F_ / 128, MC / 128);   // (32, 16)
  const dim3 g_dn(D_ / 64, MC / 128);    // (16, 16)

  for (int c = 0; c < NCHUNK; ++c) {
    const int t0 = c * TC;
    hipLaunchKernelGGL(transpose_x, g_tx, blk, 0, stream, x, xT, t0);
    hipLaunchKernelGGL(split_x, g_sx, blk, 0, stream, x, Xh, Xl, t0);
    hipLaunchKernelGGL(gemm_gate_np, g_gt, blk, 0, stream, xT, WgT, G);
    hipLaunchKernelGGL(lif_scan, g_sc, dim3(64), 0, stream, G, S8, state,
                       theta, t0);
    hipLaunchKernelGGL(up_mfma, g_up, blk, 0, stream, Xh, Xl, Wu_hi, Wu_lo,
                       S8, Hh, Hl);
    hipLaunchKernelGGL(down_mfma, g_dn, blk, 0, stream, Hh, Hl, Wd_hi, Wd_lo,
                       out, t0);
  }
}

// Round 20
// 1663.071 us; speedup vs baseline: 1.1016x; 1.0140x over previous
//
#include <hip/hip_runtime.h>
#include <hip/hip_bf16.h>
#include <math.h>

// LIFGatedRouter: out = (gate * silu(x@Wu^T)) @ Wd^T
// R20: gate block widened to 128x128 via 512 threads (8 waves), 8x4/thread,
// v_pk_fma_f32 inner loop (R19). Halves staged bytes/output and barriers
// per output; B-reads conflict-free. Per-element DAG BIT-EXACT (ascending-k
// IEEE fma chain, __fadd_rn fold at k=128,...,896 — R13-verified).
// Scan numpy-ufunc unchanged. up/down split-bf16 MFMA unchanged from R16.

namespace {

constexpr int B_ = 4;
constexpr int T_ = 2048;
constexpr int D_ = 1024;
constexpr int F_ = 4096;
constexpr int TC = 512;
constexpr int NCHUNK = T_ / TC;      // 4
constexpr int MC = B_ * TC;          // 2048 chunk-local rows
constexpr int LDK = 40;              // MFMA LDS row stride (bf16), 32+8 pad

typedef __attribute__((ext_vector_type(8))) short bf16x8;
typedef __attribute__((ext_vector_type(4))) float f32x4;
typedef __attribute__((ext_vector_type(2))) float f32x2;

// packed IEEE fma pair: acc.{lo,hi} += a.{lo,hi} * b.lo   (b lo-broadcast)
#define PK_FMA_LO(accv, av, bv)                                         \
  asm("v_pk_fma_f32 %0, %1, %2, %0 op_sel:[0,0,0] op_sel_hi:[1,0,1]"    \
      : "+v"(accv) : "v"(av), "v"(bv))
// packed IEEE fma pair: acc.{lo,hi} += a.{lo,hi} * b.hi   (b hi-broadcast)
#define PK_FMA_HI(accv, av, bv)                                         \
  asm("v_pk_fma_f32 %0, %1, %2, %0 op_sel:[0,1,0] op_sel_hi:[1,1,1]"    \
      : "+v"(accv) : "v"(av), "v"(bv))

__device__ __forceinline__ float silu_f(float u) {
  return u / (1.0f + expf(-u));
}

__device__ __forceinline__ int map_row(int r, int t0) {
  return (r >> 9) * T_ + t0 + (r & (TC - 1));   // TC == 512
}

__device__ __forceinline__ unsigned short bf16_rn(float x) {
  unsigned int u = __float_as_uint(x);
  u += 0x7FFF + ((u >> 16) & 1);
  return (unsigned short)(u >> 16);
}
__device__ __forceinline__ float bf16_f(unsigned short h) {
  unsigned int u = ((unsigned int)h) << 16;
  return __uint_as_float(u);
}

// async global(per-lane addr) -> LDS(wave-uniform base + lane*16)
__device__ __forceinline__ void async_copy16(const float* g, float* l) {
  __builtin_amdgcn_global_load_lds(
      (const __attribute__((address_space(1))) void*)g,
      (__attribute__((address_space(3))) void*)l, 16, 0, 0);
}

// ---------------------------------------------------------------------------
// transpose kernels (pure copies — fp-neutral)
// ---------------------------------------------------------------------------
__global__ __launch_bounds__(256)
void transpose_wg(const float* __restrict__ Wg, float* __restrict__ WgT) {
  __shared__ float tile[32][33];
  const int tx = threadIdx.x & 31, ty = threadIdx.x >> 5;  // 32x8
  const int d0 = blockIdx.x * 32, f0 = blockIdx.y * 32;
#pragma unroll
  for (int i = 0; i < 4; ++i)
    tile[ty + i * 8][tx] = Wg[(size_t)(f0 + ty + i * 8) * D_ + d0 + tx];
  __syncthreads();
#pragma unroll
  for (int i = 0; i < 4; ++i)
    WgT[(size_t)(d0 + ty + i * 8) * F_ + f0 + tx] = tile[tx][ty + i * 8];
}

__global__ __launch_bounds__(256)
void transpose_x(const float* __restrict__ x, float* __restrict__ xT, int t0) {
  __shared__ float tile[32][33];
  const int tx = threadIdx.x & 31, ty = threadIdx.x >> 5;  // 32x8
  const int d0 = blockIdx.x * 32, r0 = blockIdx.y * 32;
#pragma unroll
  for (int i = 0; i < 4; ++i)
    tile[ty + i * 8][tx] =
        x[(size_t)map_row(r0 + ty + i * 8, t0) * D_ + d0 + tx];
  __syncthreads();
#pragma unroll
  for (int i = 0; i < 4; ++i)
    xT[(size_t)(d0 + ty + i * 8) * MC + r0 + tx] = tile[tx][ty + i * 8];
}

// ---------------------------------------------------------------------------
// K1: gate GEMM — bit-exact DAG; 128x128 tile, 512 threads (8 waves),
// 8x4/thread, BK=32, global_load_lds staging, v_pk_fma_f32 inner loop.
// G[r,c] = chain(xT[:,r], WgT[:,c]): ascending-k IEEE fma, fold every 128.
// accP[ip][j] = (acc[2ip][j], acc[2ip+1][j]) — row-paired.
// ---------------------------------------------------------------------------
#pragma clang fp contract(off)
__global__ __launch_bounds__(512)
void gemm_gate_np(const float* __restrict__ xT, const float* __restrict__ WgT,
                  float* __restrict__ G) {
  __shared__ float As[32 * 128];
  __shared__ float Bs[32 * 128];
  const int tid = threadIdx.x;
  const int lane = tid & 63;
  const int w = tid >> 6;          // wave id 0..7
  const int tx = tid & 31;         // N: 32*4 = 128
  const int ty = tid >> 5;         // M: 16*8 = 128
  const int row0 = blockIdx.y * 128;
  const int col0 = blockIdx.x * 128;

  f32x2 accP[4][4];   // [row-pair][col]
  f32x2 csumP[4][4];
#pragma unroll
  for (int i = 0; i < 4; ++i)
#pragma unroll
    for (int j = 0; j < 4; ++j) {
      accP[i][j] = (f32x2)0.0f;
      csumP[i][j] = (f32x2)0.0f;
    }

  for (int kt = 0; kt < D_; kt += 32) {
    if (kt != 0 && (kt & 127) == 0) {   // fold at k = 128,256,...,896
#pragma unroll
      for (int i = 0; i < 4; ++i)
#pragma unroll
        for (int j = 0; j < 4; ++j) {
          csumP[i][j].x = __fadd_rn(csumP[i][j].x, accP[i][j].x);
          csumP[i][j].y = __fadd_rn(csumP[i][j].y, accP[i][j].y);
          accP[i][j] = (f32x2)0.0f;
        }
    }
    __syncthreads();
    // A tile: 32 k-rows x 128 f32 = 16KB -> 2 wave-issues/wave (1KB each)
#pragma unroll
    for (int t = 0; t < 2; ++t) {
      const int ii = w * 2 + t;                   // 0..15
      const int kr = kt + ii * 2 + (lane >> 5);   // 2 k-rows per issue
      async_copy16(&xT[(size_t)kr * MC + row0 + (lane & 31) * 4],
                   &As[ii * 256]);
    }
    // B tile: 32 k-rows x 128 f32 = 16KB -> 2 wave-issues/wave
#pragma unroll
    for (int t = 0; t < 2; ++t) {
      const int ii = w * 2 + t;                   // 0..15
      const int kr = kt + ii * 2 + (lane >> 5);
      async_copy16(&WgT[(size_t)kr * F_ + col0 + (lane & 31) * 4],
                   &Bs[ii * 256]);
    }
    __syncthreads();   // drains vmcnt — tiles ready
#pragma unroll
    for (int kk = 0; kk < 32; ++kk) {   // ascending k
      const float4 a0 = *reinterpret_cast<const float4*>(&As[kk * 128 + ty * 8]);
      const float4 a1 = *reinterpret_cast<const float4*>(&As[kk * 128 + ty * 8 + 4]);
      const float4 b0 = *reinterpret_cast<const float4*>(&Bs[kk * 128 + tx * 4]);
      f32x2 ap[4];
      ap[0] = (f32x2){a0.x, a0.y};
      ap[1] = (f32x2){a0.z, a0.w};
      ap[2] = (f32x2){a1.x, a1.y};
      ap[3] = (f32x2){a1.z, a1.w};
      const f32x2 bp0 = (f32x2){b0.x, b0.y};
      const f32x2 bp1 = (f32x2){b0.z, b0.w};
#pragma unroll
      for (int ip = 0; ip < 4; ++ip) {
        PK_FMA_LO(accP[ip][0], ap[ip], bp0);   // col 0: b0.x
        PK_FMA_HI(accP[ip][1], ap[ip], bp0);   // col 1: b0.y
        PK_FMA_LO(accP[ip][2], ap[ip], bp1);   // col 2: b0.z
        PK_FMA_HI(accP[ip][3], ap[ip], bp1);   // col 3: b0.w
      }
    }
  }

#pragma unroll
  for (int ip = 0; ip < 4; ++ip) {
#pragma unroll
    for (int h = 0; h < 2; ++h) {
      const int r = row0 + ty * 8 + ip * 2 + h;
      float4 v;
      v.x = __fadd_rn(h ? csumP[ip][0].y : csumP[ip][0].x,
                      h ? accP[ip][0].y : accP[ip][0].x);
      v.y = __fadd_rn(h ? csumP[ip][1].y : csumP[ip][1].x,
                      h ? accP[ip][1].y : accP[ip][1].x);
      v.z = __fadd_rn(h ? csumP[ip][2].y : csumP[ip][2].x,
                      h ? accP[ip][2].y : accP[ip][2].x);
      v.w = __fadd_rn(h ? csumP[ip][3].y : csumP[ip][3].x,
                      h ? accP[ip][3].y : accP[ip][3].x);
      *reinterpret_cast<float4*>(&G[(size_t)r * F_ + col0 + tx * 4]) = v;
    }
  }
}
#pragma clang fp contract(fast)

// ---------------------------------------------------------------------------
// K2: LIF scan — numpy f32 ufunc semantics (bit-exact), batched loads.
// ---------------------------------------------------------------------------
#pragma clang fp contract(off)
__global__ __launch_bounds__(64)
void lif_scan(const float* __restrict__ G, unsigned char* __restrict__ S8,
              float* __restrict__ state, const float* __restrict__ theta,
              int t0) {
  const int j = blockIdx.x * 64 + threadIdx.x;
  const int f = j & (F_ - 1);
  const int b = j >> 12;
  float m = (t0 == 0) ? 0.0f : state[j];
  const float th = theta[f];
  const size_t base = (size_t)b * TC * F_ + f;
  for (int tb = 0; tb < TC; tb += 16) {
    float g[16];
#pragma unroll
    for (int u = 0; u < 16; ++u) g[u] = G[base + (size_t)(tb + u) * F_];
#pragma unroll
    for (int u = 0; u < 16; ++u) {
      const float bm = __fmul_rn(0.8f, m);
      m = __fadd_rn(bm, g[u]);
      const float s = (m >= 1.0f) ? 1.0f : 0.0f;
      const float r = __fmul_rn(th, s);
      m = __fsub_rn(m, r);
      S8[base + (size_t)(tb + u) * F_] = (unsigned char)s;
    }
  }
  state[j] = m;
}
#pragma clang fp contract(fast)

// ---------------------------------------------------------------------------
// weight split: f32 -> (hi, lo) bf16
// ---------------------------------------------------------------------------
__global__ __launch_bounds__(256)
void split_f32(const float* __restrict__ src, unsigned short* __restrict__ hi,
               unsigned short* __restrict__ lo, int n4) {
  int i = blockIdx.x * 256 + threadIdx.x;
  const int stride = gridDim.x * 256;
  for (; i < n4; i += stride) {
    const float4 v = reinterpret_cast<const float4*>(src)[i];
    ushort4 h, l;
    h.x = bf16_rn(v.x); l.x = bf16_rn(v.x - bf16_f(h.x));
    h.y = bf16_rn(v.y); l.y = bf16_rn(v.y - bf16_f(h.y));
    h.z = bf16_rn(v.z); l.z = bf16_rn(v.z - bf16_f(h.z));
    h.w = bf16_rn(v.w); l.w = bf16_rn(v.w - bf16_f(h.w));
    reinterpret_cast<ushort4*>(hi)[i] = h;
    reinterpret_cast<ushort4*>(lo)[i] = l;
  }
}

// x chunk split with row mapping
__global__ __launch_bounds__(256)
void split_x(const float* __restrict__ x, unsigned short* __restrict__ Xh,
             unsigned short* __restrict__ Xl, int t0) {
  const int i = blockIdx.x * 256 + threadIdx.x;   // float4 index, MC*D/4
  const int r = i >> 8;                            // D/4 == 256
  const int q = i & 255;
  const float4 v = *reinterpret_cast<const float4*>(
      &x[(size_t)map_row(r, t0) * D_ + q * 4]);
  ushort4 h, l;
  h.x = bf16_rn(v.x); l.x = bf16_rn(v.x - bf16_f(h.x));
  h.y = bf16_rn(v.y); l.y = bf16_rn(v.y - bf16_f(h.y));
  h.z = bf16_rn(v.z); l.z = bf16_rn(v.z - bf16_f(h.z));
  h.w = bf16_rn(v.w); l.w = bf16_rn(v.w - bf16_f(h.w));
  *reinterpret_cast<ushort4*>(&Xh[(size_t)r * D_ + q * 4]) = h;
  *reinterpret_cast<ushort4*>(&Xl[(size_t)r * D_ + q * 4]) = l;
}

// ---------------------------------------------------------------------------
// K3: up = x @ Wu^T via split-bf16 MFMA; epilogue h = spike*silu(up) -> hi/lo.
// ---------------------------------------------------------------------------
__global__ __launch_bounds__(256)
void up_mfma(const unsigned short* __restrict__ Xh,
             const unsigned short* __restrict__ Xl,
             const unsigned short* __restrict__ Wh,
             const unsigned short* __restrict__ Wl,
             const unsigned char* __restrict__ S8,
             unsigned short* __restrict__ Hh, unsigned short* __restrict__ Hl) {
  __shared__ unsigned short Ah[128 * LDK], Al[128 * LDK];
  __shared__ unsigned short Bh[128 * LDK], Bl[128 * LDK];
  const int tid = threadIdx.x;
  const int lane = tid & 63;
  const int w = tid >> 6;
  const int wr = (w >> 1) * 64;
  const int wc = (w & 1) * 64;
  const int brow = blockIdx.y * 128;
  const int bcol = blockIdx.x * 128;

  f32x4 acc[4][4];
#pragma unroll
  for (int i = 0; i < 4; ++i)
#pragma unroll
    for (int j = 0; j < 4; ++j) acc[i][j] = (f32x4)0.0f;

  for (int k0 = 0; k0 < D_; k0 += 32) {
    __syncthreads();
#pragma unroll
    for (int s = 0; s < 2; ++s) {
      const int v = tid + s * 256;
      const int row = v >> 2, q = v & 3;
      *reinterpret_cast<uint4*>(&Ah[row * LDK + q * 8]) =
          *reinterpret_cast<const uint4*>(
              &Xh[(size_t)(brow + row) * D_ + k0 + q * 8]);
      *reinterpret_cast<uint4*>(&Al[row * LDK + q * 8]) =
          *reinterpret_cast<const uint4*>(
              &Xl[(size_t)(brow + row) * D_ + k0 + q * 8]);
      *reinterpret_cast<uint4*>(&Bh[row * LDK + q * 8]) =
          *reinterpret_cast<const uint4*>(
              &Wh[(size_t)(bcol + row) * D_ + k0 + q * 8]);
      *reinterpret_cast<uint4*>(&Bl[row * LDK + q * 8]) =
          *reinterpret_cast<const uint4*>(
              &Wl[(size_t)(bcol + row) * D_ + k0 + q * 8]);
    }
    __syncthreads();
    const int fr = lane & 15;
    const int kq = (lane >> 4) * 8;
    bf16x8 ah[4], al[4], bh[4], bl[4];
#pragma unroll
    for (int i = 0; i < 4; ++i) {
      ah[i] = *reinterpret_cast<const bf16x8*>(&Ah[(wr + i * 16 + fr) * LDK + kq]);
      al[i] = *reinterpret_cast<const bf16x8*>(&Al[(wr + i * 16 + fr) * LDK + kq]);
      bh[i] = *reinterpret_cast<const bf16x8*>(&Bh[(wc + i * 16 + fr) * LDK + kq]);
      bl[i] = *reinterpret_cast<const bf16x8*>(&Bl[(wc + i * 16 + fr) * LDK + kq]);
    }
#pragma unroll
    for (int i = 0; i < 4; ++i)
#pragma unroll
      for (int j = 0; j < 4; ++j) {
        acc[i][j] = __builtin_amdgcn_mfma_f32_16x16x32_bf16(ah[i], bh[j], acc[i][j], 0, 0, 0);
        acc[i][j] = __builtin_amdgcn_mfma_f32_16x16x32_bf16(ah[i], bl[j], acc[i][j], 0, 0, 0);
        acc[i][j] = __builtin_amdgcn_mfma_f32_16x16x32_bf16(al[i], bh[j], acc[i][j], 0, 0, 0);
      }
  }

  const int fr = lane & 15;
  const int rg = (lane >> 4) * 4;
#pragma unroll
  for (int i = 0; i < 4; ++i)
#pragma unroll
    for (int j = 0; j < 4; ++j) {
      const int c = bcol + wc + j * 16 + fr;
#pragma unroll
      for (int r = 0; r < 4; ++r) {
        const int rl = brow + wr + i * 16 + rg + r;
        const float up = acc[i][j][r];
        const float h = S8[(size_t)rl * F_ + c] ? silu_f(up) : 0.0f;
        const unsigned short hh = bf16_rn(h);
        Hh[(size_t)rl * F_ + c] = hh;
        Hl[(size_t)rl * F_ + c] = bf16_rn(h - bf16_f(hh));
      }
    }
}

// ---------------------------------------------------------------------------
// K4: out = h @ Wd^T via split-bf16 MFMA. Tile 128x64, wave tile 64x32.
// ---------------------------------------------------------------------------
__global__ __launch_bounds__(256)
void down_mfma(const unsigned short* __restrict__ Hh,
               const unsigned short* __restrict__ Hl,
               const unsigned short* __restrict__ Wh,
               const unsigned short* __restrict__ Wl,
               float* __restrict__ out, int t0) {
  __shared__ unsigned short Ah[128 * LDK], Al[128 * LDK];
  __shared__ unsigned short Bh[64 * LDK], Bl[64 * LDK];
  const int tid = threadIdx.x;
  const int lane = tid & 63;
  const int w = tid >> 6;
  const int wr = (w >> 1) * 64;
  const int wc = (w & 1) * 32;
  const int brow = blockIdx.y * 128;
  const int bcol = blockIdx.x * 64;

  f32x4 acc[4][2];
#pragma unroll
  for (int i = 0; i < 4; ++i)
#pragma unroll
    for (int j = 0; j < 2; ++j) acc[i][j] = (f32x4)0.0f;

  for (int k0 = 0; k0 < F_; k0 += 32) {
    __syncthreads();
#pragma unroll
    for (int s = 0; s < 2; ++s) {
      const int v = tid + s * 256;
      const int row = v >> 2, q = v & 3;
      *reinterpret_cast<uint4*>(&Ah[row * LDK + q * 8]) =
          *reinterpret_cast<const uint4*>(
              &Hh[(size_t)(brow + row) * F_ + k0 + q * 8]);
      *reinterpret_cast<uint4*>(&Al[row * LDK + q * 8]) =
          *reinterpret_cast<const uint4*>(
              &Hl[(size_t)(brow + row) * F_ + k0 + q * 8]);
    }
    {
      const int row = tid >> 2, q = tid & 3;
      *reinterpret_cast<uint4*>(&Bh[row * LDK + q * 8]) =
          *reinterpret_cast<const uint4*>(
              &Wh[(size_t)(bcol + row) * F_ + k0 + q * 8]);
      *reinterpret_cast<uint4*>(&Bl[row * LDK + q * 8]) =
          *reinterpret_cast<const uint4*>(
              &Wl[(size_t)(bcol + row) * F_ + k0 + q * 8]);
    }
    __syncthreads();
    const int fr = lane & 15;
    const int kq = (lane >> 4) * 8;
    bf16x8 ah[4], al[4], bh[2], bl[2];
#pragma unroll
    for (int i = 0; i < 4; ++i) {
      ah[i] = *reinterpret_cast<const bf16x8*>(&Ah[(wr + i * 16 + fr) * LDK + kq]);
      al[i] = *reinterpret_cast<const bf16x8*>(&Al[(wr + i * 16 + fr) * LDK + kq]);
    }
#pragma unroll
    for (int j = 0; j < 2; ++j) {
      bh[j] = *reinterpret_cast<const bf16x8*>(&Bh[(wc + j * 16 + fr) * LDK + kq]);
      bl[j] = *reinterpret_cast<const bf16x8*>(&Bl[(wc + j * 16 + fr) * LDK + kq]);
    }
#pragma unroll
    for (int i = 0; i < 4; ++i)
#pragma unroll
      for (int j = 0; j < 2; ++j) {
        acc[i][j] = __builtin_amdgcn_mfma_f32_16x16x32_bf16(ah[i], bh[j], acc[i][j], 0, 0, 0);
        acc[i][j] = __builtin_amdgcn_mfma_f32_16x16x32_bf16(ah[i], bl[j], acc[i][j], 0, 0, 0);
        acc[i][j] = __builtin_amdgcn_mfma_f32_16x16x32_bf16(al[i], bh[j], acc[i][j], 0, 0, 0);
      }
  }

  const int fr = lane & 15;
  const int rg = (lane >> 4) * 4;
#pragma unroll
  for (int i = 0; i < 4; ++i)
#pragma unroll
    for (int j = 0; j < 2; ++j) {
      const int c = bcol + wc + j * 16 + fr;
#pragma unroll
      for (int r = 0; r < 4; ++r) {
        const int rl = brow + wr + i * 16 + rg + r;
        out[(size_t)map_row(rl, t0) * D_ + c] = acc[i][j][r];
      }
    }
}

}  // namespace

extern "C" void kernel_launch(void* const* d_in, const int* in_sizes, int n_in,
                              void* d_out, int out_size, void* d_ws,
                              size_t ws_size, hipStream_t stream) {
  const float* x = (const float*)d_in[0];
  const float* Wg = (const float*)d_in[1];
  const float* Wu = (const float*)d_in[2];
  const float* Wd = (const float*)d_in[3];
  const float* theta = (const float*)d_in[4];
  float* out = (float*)d_out;

  // ws layout (100.73 MB; R1 proved >= 100.79 MB available)
  char* ws = (char*)d_ws;
  const size_t wu_b = (size_t)F_ * D_ * 2;            // 8.39 MB
  unsigned short* Wu_hi = (unsigned short*)ws;
  unsigned short* Wu_lo = (unsigned short*)(ws + wu_b);
  unsigned short* Wd_hi = (unsigned short*)(ws + 2 * wu_b);
  unsigned short* Wd_lo = (unsigned short*)(ws + 3 * wu_b);
  float* WgT = (float*)(ws + 4 * wu_b);                        // 16.78 MB
  char* xbase = ws + 4 * wu_b + (size_t)F_ * D_ * 4;
  unsigned short* Xh = (unsigned short*)xbase;                 // 4.19 MB
  unsigned short* Xl = (unsigned short*)(xbase + (size_t)MC * D_ * 2);
  char* gbase = xbase + (size_t)MC * D_ * 4;
  float* G = (float*)gbase;                                    // 33.55 MB
  unsigned short* Hh = (unsigned short*)gbase;                 // overlays G
  unsigned short* Hl = (unsigned short*)(gbase + (size_t)MC * F_ * 2);
  char* s8xt = gbase + (size_t)MC * F_ * 4;                    // 8.39 MB shared
  float* xT = (float*)s8xt;          // alive: transpose_x -> gate
  unsigned char* S8 = (unsigned char*)s8xt;  // alive: scan -> up (disjoint)
  float* state = (float*)(s8xt + (size_t)MC * D_ * 4);         // 64 KB

  const dim3 blk(256);
  hipLaunchKernelGGL(split_f32, dim3(1024), blk, 0, stream, Wu, Wu_hi, Wu_lo,
                     F_ * D_ / 4);
  hipLaunchKernelGGL(split_f32, dim3(1024), blk, 0, stream, Wd, Wd_hi, Wd_lo,
                     D_ * F_ / 4);
  hipLaunchKernelGGL(transpose_wg, dim3(D_ / 32, F_ / 32), blk, 0, stream,
                     Wg, WgT);

  const dim3 g_tx(D_ / 32, MC / 32);     // (32, 64)
  const dim3 g_gt(F_ / 128, MC / 128);   // (32, 16) -> 512 blocks
  const dim3 g_sc(B_ * F_ / 64);         // 256 blocks x 64
  const dim3 g_sx(MC * D_ / 4 / 256);    // 2048 blocks
  const dim3 g_up(F_ / 128, MC / 128);   // (32, 16)
  const dim3 g_dn(D_ / 64, MC / 128);    // (16, 16)

  for (int c = 0; c < NCHUNK; ++c) {
    const int t0 = c * TC;
    hipLaunchKernelGGL(transpose_x, g_tx, blk, 0, stream, x, xT, t0);
    hipLaunchKernelGGL(split_x, g_sx, blk, 0, stream, x, Xh, Xl, t0);
    hipLaunchKernelGGL(gemm_gate_np, g_gt, dim3(512), 0, stream, xT, WgT, G);
    hipLaunchKernelGGL(lif_scan, g_sc, dim3(64), 0, stream, G, S8, state,
                       theta, t0);
    hipLaunchKernelGGL(up_mfma, g_up, blk, 0, stream, Xh, Xl, Wu_hi, Wu_lo,
                       S8, Hh, Hl);
    hipLaunchKernelGGL(down_mfma, g_dn, blk, 0, stream, Hh, Hl, Wd_hi, Wd_lo,
                       out, t0);
  }
}

// Round 21
// 1527.792 us; speedup vs baseline: 1.1992x; 1.0885x over previous
//
#include <hip/hip_runtime.h>
#include <hip/hip_bf16.h>
#include <math.h>

// LIFGatedRouter: out = (gate * silu(x@Wu^T)) @ Wd^T
// R21: up/down GEMMs use ONE-SIDED split: (a_hi + a_lo) x b_hi = 2 MFMAs
// (drop a*b_lo term; error ~1e-3 << 0.0252 threshold). B-side lo never
// computed/staged -> 25% less LDS+staging, 33% fewer MFMAs, half weight prep.
// Gate GEMM (v_pk_fma_f32, 128x128x8-wave, global_load_lds, fold@128k —
// R13-verified BIT-EXACT DAG) and scan (numpy-ufunc) unchanged from R20.

namespace {

constexpr int B_ = 4;
constexpr int T_ = 2048;
constexpr int D_ = 1024;
constexpr int F_ = 4096;
constexpr int TC = 512;
constexpr int NCHUNK = T_ / TC;      // 4
constexpr int MC = B_ * TC;          // 2048 chunk-local rows
constexpr int LDK = 40;              // MFMA LDS row stride (bf16), 32+8 pad

typedef __attribute__((ext_vector_type(8))) short bf16x8;
typedef __attribute__((ext_vector_type(4))) float f32x4;
typedef __attribute__((ext_vector_type(2))) float f32x2;

// packed IEEE fma pair: acc.{lo,hi} += a.{lo,hi} * b.lo   (b lo-broadcast)
#define PK_FMA_LO(accv, av, bv)                                         \
  asm("v_pk_fma_f32 %0, %1, %2, %0 op_sel:[0,0,0] op_sel_hi:[1,0,1]"    \
      : "+v"(accv) : "v"(av), "v"(bv))
// packed IEEE fma pair: acc.{lo,hi} += a.{lo,hi} * b.hi   (b hi-broadcast)
#define PK_FMA_HI(accv, av, bv)                                         \
  asm("v_pk_fma_f32 %0, %1, %2, %0 op_sel:[0,1,0] op_sel_hi:[1,1,1]"    \
      : "+v"(accv) : "v"(av), "v"(bv))

__device__ __forceinline__ float silu_f(float u) {
  return u / (1.0f + expf(-u));
}

__device__ __forceinline__ int map_row(int r, int t0) {
  return (r >> 9) * T_ + t0 + (r & (TC - 1));   // TC == 512
}

__device__ __forceinline__ unsigned short bf16_rn(float x) {
  unsigned int u = __float_as_uint(x);
  u += 0x7FFF + ((u >> 16) & 1);
  return (unsigned short)(u >> 16);
}
__device__ __forceinline__ float bf16_f(unsigned short h) {
  unsigned int u = ((unsigned int)h) << 16;
  return __uint_as_float(u);
}

// async global(per-lane addr) -> LDS(wave-uniform base + lane*16)
__device__ __forceinline__ void async_copy16(const float* g, float* l) {
  __builtin_amdgcn_global_load_lds(
      (const __attribute__((address_space(1))) void*)g,
      (__attribute__((address_space(3))) void*)l, 16, 0, 0);
}

// ---------------------------------------------------------------------------
// transpose kernels (pure copies — fp-neutral)
// ---------------------------------------------------------------------------
__global__ __launch_bounds__(256)
void transpose_wg(const float* __restrict__ Wg, float* __restrict__ WgT) {
  __shared__ float tile[32][33];
  const int tx = threadIdx.x & 31, ty = threadIdx.x >> 5;  // 32x8
  const int d0 = blockIdx.x * 32, f0 = blockIdx.y * 32;
#pragma unroll
  for (int i = 0; i < 4; ++i)
    tile[ty + i * 8][tx] = Wg[(size_t)(f0 + ty + i * 8) * D_ + d0 + tx];
  __syncthreads();
#pragma unroll
  for (int i = 0; i < 4; ++i)
    WgT[(size_t)(d0 + ty + i * 8) * F_ + f0 + tx] = tile[tx][ty + i * 8];
}

__global__ __launch_bounds__(256)
void transpose_x(const float* __restrict__ x, float* __restrict__ xT, int t0) {
  __shared__ float tile[32][33];
  const int tx = threadIdx.x & 31, ty = threadIdx.x >> 5;  // 32x8
  const int d0 = blockIdx.x * 32, r0 = blockIdx.y * 32;
#pragma unroll
  for (int i = 0; i < 4; ++i)
    tile[ty + i * 8][tx] =
        x[(size_t)map_row(r0 + ty + i * 8, t0) * D_ + d0 + tx];
  __syncthreads();
#pragma unroll
  for (int i = 0; i < 4; ++i)
    xT[(size_t)(d0 + ty + i * 8) * MC + r0 + tx] = tile[tx][ty + i * 8];
}

// ---------------------------------------------------------------------------
// K1: gate GEMM — bit-exact DAG; 128x128 tile, 512 threads (8 waves),
// 8x4/thread, BK=32, global_load_lds staging, v_pk_fma_f32 inner loop.
// ---------------------------------------------------------------------------
#pragma clang fp contract(off)
__global__ __launch_bounds__(512)
void gemm_gate_np(const float* __restrict__ xT, const float* __restrict__ WgT,
                  float* __restrict__ G) {
  __shared__ float As[32 * 128];
  __shared__ float Bs[32 * 128];
  const int tid = threadIdx.x;
  const int lane = tid & 63;
  const int w = tid >> 6;          // wave id 0..7
  const int tx = tid & 31;         // N: 32*4 = 128
  const int ty = tid >> 5;         // M: 16*8 = 128
  const int row0 = blockIdx.y * 128;
  const int col0 = blockIdx.x * 128;

  f32x2 accP[4][4];   // [row-pair][col]
  f32x2 csumP[4][4];
#pragma unroll
  for (int i = 0; i < 4; ++i)
#pragma unroll
    for (int j = 0; j < 4; ++j) {
      accP[i][j] = (f32x2)0.0f;
      csumP[i][j] = (f32x2)0.0f;
    }

  for (int kt = 0; kt < D_; kt += 32) {
    if (kt != 0 && (kt & 127) == 0) {   // fold at k = 128,256,...,896
#pragma unroll
      for (int i = 0; i < 4; ++i)
#pragma unroll
        for (int j = 0; j < 4; ++j) {
          csumP[i][j].x = __fadd_rn(csumP[i][j].x, accP[i][j].x);
          csumP[i][j].y = __fadd_rn(csumP[i][j].y, accP[i][j].y);
          accP[i][j] = (f32x2)0.0f;
        }
    }
    __syncthreads();
#pragma unroll
    for (int t = 0; t < 2; ++t) {
      const int ii = w * 2 + t;                   // 0..15
      const int kr = kt + ii * 2 + (lane >> 5);
      async_copy16(&xT[(size_t)kr * MC + row0 + (lane & 31) * 4],
                   &As[ii * 256]);
    }
#pragma unroll
    for (int t = 0; t < 2; ++t) {
      const int ii = w * 2 + t;
      const int kr = kt + ii * 2 + (lane >> 5);
      async_copy16(&WgT[(size_t)kr * F_ + col0 + (lane & 31) * 4],
                   &Bs[ii * 256]);
    }
    __syncthreads();   // drains vmcnt — tiles ready
#pragma unroll
    for (int kk = 0; kk < 32; ++kk) {   // ascending k
      const float4 a0 = *reinterpret_cast<const float4*>(&As[kk * 128 + ty * 8]);
      const float4 a1 = *reinterpret_cast<const float4*>(&As[kk * 128 + ty * 8 + 4]);
      const float4 b0 = *reinterpret_cast<const float4*>(&Bs[kk * 128 + tx * 4]);
      f32x2 ap[4];
      ap[0] = (f32x2){a0.x, a0.y};
      ap[1] = (f32x2){a0.z, a0.w};
      ap[2] = (f32x2){a1.x, a1.y};
      ap[3] = (f32x2){a1.z, a1.w};
      const f32x2 bp0 = (f32x2){b0.x, b0.y};
      const f32x2 bp1 = (f32x2){b0.z, b0.w};
#pragma unroll
      for (int ip = 0; ip < 4; ++ip) {
        PK_FMA_LO(accP[ip][0], ap[ip], bp0);   // col 0: b0.x
        PK_FMA_HI(accP[ip][1], ap[ip], bp0);   // col 1: b0.y
        PK_FMA_LO(accP[ip][2], ap[ip], bp1);   // col 2: b0.z
        PK_FMA_HI(accP[ip][3], ap[ip], bp1);   // col 3: b0.w
      }
    }
  }

#pragma unroll
  for (int ip = 0; ip < 4; ++ip) {
#pragma unroll
    for (int h = 0; h < 2; ++h) {
      const int r = row0 + ty * 8 + ip * 2 + h;
      float4 v;
      v.x = __fadd_rn(h ? csumP[ip][0].y : csumP[ip][0].x,
                      h ? accP[ip][0].y : accP[ip][0].x);
      v.y = __fadd_rn(h ? csumP[ip][1].y : csumP[ip][1].x,
                      h ? accP[ip][1].y : accP[ip][1].x);
      v.z = __fadd_rn(h ? csumP[ip][2].y : csumP[ip][2].x,
                      h ? accP[ip][2].y : accP[ip][2].x);
      v.w = __fadd_rn(h ? csumP[ip][3].y : csumP[ip][3].x,
                      h ? accP[ip][3].y : accP[ip][3].x);
      *reinterpret_cast<float4*>(&G[(size_t)r * F_ + col0 + tx * 4]) = v;
    }
  }
}
#pragma clang fp contract(fast)

// ---------------------------------------------------------------------------
// K2: LIF scan — numpy f32 ufunc semantics (bit-exact), batched loads.
// ---------------------------------------------------------------------------
#pragma clang fp contract(off)
__global__ __launch_bounds__(64)
void lif_scan(const float* __restrict__ G, unsigned char* __restrict__ S8,
              float* __restrict__ state, const float* __restrict__ theta,
              int t0) {
  const int j = blockIdx.x * 64 + threadIdx.x;
  const int f = j & (F_ - 1);
  const int b = j >> 12;
  float m = (t0 == 0) ? 0.0f : state[j];
  const float th = theta[f];
  const size_t base = (size_t)b * TC * F_ + f;
  for (int tb = 0; tb < TC; tb += 16) {
    float g[16];
#pragma unroll
    for (int u = 0; u < 16; ++u) g[u] = G[base + (size_t)(tb + u) * F_];
#pragma unroll
    for (int u = 0; u < 16; ++u) {
      const float bm = __fmul_rn(0.8f, m);
      m = __fadd_rn(bm, g[u]);
      const float s = (m >= 1.0f) ? 1.0f : 0.0f;
      const float r = __fmul_rn(th, s);
      m = __fsub_rn(m, r);
      S8[base + (size_t)(tb + u) * F_] = (unsigned char)s;
    }
  }
  state[j] = m;
}
#pragma clang fp contract(fast)

// ---------------------------------------------------------------------------
// cast to bf16 hi only (B-side of one-sided split)
// ---------------------------------------------------------------------------
__global__ __launch_bounds__(256)
void cast_hi(const float* __restrict__ src, unsigned short* __restrict__ hi,
             int n4) {
  int i = blockIdx.x * 256 + threadIdx.x;
  const int stride = gridDim.x * 256;
  for (; i < n4; i += stride) {
    const float4 v = reinterpret_cast<const float4*>(src)[i];
    ushort4 h;
    h.x = bf16_rn(v.x);
    h.y = bf16_rn(v.y);
    h.z = bf16_rn(v.z);
    h.w = bf16_rn(v.w);
    reinterpret_cast<ushort4*>(hi)[i] = h;
  }
}

// x chunk split with row mapping (A-side: hi + lo)
__global__ __launch_bounds__(256)
void split_x(const float* __restrict__ x, unsigned short* __restrict__ Xh,
             unsigned short* __restrict__ Xl, int t0) {
  const int i = blockIdx.x * 256 + threadIdx.x;   // float4 index, MC*D/4
  const int r = i >> 8;                            // D/4 == 256
  const int q = i & 255;
  const float4 v = *reinterpret_cast<const float4*>(
      &x[(size_t)map_row(r, t0) * D_ + q * 4]);
  ushort4 h, l;
  h.x = bf16_rn(v.x); l.x = bf16_rn(v.x - bf16_f(h.x));
  h.y = bf16_rn(v.y); l.y = bf16_rn(v.y - bf16_f(h.y));
  h.z = bf16_rn(v.z); l.z = bf16_rn(v.z - bf16_f(h.z));
  h.w = bf16_rn(v.w); l.w = bf16_rn(v.w - bf16_f(h.w));
  *reinterpret_cast<ushort4*>(&Xh[(size_t)r * D_ + q * 4]) = h;
  *reinterpret_cast<ushort4*>(&Xl[(size_t)r * D_ + q * 4]) = l;
}

// ---------------------------------------------------------------------------
// K3: up = x @ Wu^T via one-sided split MFMA ((xh+xl)*Wh, 2 MFMAs);
// epilogue h = spike*silu(up) -> hi/lo. Tile 128x128, wave tile 64x64.
// ---------------------------------------------------------------------------
__global__ __launch_bounds__(256)
void up_mfma(const unsigned short* __restrict__ Xh,
             const unsigned short* __restrict__ Xl,
             const unsigned short* __restrict__ Wh,
             const unsigned char* __restrict__ S8,
             unsigned short* __restrict__ Hh, unsigned short* __restrict__ Hl) {
  __shared__ unsigned short Ah[128 * LDK], Al[128 * LDK];
  __shared__ unsigned short Bh[128 * LDK];
  const int tid = threadIdx.x;
  const int lane = tid & 63;
  const int w = tid >> 6;
  const int wr = (w >> 1) * 64;
  const int wc = (w & 1) * 64;
  const int brow = blockIdx.y * 128;
  const int bcol = blockIdx.x * 128;

  f32x4 acc[4][4];
#pragma unroll
  for (int i = 0; i < 4; ++i)
#pragma unroll
    for (int j = 0; j < 4; ++j) acc[i][j] = (f32x4)0.0f;

  for (int k0 = 0; k0 < D_; k0 += 32) {
    __syncthreads();
#pragma unroll
    for (int s = 0; s < 2; ++s) {
      const int v = tid + s * 256;
      const int row = v >> 2, q = v & 3;
      *reinterpret_cast<uint4*>(&Ah[row * LDK + q * 8]) =
          *reinterpret_cast<const uint4*>(
              &Xh[(size_t)(brow + row) * D_ + k0 + q * 8]);
      *reinterpret_cast<uint4*>(&Al[row * LDK + q * 8]) =
          *reinterpret_cast<const uint4*>(
              &Xl[(size_t)(brow + row) * D_ + k0 + q * 8]);
      *reinterpret_cast<uint4*>(&Bh[row * LDK + q * 8]) =
          *reinterpret_cast<const uint4*>(
              &Wh[(size_t)(bcol + row) * D_ + k0 + q * 8]);
    }
    __syncthreads();
    const int fr = lane & 15;
    const int kq = (lane >> 4) * 8;
    bf16x8 ah[4], al[4], bh[4];
#pragma unroll
    for (int i = 0; i < 4; ++i) {
      ah[i] = *reinterpret_cast<const bf16x8*>(&Ah[(wr + i * 16 + fr) * LDK + kq]);
      al[i] = *reinterpret_cast<const bf16x8*>(&Al[(wr + i * 16 + fr) * LDK + kq]);
      bh[i] = *reinterpret_cast<const bf16x8*>(&Bh[(wc + i * 16 + fr) * LDK + kq]);
    }
#pragma unroll
    for (int i = 0; i < 4; ++i)
#pragma unroll
      for (int j = 0; j < 4; ++j) {
        acc[i][j] = __builtin_amdgcn_mfma_f32_16x16x32_bf16(ah[i], bh[j], acc[i][j], 0, 0, 0);
        acc[i][j] = __builtin_amdgcn_mfma_f32_16x16x32_bf16(al[i], bh[j], acc[i][j], 0, 0, 0);
      }
  }

  const int fr = lane & 15;
  const int rg = (lane >> 4) * 4;
#pragma unroll
  for (int i = 0; i < 4; ++i)
#pragma unroll
    for (int j = 0; j < 4; ++j) {
      const int c = bcol + wc + j * 16 + fr;
#pragma unroll
      for (int r = 0; r < 4; ++r) {
        const int rl = brow + wr + i * 16 + rg + r;
        const float up = acc[i][j][r];
        const float h = S8[(size_t)rl * F_ + c] ? silu_f(up) : 0.0f;
        const unsigned short hh = bf16_rn(h);
        Hh[(size_t)rl * F_ + c] = hh;
        Hl[(size_t)rl * F_ + c] = bf16_rn(h - bf16_f(hh));
      }
    }
}

// ---------------------------------------------------------------------------
// K4: out = h @ Wd^T via one-sided split MFMA ((hh+hl)*Wh, 2 MFMAs).
// Tile 128x64, wave tile 64x32.
// ---------------------------------------------------------------------------
__global__ __launch_bounds__(256)
void down_mfma(const unsigned short* __restrict__ Hh,
               const unsigned short* __restrict__ Hl,
               const unsigned short* __restrict__ Wh,
               float* __restrict__ out, int t0) {
  __shared__ unsigned short Ah[128 * LDK], Al[128 * LDK];
  __shared__ unsigned short Bh[64 * LDK];
  const int tid = threadIdx.x;
  const int lane = tid & 63;
  const int w = tid >> 6;
  const int wr = (w >> 1) * 64;
  const int wc = (w & 1) * 32;
  const int brow = blockIdx.y * 128;
  const int bcol = blockIdx.x * 64;

  f32x4 acc[4][2];
#pragma unroll
  for (int i = 0; i < 4; ++i)
#pragma unroll
    for (int j = 0; j < 2; ++j) acc[i][j] = (f32x4)0.0f;

  for (int k0 = 0; k0 < F_; k0 += 32) {
    __syncthreads();
#pragma unroll
    for (int s = 0; s < 2; ++s) {
      const int v = tid + s * 256;
      const int row = v >> 2, q = v & 3;
      *reinterpret_cast<uint4*>(&Ah[row * LDK + q * 8]) =
          *reinterpret_cast<const uint4*>(
              &Hh[(size_t)(brow + row) * F_ + k0 + q * 8]);
      *reinterpret_cast<uint4*>(&Al[row * LDK + q * 8]) =
          *reinterpret_cast<const uint4*>(
              &Hl[(size_t)(brow + row) * F_ + k0 + q * 8]);
    }
    {
      const int row = tid >> 2, q = tid & 3;
      *reinterpret_cast<uint4*>(&Bh[row * LDK + q * 8]) =
          *reinterpret_cast<const uint4*>(
              &Wh[(size_t)(bcol + row) * F_ + k0 + q * 8]);
    }
    __syncthreads();
    const int fr = lane & 15;
    const int kq = (lane >> 4) * 8;
    bf16x8 ah[4], al[4], bh[2];
#pragma unroll
    for (int i = 0; i < 4; ++i) {
      ah[i] = *reinterpret_cast<const bf16x8*>(&Ah[(wr + i * 16 + fr) * LDK + kq]);
      al[i] = *reinterpret_cast<const bf16x8*>(&Al[(wr + i * 16 + fr) * LDK + kq]);
    }
#pragma unroll
    for (int j = 0; j < 2; ++j)
      bh[j] = *reinterpret_cast<const bf16x8*>(&Bh[(wc + j * 16 + fr) * LDK + kq]);
#pragma unroll
    for (int i = 0; i < 4; ++i)
#pragma unroll
      for (int j = 0; j < 2; ++j) {
        acc[i][j] = __builtin_amdgcn_mfma_f32_16x16x32_bf16(ah[i], bh[j], acc[i][j], 0, 0, 0);
        acc[i][j] = __builtin_amdgcn_mfma_f32_16x16x32_bf16(al[i], bh[j], acc[i][j], 0, 0, 0);
      }
  }

  const int fr = lane & 15;
  const int rg = (lane >> 4) * 4;
#pragma unroll
  for (int i = 0; i < 4; ++i)
#pragma unroll
    for (int j = 0; j < 2; ++j) {
      const int c = bcol + wc + j * 16 + fr;
#pragma unroll
      for (int r = 0; r < 4; ++r) {
        const int rl = brow + wr + i * 16 + rg + r;
        out[(size_t)map_row(rl, t0) * D_ + c] = acc[i][j][r];
      }
    }
}

}  // namespace

extern "C" void kernel_launch(void* const* d_in, const int* in_sizes, int n_in,
                              void* d_out, int out_size, void* d_ws,
                              size_t ws_size, hipStream_t stream) {
  const float* x = (const float*)d_in[0];
  const float* Wg = (const float*)d_in[1];
  const float* Wu = (const float*)d_in[2];
  const float* Wd = (const float*)d_in[3];
  const float* theta = (const float*)d_in[4];
  float* out = (float*)d_out;

  // ws layout (~84 MB)
  char* ws = (char*)d_ws;
  const size_t wu_b = (size_t)F_ * D_ * 2;            // 8.39 MB
  unsigned short* Wu_hi = (unsigned short*)ws;
  unsigned short* Wd_hi = (unsigned short*)(ws + wu_b);
  float* WgT = (float*)(ws + 2 * wu_b);                        // 16.78 MB
  char* xbase = ws + 2 * wu_b + (size_t)F_ * D_ * 4;
  unsigned short* Xh = (unsigned short*)xbase;                 // 4.19 MB
  unsigned short* Xl = (unsigned short*)(xbase + (size_t)MC * D_ * 2);
  char* gbase = xbase + (size_t)MC * D_ * 4;
  float* G = (float*)gbase;                                    // 33.55 MB
  unsigned short* Hh = (unsigned short*)gbase;                 // overlays G
  unsigned short* Hl = (unsigned short*)(gbase + (size_t)MC * F_ * 2);
  char* s8xt = gbase + (size_t)MC * F_ * 4;                    // 8.39 MB shared
  float* xT = (float*)s8xt;          // alive: transpose_x -> gate
  unsigned char* S8 = (unsigned char*)s8xt;  // alive: scan -> up (disjoint)
  float* state = (float*)(s8xt + (size_t)MC * D_ * 4);         // 64 KB

  const dim3 blk(256);
  hipLaunchKernelGGL(cast_hi, dim3(1024), blk, 0, stream, Wu, Wu_hi,
                     F_ * D_ / 4);
  hipLaunchKernelGGL(cast_hi, dim3(1024), blk, 0, stream, Wd, Wd_hi,
                     D_ * F_ / 4);
  hipLaunchKernelGGL(transpose_wg, dim3(D_ / 32, F_ / 32), blk, 0, stream,
                     Wg, WgT);

  const dim3 g_tx(D_ / 32, MC / 32);     // (32, 64)
  const dim3 g_gt(F_ / 128, MC / 128);   // (32, 16) -> 512 blocks
  const dim3 g_sc(B_ * F_ / 64);         // 256 blocks x 64
  const dim3 g_sx(MC * D_ / 4 / 256);    // 2048 blocks
  const dim3 g_up(F_ / 128, MC / 128);   // (32, 16)
  const dim3 g_dn(D_ / 64, MC / 128);    // (16, 16)

  for (int c = 0; c < NCHUNK; ++c) {
    const int t0 = c * TC;
    hipLaunchKernelGGL(transpose_x, g_tx, blk, 0, stream, x, xT, t0);
    hipLaunchKernelGGL(split_x, g_sx, blk, 0, stream, x, Xh, Xl, t0);
    hipLaunchKernelGGL(gemm_gate_np, g_gt, dim3(512), 0, stream, xT, WgT, G);
    hipLaunchKernelGGL(lif_scan, g_sc, dim3(64), 0, stream, G, S8, state,
                       theta, t0);
    hipLaunchKernelGGL(up_mfma, g_up, blk, 0, stream, Xh, Xl, Wu_hi,
                       S8, Hh, Hl);
    hipLaunchKernelGGL(down_mfma, g_dn, blk, 0, stream, Hh, Hl, Wd_hi,
                       out, t0);
  }
}

// Round 22
// 1509.008 us; speedup vs baseline: 1.2141x; 1.0124x over previous
//
#include <hip/hip_runtime.h>
#include <hip/hip_bf16.h>
#include <math.h>

// LIFGatedRouter: out = (gate * silu(x@Wu^T)) @ Wd^T
// R22: (1) gate GEMM double-buffered at 512 threads — occupancy-neutral this
// time (grid-limited 2 blocks/CU; 64KB LDS still fits 2) — prefetch next
// K-tile before the pk_fma loop so the barrier's vmcnt drain is ~free.
// (2) transpose_x + split_x merged into prep_x (x chunk read once).
// Gate per-element DAG BIT-EXACT (ascending-k IEEE fma chain via
// v_pk_fma_f32, __fadd_rn fold at k=128,...,896 — R13-verified).
// Scan numpy-ufunc unchanged. up/down one-sided-split MFMA unchanged (R21).

namespace {

constexpr int B_ = 4;
constexpr int T_ = 2048;
constexpr int D_ = 1024;
constexpr int F_ = 4096;
constexpr int TC = 512;
constexpr int NCHUNK = T_ / TC;      // 4
constexpr int MC = B_ * TC;          // 2048 chunk-local rows
constexpr int LDK = 40;              // MFMA LDS row stride (bf16), 32+8 pad

typedef __attribute__((ext_vector_type(8))) short bf16x8;
typedef __attribute__((ext_vector_type(4))) float f32x4;
typedef __attribute__((ext_vector_type(2))) float f32x2;

// packed IEEE fma pair: acc.{lo,hi} += a.{lo,hi} * b.lo   (b lo-broadcast)
#define PK_FMA_LO(accv, av, bv)                                         \
  asm("v_pk_fma_f32 %0, %1, %2, %0 op_sel:[0,0,0] op_sel_hi:[1,0,1]"    \
      : "+v"(accv) : "v"(av), "v"(bv))
// packed IEEE fma pair: acc.{lo,hi} += a.{lo,hi} * b.hi   (b hi-broadcast)
#define PK_FMA_HI(accv, av, bv)                                         \
  asm("v_pk_fma_f32 %0, %1, %2, %0 op_sel:[0,1,0] op_sel_hi:[1,1,1]"    \
      : "+v"(accv) : "v"(av), "v"(bv))

__device__ __forceinline__ float silu_f(float u) {
  return u / (1.0f + expf(-u));
}

__device__ __forceinline__ int map_row(int r, int t0) {
  return (r >> 9) * T_ + t0 + (r & (TC - 1));   // TC == 512
}

__device__ __forceinline__ unsigned short bf16_rn(float x) {
  unsigned int u = __float_as_uint(x);
  u += 0x7FFF + ((u >> 16) & 1);
  return (unsigned short)(u >> 16);
}
__device__ __forceinline__ float bf16_f(unsigned short h) {
  unsigned int u = ((unsigned int)h) << 16;
  return __uint_as_float(u);
}

// async global(per-lane addr) -> LDS(wave-uniform base + lane*16)
__device__ __forceinline__ void async_copy16(const float* g, float* l) {
  __builtin_amdgcn_global_load_lds(
      (const __attribute__((address_space(1))) void*)g,
      (__attribute__((address_space(3))) void*)l, 16, 0, 0);
}

// ---------------------------------------------------------------------------
// weight transpose (pure copy — fp-neutral)
// ---------------------------------------------------------------------------
__global__ __launch_bounds__(256)
void transpose_wg(const float* __restrict__ Wg, float* __restrict__ WgT) {
  __shared__ float tile[32][33];
  const int tx = threadIdx.x & 31, ty = threadIdx.x >> 5;  // 32x8
  const int d0 = blockIdx.x * 32, f0 = blockIdx.y * 32;
#pragma unroll
  for (int i = 0; i < 4; ++i)
    tile[ty + i * 8][tx] = Wg[(size_t)(f0 + ty + i * 8) * D_ + d0 + tx];
  __syncthreads();
#pragma unroll
  for (int i = 0; i < 4; ++i)
    WgT[(size_t)(d0 + ty + i * 8) * F_ + f0 + tx] = tile[tx][ty + i * 8];
}

// ---------------------------------------------------------------------------
// prep_x: read x chunk ONCE -> xT (f32, K-major) + Xh/Xl (bf16 hi/lo split).
// 32x32 tile, 256 threads, float4 I/O.
// ---------------------------------------------------------------------------
__global__ __launch_bounds__(256)
void prep_x(const float* __restrict__ x, float* __restrict__ xT,
            unsigned short* __restrict__ Xh, unsigned short* __restrict__ Xl,
            int t0) {
  __shared__ float tile[32][33];
  const int tx = threadIdx.x & 7;    // d-quad 0..7
  const int ty = threadIdx.x >> 3;   // r 0..31
  const int d0 = blockIdx.x * 32, r0 = blockIdx.y * 32;

  const float4 v = *reinterpret_cast<const float4*>(
      &x[(size_t)map_row(r0 + ty, t0) * D_ + d0 + tx * 4]);
  // bf16 split (row-major, coalesced ushort4)
  ushort4 h, l;
  h.x = bf16_rn(v.x); l.x = bf16_rn(v.x - bf16_f(h.x));
  h.y = bf16_rn(v.y); l.y = bf16_rn(v.y - bf16_f(h.y));
  h.z = bf16_rn(v.z); l.z = bf16_rn(v.z - bf16_f(h.z));
  h.w = bf16_rn(v.w); l.w = bf16_rn(v.w - bf16_f(h.w));
  *reinterpret_cast<ushort4*>(&Xh[(size_t)(r0 + ty) * D_ + d0 + tx * 4]) = h;
  *reinterpret_cast<ushort4*>(&Xl[(size_t)(r0 + ty) * D_ + d0 + tx * 4]) = l;
  // transpose via LDS
  tile[ty][tx * 4 + 0] = v.x;
  tile[ty][tx * 4 + 1] = v.y;
  tile[ty][tx * 4 + 2] = v.z;
  tile[ty][tx * 4 + 3] = v.w;
  __syncthreads();
  float4 w;
  w.x = tile[tx * 4 + 0][ty];
  w.y = tile[tx * 4 + 1][ty];
  w.z = tile[tx * 4 + 2][ty];
  w.w = tile[tx * 4 + 3][ty];
  *reinterpret_cast<float4*>(&xT[(size_t)(d0 + ty) * MC + r0 + tx * 4]) = w;
}

// ---------------------------------------------------------------------------
// K1: gate GEMM — bit-exact DAG; 128x128 tile, 512 threads (8 waves),
// 8x4/thread, BK=32, DOUBLE-BUFFERED global_load_lds staging (prefetch next
// tile before compute), v_pk_fma_f32 inner loop, one barrier per tile.
// ---------------------------------------------------------------------------
#pragma clang fp contract(off)
__global__ __launch_bounds__(512)
void gemm_gate_np(const float* __restrict__ xT, const float* __restrict__ WgT,
                  float* __restrict__ G) {
  __shared__ float As[2][32 * 128];
  __shared__ float Bs[2][32 * 128];
  const int tid = threadIdx.x;
  const int lane = tid & 63;
  const int w = tid >> 6;          // wave id 0..7
  const int tx = tid & 31;         // N: 32*4 = 128
  const int ty = tid >> 5;         // M: 16*8 = 128
  const int row0 = blockIdx.y * 128;
  const int col0 = blockIdx.x * 128;

  f32x2 accP[4][4];   // [row-pair][col]
  f32x2 csumP[4][4];
#pragma unroll
  for (int i = 0; i < 4; ++i)
#pragma unroll
    for (int j = 0; j < 4; ++j) {
      accP[i][j] = (f32x2)0.0f;
      csumP[i][j] = (f32x2)0.0f;
    }

  const int a_off = (tid >> 6) * 2;            // wave-uniform
  const int lr = (lane & 31) * 4;
  const int lh = lane >> 5;

  // stage K-tile kt32 into buffer buf
  auto stage = [&](int kt32, int buf) {
    const int kt = kt32 * 32;
#pragma unroll
    for (int t = 0; t < 2; ++t) {
      const int ii = a_off + t;                // 0..15 across 8 waves
      const int kr = kt + ii * 2 + lh;
      async_copy16(&xT[(size_t)kr * MC + row0 + lr], &As[buf][ii * 256]);
    }
#pragma unroll
    for (int t = 0; t < 2; ++t) {
      const int ii = a_off + t;
      const int kr = kt + ii * 2 + lh;
      async_copy16(&WgT[(size_t)kr * F_ + col0 + lr], &Bs[buf][ii * 256]);
    }
  };

  stage(0, 0);
  __syncthreads();   // drain prologue
  int cur = 0;

  for (int kt32 = 0; kt32 < 32; ++kt32) {
    if (kt32 != 0 && (kt32 & 3) == 0) {   // fold at k = 128,256,...,896
#pragma unroll
      for (int i = 0; i < 4; ++i)
#pragma unroll
        for (int j = 0; j < 4; ++j) {
          csumP[i][j].x = __fadd_rn(csumP[i][j].x, accP[i][j].x);
          csumP[i][j].y = __fadd_rn(csumP[i][j].y, accP[i][j].y);
          accP[i][j] = (f32x2)0.0f;
        }
    }
    if (kt32 + 1 < 32) stage(kt32 + 1, cur ^ 1);   // prefetch next tile
#pragma unroll
    for (int kk = 0; kk < 32; ++kk) {   // ascending k
      const float4 a0 = *reinterpret_cast<const float4*>(&As[cur][kk * 128 + ty * 8]);
      const float4 a1 = *reinterpret_cast<const float4*>(&As[cur][kk * 128 + ty * 8 + 4]);
      const float4 b0 = *reinterpret_cast<const float4*>(&Bs[cur][kk * 128 + tx * 4]);
      f32x2 ap[4];
      ap[0] = (f32x2){a0.x, a0.y};
      ap[1] = (f32x2){a0.z, a0.w};
      ap[2] = (f32x2){a1.x, a1.y};
      ap[3] = (f32x2){a1.z, a1.w};
      const f32x2 bp0 = (f32x2){b0.x, b0.y};
      const f32x2 bp1 = (f32x2){b0.z, b0.w};
#pragma unroll
      for (int ip = 0; ip < 4; ++ip) {
        PK_FMA_LO(accP[ip][0], ap[ip], bp0);   // col 0: b0.x
        PK_FMA_HI(accP[ip][1], ap[ip], bp0);   // col 1: b0.y
        PK_FMA_LO(accP[ip][2], ap[ip], bp1);   // col 2: b0.z
        PK_FMA_HI(accP[ip][3], ap[ip], bp1);   // col 3: b0.w
      }
    }
    __syncthreads();   // prefetch loads landed; prev buffer free
    cur ^= 1;
  }

#pragma unroll
  for (int ip = 0; ip < 4; ++ip) {
#pragma unroll
    for (int h = 0; h < 2; ++h) {
      const int r = row0 + ty * 8 + ip * 2 + h;
      float4 v;
      v.x = __fadd_rn(h ? csumP[ip][0].y : csumP[ip][0].x,
                      h ? accP[ip][0].y : accP[ip][0].x);
      v.y = __fadd_rn(h ? csumP[ip][1].y : csumP[ip][1].x,
                      h ? accP[ip][1].y : accP[ip][1].x);
      v.z = __fadd_rn(h ? csumP[ip][2].y : csumP[ip][2].x,
                      h ? accP[ip][2].y : accP[ip][2].x);
      v.w = __fadd_rn(h ? csumP[ip][3].y : csumP[ip][3].x,
                      h ? accP[ip][3].y : accP[ip][3].x);
      *reinterpret_cast<float4*>(&G[(size_t)r * F_ + col0 + tx * 4]) = v;
    }
  }
}
#pragma clang fp contract(fast)

// ---------------------------------------------------------------------------
// K2: LIF scan — numpy f32 ufunc semantics (bit-exact), batched loads.
// ---------------------------------------------------------------------------
#pragma clang fp contract(off)
__global__ __launch_bounds__(64)
void lif_scan(const float* __restrict__ G, unsigned char* __restrict__ S8,
              float* __restrict__ state, const float* __restrict__ theta,
              int t0) {
  const int j = blockIdx.x * 64 + threadIdx.x;
  const int f = j & (F_ - 1);
  const int b = j >> 12;
  float m = (t0 == 0) ? 0.0f : state[j];
  const float th = theta[f];
  const size_t base = (size_t)b * TC * F_ + f;
  for (int tb = 0; tb < TC; tb += 16) {
    float g[16];
#pragma unroll
    for (int u = 0; u < 16; ++u) g[u] = G[base + (size_t)(tb + u) * F_];
#pragma unroll
    for (int u = 0; u < 16; ++u) {
      const float bm = __fmul_rn(0.8f, m);
      m = __fadd_rn(bm, g[u]);
      const float s = (m >= 1.0f) ? 1.0f : 0.0f;
      const float r = __fmul_rn(th, s);
      m = __fsub_rn(m, r);
      S8[base + (size_t)(tb + u) * F_] = (unsigned char)s;
    }
  }
  state[j] = m;
}
#pragma clang fp contract(fast)

// ---------------------------------------------------------------------------
// cast to bf16 hi only (B-side of one-sided split)
// ---------------------------------------------------------------------------
__global__ __launch_bounds__(256)
void cast_hi(const float* __restrict__ src, unsigned short* __restrict__ hi,
             int n4) {
  int i = blockIdx.x * 256 + threadIdx.x;
  const int stride = gridDim.x * 256;
  for (; i < n4; i += stride) {
    const float4 v = reinterpret_cast<const float4*>(src)[i];
    ushort4 h;
    h.x = bf16_rn(v.x);
    h.y = bf16_rn(v.y);
    h.z = bf16_rn(v.z);
    h.w = bf16_rn(v.w);
    reinterpret_cast<ushort4*>(hi)[i] = h;
  }
}

// ---------------------------------------------------------------------------
// K3: up = x @ Wu^T via one-sided split MFMA ((xh+xl)*Wh, 2 MFMAs);
// epilogue h = spike*silu(up) -> hi/lo. Tile 128x128, wave tile 64x64.
// ---------------------------------------------------------------------------
__global__ __launch_bounds__(256)
void up_mfma(const unsigned short* __restrict__ Xh,
             const unsigned short* __restrict__ Xl,
             const unsigned short* __restrict__ Wh,
             const unsigned char* __restrict__ S8,
             unsigned short* __restrict__ Hh, unsigned short* __restrict__ Hl) {
  __shared__ unsigned short Ah[128 * LDK], Al[128 * LDK];
  __shared__ unsigned short Bh[128 * LDK];
  const int tid = threadIdx.x;
  const int lane = tid & 63;
  const int w = tid >> 6;
  const int wr = (w >> 1) * 64;
  const int wc = (w & 1) * 64;
  const int brow = blockIdx.y * 128;
  const int bcol = blockIdx.x * 128;

  f32x4 acc[4][4];
#pragma unroll
  for (int i = 0; i < 4; ++i)
#pragma unroll
    for (int j = 0; j < 4; ++j) acc[i][j] = (f32x4)0.0f;

  for (int k0 = 0; k0 < D_; k0 += 32) {
    __syncthreads();
#pragma unroll
    for (int s = 0; s < 2; ++s) {
      const int v = tid + s * 256;
      const int row = v >> 2, q = v & 3;
      *reinterpret_cast<uint4*>(&Ah[row * LDK + q * 8]) =
          *reinterpret_cast<const uint4*>(
              &Xh[(size_t)(brow + row) * D_ + k0 + q * 8]);
      *reinterpret_cast<uint4*>(&Al[row * LDK + q * 8]) =
          *reinterpret_cast<const uint4*>(
              &Xl[(size_t)(brow + row) * D_ + k0 + q * 8]);
      *reinterpret_cast<uint4*>(&Bh[row * LDK + q * 8]) =
          *reinterpret_cast<const uint4*>(
              &Wh[(size_t)(bcol + row) * D_ + k0 + q * 8]);
    }
    __syncthreads();
    const int fr = lane & 15;
    const int kq = (lane >> 4) * 8;
    bf16x8 ah[4], al[4], bh[4];
#pragma unroll
    for (int i = 0; i < 4; ++i) {
      ah[i] = *reinterpret_cast<const bf16x8*>(&Ah[(wr + i * 16 + fr) * LDK + kq]);
      al[i] = *reinterpret_cast<const bf16x8*>(&Al[(wr + i * 16 + fr) * LDK + kq]);
      bh[i] = *reinterpret_cast<const bf16x8*>(&Bh[(wc + i * 16 + fr) * LDK + kq]);
    }
#pragma unroll
    for (int i = 0; i < 4; ++i)
#pragma unroll
      for (int j = 0; j < 4; ++j) {
        acc[i][j] = __builtin_amdgcn_mfma_f32_16x16x32_bf16(ah[i], bh[j], acc[i][j], 0, 0, 0);
        acc[i][j] = __builtin_amdgcn_mfma_f32_16x16x32_bf16(al[i], bh[j], acc[i][j], 0, 0, 0);
      }
  }

  const int fr = lane & 15;
  const int rg = (lane >> 4) * 4;
#pragma unroll
  for (int i = 0; i < 4; ++i)
#pragma unroll
    for (int j = 0; j < 4; ++j) {
      const int c = bcol + wc + j * 16 + fr;
#pragma unroll
      for (int r = 0; r < 4; ++r) {
        const int rl = brow + wr + i * 16 + rg + r;
        const float up = acc[i][j][r];
        const float h = S8[(size_t)rl * F_ + c] ? silu_f(up) : 0.0f;
        const unsigned short hh = bf16_rn(h);
        Hh[(size_t)rl * F_ + c] = hh;
        Hl[(size_t)rl * F_ + c] = bf16_rn(h - bf16_f(hh));
      }
    }
}

// ---------------------------------------------------------------------------
// K4: out = h @ Wd^T via one-sided split MFMA ((hh+hl)*Wh, 2 MFMAs).
// Tile 128x64, wave tile 64x32.
// ---------------------------------------------------------------------------
__global__ __launch_bounds__(256)
void down_mfma(const unsigned short* __restrict__ Hh,
               const unsigned short* __restrict__ Hl,
               const unsigned short* __restrict__ Wh,
               float* __restrict__ out, int t0) {
  __shared__ unsigned short Ah[128 * LDK], Al[128 * LDK];
  __shared__ unsigned short Bh[64 * LDK];
  const int tid = threadIdx.x;
  const int lane = tid & 63;
  const int w = tid >> 6;
  const int wr = (w >> 1) * 64;
  const int wc = (w & 1) * 32;
  const int brow = blockIdx.y * 128;
  const int bcol = blockIdx.x * 64;

  f32x4 acc[4][2];
#pragma unroll
  for (int i = 0; i < 4; ++i)
#pragma unroll
    for (int j = 0; j < 2; ++j) acc[i][j] = (f32x4)0.0f;

  for (int k0 = 0; k0 < F_; k0 += 32) {
    __syncthreads();
#pragma unroll
    for (int s = 0; s < 2; ++s) {
      const int v = tid + s * 256;
      const int row = v >> 2, q = v & 3;
      *reinterpret_cast<uint4*>(&Ah[row * LDK + q * 8]) =
          *reinterpret_cast<const uint4*>(
              &Hh[(size_t)(brow + row) * F_ + k0 + q * 8]);
      *reinterpret_cast<uint4*>(&Al[row * LDK + q * 8]) =
          *reinterpret_cast<const uint4*>(
              &Hl[(size_t)(brow + row) * F_ + k0 + q * 8]);
    }
    {
      const int row = tid >> 2, q = tid & 3;
      *reinterpret_cast<uint4*>(&Bh[row * LDK + q * 8]) =
          *reinterpret_cast<const uint4*>(
              &Wh[(size_t)(bcol + row) * F_ + k0 + q * 8]);
    }
    __syncthreads();
    const int fr = lane & 15;
    const int kq = (lane >> 4) * 8;
    bf16x8 ah[4], al[4], bh[2];
#pragma unroll
    for (int i = 0; i < 4; ++i) {
      ah[i] = *reinterpret_cast<const bf16x8*>(&Ah[(wr + i * 16 + fr) * LDK + kq]);
      al[i] = *reinterpret_cast<const bf16x8*>(&Al[(wr + i * 16 + fr) * LDK + kq]);
    }
#pragma unroll
    for (int j = 0; j < 2; ++j)
      bh[j] = *reinterpret_cast<const bf16x8*>(&Bh[(wc + j * 16 + fr) * LDK + kq]);
#pragma unroll
    for (int i = 0; i < 4; ++i)
#pragma unroll
      for (int j = 0; j < 2; ++j) {
        acc[i][j] = __builtin_amdgcn_mfma_f32_16x16x32_bf16(ah[i], bh[j], acc[i][j], 0, 0, 0);
        acc[i][j] = __builtin_amdgcn_mfma_f32_16x16x32_bf16(al[i], bh[j], acc[i][j], 0, 0, 0);
      }
  }

  const int fr = lane & 15;
  const int rg = (lane >> 4) * 4;
#pragma unroll
  for (int i = 0; i < 4; ++i)
#pragma unroll
    for (int j = 0; j < 2; ++j) {
      const int c = bcol + wc + j * 16 + fr;
#pragma unroll
      for (int r = 0; r < 4; ++r) {
        const int rl = brow + wr + i * 16 + rg + r;
        out[(size_t)map_row(rl, t0) * D_ + c] = acc[i][j][r];
      }
    }
}

}  // namespace

extern "C" void kernel_launch(void* const* d_in, const int* in_sizes, int n_in,
                              void* d_out, int out_size, void* d_ws,
                              size_t ws_size, hipStream_t stream) {
  const float* x = (const float*)d_in[0];
  const float* Wg = (const float*)d_in[1];
  const float* Wu = (const float*)d_in[2];
  const float* Wd = (const float*)d_in[3];
  const float* theta = (const float*)d_in[4];
  float* out = (float*)d_out;

  // ws layout (~84 MB)
  char* ws = (char*)d_ws;
  const size_t wu_b = (size_t)F_ * D_ * 2;            // 8.39 MB
  unsigned short* Wu_hi = (unsigned short*)ws;
  unsigned short* Wd_hi = (unsigned short*)(ws + wu_b);
  float* WgT = (float*)(ws + 2 * wu_b);                        // 16.78 MB
  char* xbase = ws + 2 * wu_b + (size_t)F_ * D_ * 4;
  unsigned short* Xh = (unsigned short*)xbase;                 // 4.19 MB
  unsigned short* Xl = (unsigned short*)(xbase + (size_t)MC * D_ * 2);
  char* gbase = xbase + (size_t)MC * D_ * 4;
  float* G = (float*)gbase;                                    // 33.55 MB
  unsigned short* Hh = (unsigned short*)gbase;                 // overlays G
  unsigned short* Hl = (unsigned short*)(gbase + (size_t)MC * F_ * 2);
  char* s8xt = gbase + (size_t)MC * F_ * 4;                    // 8.39 MB shared
  float* xT = (float*)s8xt;          // alive: prep_x -> gate
  unsigned char* S8 = (unsigned char*)s8xt;  // alive: scan -> up (disjoint)
  float* state = (float*)(s8xt + (size_t)MC * D_ * 4);         // 64 KB

  const dim3 blk(256);
  hipLaunchKernelGGL(cast_hi, dim3(1024), blk, 0, stream, Wu, Wu_hi,
                     F_ * D_ / 4);
  hipLaunchKernelGGL(cast_hi, dim3(1024), blk, 0, stream, Wd, Wd_hi,
                     D_ * F_ / 4);
  hipLaunchKernelGGL(transpose_wg, dim3(D_ / 32, F_ / 32), blk, 0, stream,
                     Wg, WgT);

  const dim3 g_px(D_ / 32, MC / 32);     // (32, 64)
  const dim3 g_gt(F_ / 128, MC / 128);   // (32, 16) -> 512 blocks
  const dim3 g_sc(B_ * F_ / 64);         // 256 blocks x 64
  const dim3 g_up(F_ / 128, MC / 128);   // (32, 16)
  const dim3 g_dn(D_ / 64, MC / 128);    // (16, 16)

  for (int c = 0; c < NCHUNK; ++c) {
    const int t0 = c * TC;
    hipLaunchKernelGGL(prep_x, g_px, blk, 0, stream, x, xT, Xh, Xl, t0);
    hipLaunchKernelGGL(gemm_gate_np, g_gt, dim3(512), 0, stream, xT, WgT, G);
    hipLaunchKernelGGL(lif_scan, g_sc, dim3(64), 0, stream, G, S8, state,
                       theta, t0);
    hipLaunchKernelGGL(up_mfma, g_up, blk, 0, stream, Xh, Xl, Wu_hi,
                       S8, Hh, Hl);
    hipLaunchKernelGGL(down_mfma, g_dn, blk, 0, stream, Hh, Hl, Wd_hi,
                       out, t0);
  }
}

// Round 23
// 1380.145 us; speedup vs baseline: 1.3275x; 1.0934x over previous
//
#include <hip/hip_runtime.h>
#include <hip/hip_bf16.h>
#include <math.h>

// LIFGatedRouter: out = (gate * silu(x@Wu^T)) @ Wd^T
// R23: h stored as SINGLE bf16 (dropped Hl; error ~2e-3 << margin) ->
// down GEMM is pure hi*hi (1 MFMA per acc per K-step, half the staging).
// up = (xh+xl)*Wh (2 MFMAs, R21). Gate GEMM bit-exact DAG via v_pk_fma_f32
// (128x128, 8 waves, dbuf global_load_lds — R22). Scan numpy-ufunc exact.

namespace {

constexpr int B_ = 4;
constexpr int T_ = 2048;
constexpr int D_ = 1024;
constexpr int F_ = 4096;
constexpr int TC = 512;
constexpr int NCHUNK = T_ / TC;      // 4
constexpr int MC = B_ * TC;          // 2048 chunk-local rows
constexpr int LDK = 40;              // MFMA LDS row stride (bf16), 32+8 pad

typedef __attribute__((ext_vector_type(8))) short bf16x8;
typedef __attribute__((ext_vector_type(4))) float f32x4;
typedef __attribute__((ext_vector_type(2))) float f32x2;

// packed IEEE fma pair: acc.{lo,hi} += a.{lo,hi} * b.lo   (b lo-broadcast)
#define PK_FMA_LO(accv, av, bv)                                         \
  asm("v_pk_fma_f32 %0, %1, %2, %0 op_sel:[0,0,0] op_sel_hi:[1,0,1]"    \
      : "+v"(accv) : "v"(av), "v"(bv))
// packed IEEE fma pair: acc.{lo,hi} += a.{lo,hi} * b.hi   (b hi-broadcast)
#define PK_FMA_HI(accv, av, bv)                                         \
  asm("v_pk_fma_f32 %0, %1, %2, %0 op_sel:[0,1,0] op_sel_hi:[1,1,1]"    \
      : "+v"(accv) : "v"(av), "v"(bv))

__device__ __forceinline__ float silu_f(float u) {
  return u / (1.0f + expf(-u));
}

__device__ __forceinline__ int map_row(int r, int t0) {
  return (r >> 9) * T_ + t0 + (r & (TC - 1));   // TC == 512
}

__device__ __forceinline__ unsigned short bf16_rn(float x) {
  unsigned int u = __float_as_uint(x);
  u += 0x7FFF + ((u >> 16) & 1);
  return (unsigned short)(u >> 16);
}
__device__ __forceinline__ float bf16_f(unsigned short h) {
  unsigned int u = ((unsigned int)h) << 16;
  return __uint_as_float(u);
}

// async global(per-lane addr) -> LDS(wave-uniform base + lane*16)
__device__ __forceinline__ void async_copy16(const float* g, float* l) {
  __builtin_amdgcn_global_load_lds(
      (const __attribute__((address_space(1))) void*)g,
      (__attribute__((address_space(3))) void*)l, 16, 0, 0);
}

// ---------------------------------------------------------------------------
// weight transpose (pure copy — fp-neutral)
// ---------------------------------------------------------------------------
__global__ __launch_bounds__(256)
void transpose_wg(const float* __restrict__ Wg, float* __restrict__ WgT) {
  __shared__ float tile[32][33];
  const int tx = threadIdx.x & 31, ty = threadIdx.x >> 5;  // 32x8
  const int d0 = blockIdx.x * 32, f0 = blockIdx.y * 32;
#pragma unroll
  for (int i = 0; i < 4; ++i)
    tile[ty + i * 8][tx] = Wg[(size_t)(f0 + ty + i * 8) * D_ + d0 + tx];
  __syncthreads();
#pragma unroll
  for (int i = 0; i < 4; ++i)
    WgT[(size_t)(d0 + ty + i * 8) * F_ + f0 + tx] = tile[tx][ty + i * 8];
}

// ---------------------------------------------------------------------------
// prep_x: read x chunk ONCE -> xT (f32, K-major) + Xh/Xl (bf16 hi/lo split).
// ---------------------------------------------------------------------------
__global__ __launch_bounds__(256)
void prep_x(const float* __restrict__ x, float* __restrict__ xT,
            unsigned short* __restrict__ Xh, unsigned short* __restrict__ Xl,
            int t0) {
  __shared__ float tile[32][33];
  const int tx = threadIdx.x & 7;    // d-quad 0..7
  const int ty = threadIdx.x >> 3;   // r 0..31
  const int d0 = blockIdx.x * 32, r0 = blockIdx.y * 32;

  const float4 v = *reinterpret_cast<const float4*>(
      &x[(size_t)map_row(r0 + ty, t0) * D_ + d0 + tx * 4]);
  ushort4 h, l;
  h.x = bf16_rn(v.x); l.x = bf16_rn(v.x - bf16_f(h.x));
  h.y = bf16_rn(v.y); l.y = bf16_rn(v.y - bf16_f(h.y));
  h.z = bf16_rn(v.z); l.z = bf16_rn(v.z - bf16_f(h.z));
  h.w = bf16_rn(v.w); l.w = bf16_rn(v.w - bf16_f(h.w));
  *reinterpret_cast<ushort4*>(&Xh[(size_t)(r0 + ty) * D_ + d0 + tx * 4]) = h;
  *reinterpret_cast<ushort4*>(&Xl[(size_t)(r0 + ty) * D_ + d0 + tx * 4]) = l;
  tile[ty][tx * 4 + 0] = v.x;
  tile[ty][tx * 4 + 1] = v.y;
  tile[ty][tx * 4 + 2] = v.z;
  tile[ty][tx * 4 + 3] = v.w;
  __syncthreads();
  float4 w;
  w.x = tile[tx * 4 + 0][ty];
  w.y = tile[tx * 4 + 1][ty];
  w.z = tile[tx * 4 + 2][ty];
  w.w = tile[tx * 4 + 3][ty];
  *reinterpret_cast<float4*>(&xT[(size_t)(d0 + ty) * MC + r0 + tx * 4]) = w;
}

// ---------------------------------------------------------------------------
// K1: gate GEMM — bit-exact DAG; 128x128 tile, 512 threads (8 waves),
// 8x4/thread, BK=32, dbuf global_load_lds, v_pk_fma_f32 inner loop.
// ---------------------------------------------------------------------------
#pragma clang fp contract(off)
__global__ __launch_bounds__(512)
void gemm_gate_np(const float* __restrict__ xT, const float* __restrict__ WgT,
                  float* __restrict__ G) {
  __shared__ float As[2][32 * 128];
  __shared__ float Bs[2][32 * 128];
  const int tid = threadIdx.x;
  const int lane = tid & 63;
  const int tx = tid & 31;         // N: 32*4 = 128
  const int ty = tid >> 5;         // M: 16*8 = 128
  const int row0 = blockIdx.y * 128;
  const int col0 = blockIdx.x * 128;

  f32x2 accP[4][4];   // [row-pair][col]
  f32x2 csumP[4][4];
#pragma unroll
  for (int i = 0; i < 4; ++i)
#pragma unroll
    for (int j = 0; j < 4; ++j) {
      accP[i][j] = (f32x2)0.0f;
      csumP[i][j] = (f32x2)0.0f;
    }

  const int a_off = (tid >> 6) * 2;            // wave-uniform
  const int lr = (lane & 31) * 4;
  const int lh = lane >> 5;

  auto stage = [&](int kt32, int buf) {
    const int kt = kt32 * 32;
#pragma unroll
    for (int t = 0; t < 2; ++t) {
      const int ii = a_off + t;
      const int kr = kt + ii * 2 + lh;
      async_copy16(&xT[(size_t)kr * MC + row0 + lr], &As[buf][ii * 256]);
    }
#pragma unroll
    for (int t = 0; t < 2; ++t) {
      const int ii = a_off + t;
      const int kr = kt + ii * 2 + lh;
      async_copy16(&WgT[(size_t)kr * F_ + col0 + lr], &Bs[buf][ii * 256]);
    }
  };

  stage(0, 0);
  __syncthreads();
  int cur = 0;

  for (int kt32 = 0; kt32 < 32; ++kt32) {
    if (kt32 != 0 && (kt32 & 3) == 0) {   // fold at k = 128,256,...,896
#pragma unroll
      for (int i = 0; i < 4; ++i)
#pragma unroll
        for (int j = 0; j < 4; ++j) {
          csumP[i][j].x = __fadd_rn(csumP[i][j].x, accP[i][j].x);
          csumP[i][j].y = __fadd_rn(csumP[i][j].y, accP[i][j].y);
          accP[i][j] = (f32x2)0.0f;
        }
    }
    if (kt32 + 1 < 32) stage(kt32 + 1, cur ^ 1);
#pragma unroll
    for (int kk = 0; kk < 32; ++kk) {   // ascending k
      const float4 a0 = *reinterpret_cast<const float4*>(&As[cur][kk * 128 + ty * 8]);
      const float4 a1 = *reinterpret_cast<const float4*>(&As[cur][kk * 128 + ty * 8 + 4]);
      const float4 b0 = *reinterpret_cast<const float4*>(&Bs[cur][kk * 128 + tx * 4]);
      f32x2 ap[4];
      ap[0] = (f32x2){a0.x, a0.y};
      ap[1] = (f32x2){a0.z, a0.w};
      ap[2] = (f32x2){a1.x, a1.y};
      ap[3] = (f32x2){a1.z, a1.w};
      const f32x2 bp0 = (f32x2){b0.x, b0.y};
      const f32x2 bp1 = (f32x2){b0.z, b0.w};
#pragma unroll
      for (int ip = 0; ip < 4; ++ip) {
        PK_FMA_LO(accP[ip][0], ap[ip], bp0);
        PK_FMA_HI(accP[ip][1], ap[ip], bp0);
        PK_FMA_LO(accP[ip][2], ap[ip], bp1);
        PK_FMA_HI(accP[ip][3], ap[ip], bp1);
      }
    }
    __syncthreads();
    cur ^= 1;
  }

#pragma unroll
  for (int ip = 0; ip < 4; ++ip) {
#pragma unroll
    for (int h = 0; h < 2; ++h) {
      const int r = row0 + ty * 8 + ip * 2 + h;
      float4 v;
      v.x = __fadd_rn(h ? csumP[ip][0].y : csumP[ip][0].x,
                      h ? accP[ip][0].y : accP[ip][0].x);
      v.y = __fadd_rn(h ? csumP[ip][1].y : csumP[ip][1].x,
                      h ? accP[ip][1].y : accP[ip][1].x);
      v.z = __fadd_rn(h ? csumP[ip][2].y : csumP[ip][2].x,
                      h ? accP[ip][2].y : accP[ip][2].x);
      v.w = __fadd_rn(h ? csumP[ip][3].y : csumP[ip][3].x,
                      h ? accP[ip][3].y : accP[ip][3].x);
      *reinterpret_cast<float4*>(&G[(size_t)r * F_ + col0 + tx * 4]) = v;
    }
  }
}
#pragma clang fp contract(fast)

// ---------------------------------------------------------------------------
// K2: LIF scan — numpy f32 ufunc semantics (bit-exact), batched loads.
// ---------------------------------------------------------------------------
#pragma clang fp contract(off)
__global__ __launch_bounds__(64)
void lif_scan(const float* __restrict__ G, unsigned char* __restrict__ S8,
              float* __restrict__ state, const float* __restrict__ theta,
              int t0) {
  const int j = blockIdx.x * 64 + threadIdx.x;
  const int f = j & (F_ - 1);
  const int b = j >> 12;
  float m = (t0 == 0) ? 0.0f : state[j];
  const float th = theta[f];
  const size_t base = (size_t)b * TC * F_ + f;
  for (int tb = 0; tb < TC; tb += 16) {
    float g[16];
#pragma unroll
    for (int u = 0; u < 16; ++u) g[u] = G[base + (size_t)(tb + u) * F_];
#pragma unroll
    for (int u = 0; u < 16; ++u) {
      const float bm = __fmul_rn(0.8f, m);
      m = __fadd_rn(bm, g[u]);
      const float s = (m >= 1.0f) ? 1.0f : 0.0f;
      const float r = __fmul_rn(th, s);
      m = __fsub_rn(m, r);
      S8[base + (size_t)(tb + u) * F_] = (unsigned char)s;
    }
  }
  state[j] = m;
}
#pragma clang fp contract(fast)

// ---------------------------------------------------------------------------
// cast to bf16 hi only (B-side of one-sided split)
// ---------------------------------------------------------------------------
__global__ __launch_bounds__(256)
void cast_hi(const float* __restrict__ src, unsigned short* __restrict__ hi,
             int n4) {
  int i = blockIdx.x * 256 + threadIdx.x;
  const int stride = gridDim.x * 256;
  for (; i < n4; i += stride) {
    const float4 v = reinterpret_cast<const float4*>(src)[i];
    ushort4 h;
    h.x = bf16_rn(v.x);
    h.y = bf16_rn(v.y);
    h.z = bf16_rn(v.z);
    h.w = bf16_rn(v.w);
    reinterpret_cast<ushort4*>(hi)[i] = h;
  }
}

// ---------------------------------------------------------------------------
// K3: up = x @ Wu^T via one-sided split MFMA ((xh+xl)*Wh, 2 MFMAs);
// epilogue h = spike*silu(up) -> SINGLE bf16. Tile 128x128, wave tile 64x64.
// ---------------------------------------------------------------------------
__global__ __launch_bounds__(256)
void up_mfma(const unsigned short* __restrict__ Xh,
             const unsigned short* __restrict__ Xl,
             const unsigned short* __restrict__ Wh,
             const unsigned char* __restrict__ S8,
             unsigned short* __restrict__ Hb) {
  __shared__ unsigned short Ah[128 * LDK], Al[128 * LDK];
  __shared__ unsigned short Bh[128 * LDK];
  const int tid = threadIdx.x;
  const int lane = tid & 63;
  const int w = tid >> 6;
  const int wr = (w >> 1) * 64;
  const int wc = (w & 1) * 64;
  const int brow = blockIdx.y * 128;
  const int bcol = blockIdx.x * 128;

  f32x4 acc[4][4];
#pragma unroll
  for (int i = 0; i < 4; ++i)
#pragma unroll
    for (int j = 0; j < 4; ++j) acc[i][j] = (f32x4)0.0f;

  for (int k0 = 0; k0 < D_; k0 += 32) {
    __syncthreads();
#pragma unroll
    for (int s = 0; s < 2; ++s) {
      const int v = tid + s * 256;
      const int row = v >> 2, q = v & 3;
      *reinterpret_cast<uint4*>(&Ah[row * LDK + q * 8]) =
          *reinterpret_cast<const uint4*>(
              &Xh[(size_t)(brow + row) * D_ + k0 + q * 8]);
      *reinterpret_cast<uint4*>(&Al[row * LDK + q * 8]) =
          *reinterpret_cast<const uint4*>(
              &Xl[(size_t)(brow + row) * D_ + k0 + q * 8]);
      *reinterpret_cast<uint4*>(&Bh[row * LDK + q * 8]) =
          *reinterpret_cast<const uint4*>(
              &Wh[(size_t)(bcol + row) * D_ + k0 + q * 8]);
    }
    __syncthreads();
    const int fr = lane & 15;
    const int kq = (lane >> 4) * 8;
    bf16x8 ah[4], al[4], bh[4];
#pragma unroll
    for (int i = 0; i < 4; ++i) {
      ah[i] = *reinterpret_cast<const bf16x8*>(&Ah[(wr + i * 16 + fr) * LDK + kq]);
      al[i] = *reinterpret_cast<const bf16x8*>(&Al[(wr + i * 16 + fr) * LDK + kq]);
      bh[i] = *reinterpret_cast<const bf16x8*>(&Bh[(wc + i * 16 + fr) * LDK + kq]);
    }
#pragma unroll
    for (int i = 0; i < 4; ++i)
#pragma unroll
      for (int j = 0; j < 4; ++j) {
        acc[i][j] = __builtin_amdgcn_mfma_f32_16x16x32_bf16(ah[i], bh[j], acc[i][j], 0, 0, 0);
        acc[i][j] = __builtin_amdgcn_mfma_f32_16x16x32_bf16(al[i], bh[j], acc[i][j], 0, 0, 0);
      }
  }

  const int fr = lane & 15;
  const int rg = (lane >> 4) * 4;
#pragma unroll
  for (int i = 0; i < 4; ++i)
#pragma unroll
    for (int j = 0; j < 4; ++j) {
      const int c = bcol + wc + j * 16 + fr;
#pragma unroll
      for (int r = 0; r < 4; ++r) {
        const int rl = brow + wr + i * 16 + rg + r;
        const float up = acc[i][j][r];
        const float h = S8[(size_t)rl * F_ + c] ? silu_f(up) : 0.0f;
        Hb[(size_t)rl * F_ + c] = bf16_rn(h);
      }
    }
}

// ---------------------------------------------------------------------------
// K4: out = h @ Wd^T, pure hi*hi MFMA (1 per acc per K-step).
// Tile 128x64, wave tile 64x32.
// ---------------------------------------------------------------------------
__global__ __launch_bounds__(256)
void down_mfma(const unsigned short* __restrict__ Hb,
               const unsigned short* __restrict__ Wh,
               float* __restrict__ out, int t0) {
  __shared__ unsigned short Ah[128 * LDK];
  __shared__ unsigned short Bh[64 * LDK];
  const int tid = threadIdx.x;
  const int lane = tid & 63;
  const int w = tid >> 6;
  const int wr = (w >> 1) * 64;
  const int wc = (w & 1) * 32;
  const int brow = blockIdx.y * 128;
  const int bcol = blockIdx.x * 64;

  f32x4 acc[4][2];
#pragma unroll
  for (int i = 0; i < 4; ++i)
#pragma unroll
    for (int j = 0; j < 2; ++j) acc[i][j] = (f32x4)0.0f;

  for (int k0 = 0; k0 < F_; k0 += 32) {
    __syncthreads();
    {
      const int row = tid >> 1, q = tid & 1;     // 128 rows x 2 halves
      *reinterpret_cast<uint4*>(&Ah[row * LDK + q * 16]) =
          *reinterpret_cast<const uint4*>(
              &Hb[(size_t)(brow + row) * F_ + k0 + q * 16]);
      *reinterpret_cast<uint4*>(&Ah[row * LDK + q * 16 + 8]) =
          *reinterpret_cast<const uint4*>(
              &Hb[(size_t)(brow + row) * F_ + k0 + q * 16 + 8]);
    }
    {
      const int row = tid >> 2, q = tid & 3;     // 64 rows x 4 q
      *reinterpret_cast<uint4*>(&Bh[row * LDK + q * 8]) =
          *reinterpret_cast<const uint4*>(
              &Wh[(size_t)(bcol + row) * F_ + k0 + q * 8]);
    }
    __syncthreads();
    const int fr = lane & 15;
    const int kq = (lane >> 4) * 8;
    bf16x8 ah[4], bh[2];
#pragma unroll
    for (int i = 0; i < 4; ++i)
      ah[i] = *reinterpret_cast<const bf16x8*>(&Ah[(wr + i * 16 + fr) * LDK + kq]);
#pragma unroll
    for (int j = 0; j < 2; ++j)
      bh[j] = *reinterpret_cast<const bf16x8*>(&Bh[(wc + j * 16 + fr) * LDK + kq]);
#pragma unroll
    for (int i = 0; i < 4; ++i)
#pragma unroll
      for (int j = 0; j < 2; ++j)
        acc[i][j] = __builtin_amdgcn_mfma_f32_16x16x32_bf16(ah[i], bh[j], acc[i][j], 0, 0, 0);
  }

  const int fr = lane & 15;
  const int rg = (lane >> 4) * 4;
#pragma unroll
  for (int i = 0; i < 4; ++i)
#pragma unroll
    for (int j = 0; j < 2; ++j) {
      const int c = bcol + wc + j * 16 + fr;
#pragma unroll
      for (int r = 0; r < 4; ++r) {
        const int rl = brow + wr + i * 16 + rg + r;
        out[(size_t)map_row(rl, t0) * D_ + c] = acc[i][j][r];
      }
    }
}

}  // namespace

extern "C" void kernel_launch(void* const* d_in, const int* in_sizes, int n_in,
                              void* d_out, int out_size, void* d_ws,
                              size_t ws_size, hipStream_t stream) {
  const float* x = (const float*)d_in[0];
  const float* Wg = (const float*)d_in[1];
  const float* Wu = (const float*)d_in[2];
  const float* Wd = (const float*)d_in[3];
  const float* theta = (const float*)d_in[4];
  float* out = (float*)d_out;

  // ws layout (~76 MB)
  char* ws = (char*)d_ws;
  const size_t wu_b = (size_t)F_ * D_ * 2;            // 8.39 MB
  unsigned short* Wu_hi = (unsigned short*)ws;
  unsigned short* Wd_hi = (unsigned short*)(ws + wu_b);
  float* WgT = (float*)(ws + 2 * wu_b);                        // 16.78 MB
  char* xbase = ws + 2 * wu_b + (size_t)F_ * D_ * 4;
  unsigned short* Xh = (unsigned short*)xbase;                 // 4.19 MB
  unsigned short* Xl = (unsigned short*)(xbase + (size_t)MC * D_ * 2);
  char* gbase = xbase + (size_t)MC * D_ * 4;
  float* G = (float*)gbase;                                    // 33.55 MB
  unsigned short* Hb = (unsigned short*)gbase;                 // overlays G
  char* s8xt = gbase + (size_t)MC * F_ * 4;                    // 8.39 MB shared
  float* xT = (float*)s8xt;          // alive: prep_x -> gate
  unsigned char* S8 = (unsigned char*)s8xt;  // alive: scan -> up (disjoint)
  float* state = (float*)(s8xt + (size_t)MC * D_ * 4);         // 64 KB

  const dim3 blk(256);
  hipLaunchKernelGGL(cast_hi, dim3(1024), blk, 0, stream, Wu, Wu_hi,
                     F_ * D_ / 4);
  hipLaunchKernelGGL(cast_hi, dim3(1024), blk, 0, stream, Wd, Wd_hi,
                     D_ * F_ / 4);
  hipLaunchKernelGGL(transpose_wg, dim3(D_ / 32, F_ / 32), blk, 0, stream,
                     Wg, WgT);

  const dim3 g_px(D_ / 32, MC / 32);     // (32, 64)
  const dim3 g_gt(F_ / 128, MC / 128);   // (32, 16) -> 512 blocks
  const dim3 g_sc(B_ * F_ / 64);         // 256 blocks x 64
  const dim3 g_up(F_ / 128, MC / 128);   // (32, 16)
  const dim3 g_dn(D_ / 64, MC / 128);    // (16, 16)

  for (int c = 0; c < NCHUNK; ++c) {
    const int t0 = c * TC;
    hipLaunchKernelGGL(prep_x, g_px, blk, 0, stream, x, xT, Xh, Xl, t0);
    hipLaunchKernelGGL(gemm_gate_np, g_gt, dim3(512), 0, stream, xT, WgT, G);
    hipLaunchKernelGGL(lif_scan, g_sc, dim3(64), 0, stream, G, S8, state,
                       theta, t0);
    hipLaunchKernelGGL(up_mfma, g_up, blk, 0, stream, Xh, Xl, Wu_hi,
                       S8, Hb);
    hipLaunchKernelGGL(down_mfma, g_dn, blk, 0, stream, Hb, Wd_hi,
                       out, t0);
  }
}

// Round 24
// 1323.433 us; speedup vs baseline: 1.3844x; 1.0429x over previous
//
#include <hip/hip_runtime.h>
#include <hip/hip_bf16.h>
#include <math.h>

// LIFGatedRouter: out = (gate * silu(x@Wu^T)) @ Wd^T
// R24: up GEMM now pure hi*hi (dropped Xl; dropped-term error ~2.3e-3 on up,
// ~1.4e-3 on out — margin confirmed by R21/R23 actuals). Both up/down are
// 1-MFMA-per-acc bf16 GEMMs. Gate GEMM bit-exact DAG via v_pk_fma_f32
// (128x128, 8 waves, dbuf global_load_lds — R22). Scan numpy-ufunc exact.

namespace {

constexpr int B_ = 4;
constexpr int T_ = 2048;
constexpr int D_ = 1024;
constexpr int F_ = 4096;
constexpr int TC = 512;
constexpr int NCHUNK = T_ / TC;      // 4
constexpr int MC = B_ * TC;          // 2048 chunk-local rows
constexpr int LDK = 40;              // MFMA LDS row stride (bf16), 32+8 pad

typedef __attribute__((ext_vector_type(8))) short bf16x8;
typedef __attribute__((ext_vector_type(4))) float f32x4;
typedef __attribute__((ext_vector_type(2))) float f32x2;

// packed IEEE fma pair: acc.{lo,hi} += a.{lo,hi} * b.lo   (b lo-broadcast)
#define PK_FMA_LO(accv, av, bv)                                         \
  asm("v_pk_fma_f32 %0, %1, %2, %0 op_sel:[0,0,0] op_sel_hi:[1,0,1]"    \
      : "+v"(accv) : "v"(av), "v"(bv))
// packed IEEE fma pair: acc.{lo,hi} += a.{lo,hi} * b.hi   (b hi-broadcast)
#define PK_FMA_HI(accv, av, bv)                                         \
  asm("v_pk_fma_f32 %0, %1, %2, %0 op_sel:[0,1,0] op_sel_hi:[1,1,1]"    \
      : "+v"(accv) : "v"(av), "v"(bv))

__device__ __forceinline__ float silu_f(float u) {
  return u / (1.0f + expf(-u));
}

__device__ __forceinline__ int map_row(int r, int t0) {
  return (r >> 9) * T_ + t0 + (r & (TC - 1));   // TC == 512
}

__device__ __forceinline__ unsigned short bf16_rn(float x) {
  unsigned int u = __float_as_uint(x);
  u += 0x7FFF + ((u >> 16) & 1);
  return (unsigned short)(u >> 16);
}
__device__ __forceinline__ float bf16_f(unsigned short h) {
  unsigned int u = ((unsigned int)h) << 16;
  return __uint_as_float(u);
}

// async global(per-lane addr) -> LDS(wave-uniform base + lane*16)
__device__ __forceinline__ void async_copy16(const float* g, float* l) {
  __builtin_amdgcn_global_load_lds(
      (const __attribute__((address_space(1))) void*)g,
      (__attribute__((address_space(3))) void*)l, 16, 0, 0);
}

// ---------------------------------------------------------------------------
// weight transpose (pure copy — fp-neutral)
// ---------------------------------------------------------------------------
__global__ __launch_bounds__(256)
void transpose_wg(const float* __restrict__ Wg, float* __restrict__ WgT) {
  __shared__ float tile[32][33];
  const int tx = threadIdx.x & 31, ty = threadIdx.x >> 5;  // 32x8
  const int d0 = blockIdx.x * 32, f0 = blockIdx.y * 32;
#pragma unroll
  for (int i = 0; i < 4; ++i)
    tile[ty + i * 8][tx] = Wg[(size_t)(f0 + ty + i * 8) * D_ + d0 + tx];
  __syncthreads();
#pragma unroll
  for (int i = 0; i < 4; ++i)
    WgT[(size_t)(d0 + ty + i * 8) * F_ + f0 + tx] = tile[tx][ty + i * 8];
}

// ---------------------------------------------------------------------------
// prep_x: read x chunk ONCE -> xT (f32, K-major) + Xh (bf16 hi).
// ---------------------------------------------------------------------------
__global__ __launch_bounds__(256)
void prep_x(const float* __restrict__ x, float* __restrict__ xT,
            unsigned short* __restrict__ Xh, int t0) {
  __shared__ float tile[32][33];
  const int tx = threadIdx.x & 7;    // d-quad 0..7
  const int ty = threadIdx.x >> 3;   // r 0..31
  const int d0 = blockIdx.x * 32, r0 = blockIdx.y * 32;

  const float4 v = *reinterpret_cast<const float4*>(
      &x[(size_t)map_row(r0 + ty, t0) * D_ + d0 + tx * 4]);
  ushort4 h;
  h.x = bf16_rn(v.x);
  h.y = bf16_rn(v.y);
  h.z = bf16_rn(v.z);
  h.w = bf16_rn(v.w);
  *reinterpret_cast<ushort4*>(&Xh[(size_t)(r0 + ty) * D_ + d0 + tx * 4]) = h;
  tile[ty][tx * 4 + 0] = v.x;
  tile[ty][tx * 4 + 1] = v.y;
  tile[ty][tx * 4 + 2] = v.z;
  tile[ty][tx * 4 + 3] = v.w;
  __syncthreads();
  float4 w;
  w.x = tile[tx * 4 + 0][ty];
  w.y = tile[tx * 4 + 1][ty];
  w.z = tile[tx * 4 + 2][ty];
  w.w = tile[tx * 4 + 3][ty];
  *reinterpret_cast<float4*>(&xT[(size_t)(d0 + ty) * MC + r0 + tx * 4]) = w;
}

// ---------------------------------------------------------------------------
// K1: gate GEMM — bit-exact DAG; 128x128 tile, 512 threads (8 waves),
// 8x4/thread, BK=32, dbuf global_load_lds, v_pk_fma_f32 inner loop.
// ---------------------------------------------------------------------------
#pragma clang fp contract(off)
__global__ __launch_bounds__(512)
void gemm_gate_np(const float* __restrict__ xT, const float* __restrict__ WgT,
                  float* __restrict__ G) {
  __shared__ float As[2][32 * 128];
  __shared__ float Bs[2][32 * 128];
  const int tid = threadIdx.x;
  const int lane = tid & 63;
  const int tx = tid & 31;         // N: 32*4 = 128
  const int ty = tid >> 5;         // M: 16*8 = 128
  const int row0 = blockIdx.y * 128;
  const int col0 = blockIdx.x * 128;

  f32x2 accP[4][4];   // [row-pair][col]
  f32x2 csumP[4][4];
#pragma unroll
  for (int i = 0; i < 4; ++i)
#pragma unroll
    for (int j = 0; j < 4; ++j) {
      accP[i][j] = (f32x2)0.0f;
      csumP[i][j] = (f32x2)0.0f;
    }

  const int a_off = (tid >> 6) * 2;            // wave-uniform
  const int lr = (lane & 31) * 4;
  const int lh = lane >> 5;

  auto stage = [&](int kt32, int buf) {
    const int kt = kt32 * 32;
#pragma unroll
    for (int t = 0; t < 2; ++t) {
      const int ii = a_off + t;
      const int kr = kt + ii * 2 + lh;
      async_copy16(&xT[(size_t)kr * MC + row0 + lr], &As[buf][ii * 256]);
    }
#pragma unroll
    for (int t = 0; t < 2; ++t) {
      const int ii = a_off + t;
      const int kr = kt + ii * 2 + lh;
      async_copy16(&WgT[(size_t)kr * F_ + col0 + lr], &Bs[buf][ii * 256]);
    }
  };

  stage(0, 0);
  __syncthreads();
  int cur = 0;

  for (int kt32 = 0; kt32 < 32; ++kt32) {
    if (kt32 != 0 && (kt32 & 3) == 0) {   // fold at k = 128,256,...,896
#pragma unroll
      for (int i = 0; i < 4; ++i)
#pragma unroll
        for (int j = 0; j < 4; ++j) {
          csumP[i][j].x = __fadd_rn(csumP[i][j].x, accP[i][j].x);
          csumP[i][j].y = __fadd_rn(csumP[i][j].y, accP[i][j].y);
          accP[i][j] = (f32x2)0.0f;
        }
    }
    if (kt32 + 1 < 32) stage(kt32 + 1, cur ^ 1);
#pragma unroll
    for (int kk = 0; kk < 32; ++kk) {   // ascending k
      const float4 a0 = *reinterpret_cast<const float4*>(&As[cur][kk * 128 + ty * 8]);
      const float4 a1 = *reinterpret_cast<const float4*>(&As[cur][kk * 128 + ty * 8 + 4]);
      const float4 b0 = *reinterpret_cast<const float4*>(&Bs[cur][kk * 128 + tx * 4]);
      f32x2 ap[4];
      ap[0] = (f32x2){a0.x, a0.y};
      ap[1] = (f32x2){a0.z, a0.w};
      ap[2] = (f32x2){a1.x, a1.y};
      ap[3] = (f32x2){a1.z, a1.w};
      const f32x2 bp0 = (f32x2){b0.x, b0.y};
      const f32x2 bp1 = (f32x2){b0.z, b0.w};
#pragma unroll
      for (int ip = 0; ip < 4; ++ip) {
        PK_FMA_LO(accP[ip][0], ap[ip], bp0);
        PK_FMA_HI(accP[ip][1], ap[ip], bp0);
        PK_FMA_LO(accP[ip][2], ap[ip], bp1);
        PK_FMA_HI(accP[ip][3], ap[ip], bp1);
      }
    }
    __syncthreads();
    cur ^= 1;
  }

#pragma unroll
  for (int ip = 0; ip < 4; ++ip) {
#pragma unroll
    for (int h = 0; h < 2; ++h) {
      const int r = row0 + ty * 8 + ip * 2 + h;
      float4 v;
      v.x = __fadd_rn(h ? csumP[ip][0].y : csumP[ip][0].x,
                      h ? accP[ip][0].y : accP[ip][0].x);
      v.y = __fadd_rn(h ? csumP[ip][1].y : csumP[ip][1].x,
                      h ? accP[ip][1].y : accP[ip][1].x);
      v.z = __fadd_rn(h ? csumP[ip][2].y : csumP[ip][2].x,
                      h ? accP[ip][2].y : accP[ip][2].x);
      v.w = __fadd_rn(h ? csumP[ip][3].y : csumP[ip][3].x,
                      h ? accP[ip][3].y : accP[ip][3].x);
      *reinterpret_cast<float4*>(&G[(size_t)r * F_ + col0 + tx * 4]) = v;
    }
  }
}
#pragma clang fp contract(fast)

// ---------------------------------------------------------------------------
// K2: LIF scan — numpy f32 ufunc semantics (bit-exact), batched loads.
// ---------------------------------------------------------------------------
#pragma clang fp contract(off)
__global__ __launch_bounds__(64)
void lif_scan(const float* __restrict__ G, unsigned char* __restrict__ S8,
              float* __restrict__ state, const float* __restrict__ theta,
              int t0) {
  const int j = blockIdx.x * 64 + threadIdx.x;
  const int f = j & (F_ - 1);
  const int b = j >> 12;
  float m = (t0 == 0) ? 0.0f : state[j];
  const float th = theta[f];
  const size_t base = (size_t)b * TC * F_ + f;
  for (int tb = 0; tb < TC; tb += 16) {
    float g[16];
#pragma unroll
    for (int u = 0; u < 16; ++u) g[u] = G[base + (size_t)(tb + u) * F_];
#pragma unroll
    for (int u = 0; u < 16; ++u) {
      const float bm = __fmul_rn(0.8f, m);
      m = __fadd_rn(bm, g[u]);
      const float s = (m >= 1.0f) ? 1.0f : 0.0f;
      const float r = __fmul_rn(th, s);
      m = __fsub_rn(m, r);
      S8[base + (size_t)(tb + u) * F_] = (unsigned char)s;
    }
  }
  state[j] = m;
}
#pragma clang fp contract(fast)

// ---------------------------------------------------------------------------
// cast to bf16 hi only (weights)
// ---------------------------------------------------------------------------
__global__ __launch_bounds__(256)
void cast_hi(const float* __restrict__ src, unsigned short* __restrict__ hi,
             int n4) {
  int i = blockIdx.x * 256 + threadIdx.x;
  const int stride = gridDim.x * 256;
  for (; i < n4; i += stride) {
    const float4 v = reinterpret_cast<const float4*>(src)[i];
    ushort4 h;
    h.x = bf16_rn(v.x);
    h.y = bf16_rn(v.y);
    h.z = bf16_rn(v.z);
    h.w = bf16_rn(v.w);
    reinterpret_cast<ushort4*>(hi)[i] = h;
  }
}

// ---------------------------------------------------------------------------
// K3: up = xh @ Wh^T, pure hi*hi MFMA (1 per acc per K-step);
// epilogue h = spike*silu(up) -> single bf16. Tile 128x128, wave 64x64.
// ---------------------------------------------------------------------------
__global__ __launch_bounds__(256)
void up_mfma(const unsigned short* __restrict__ Xh,
             const unsigned short* __restrict__ Wh,
             const unsigned char* __restrict__ S8,
             unsigned short* __restrict__ Hb) {
  __shared__ unsigned short Ah[128 * LDK];
  __shared__ unsigned short Bh[128 * LDK];
  const int tid = threadIdx.x;
  const int lane = tid & 63;
  const int w = tid >> 6;
  const int wr = (w >> 1) * 64;
  const int wc = (w & 1) * 64;
  const int brow = blockIdx.y * 128;
  const int bcol = blockIdx.x * 128;

  f32x4 acc[4][4];
#pragma unroll
  for (int i = 0; i < 4; ++i)
#pragma unroll
    for (int j = 0; j < 4; ++j) acc[i][j] = (f32x4)0.0f;

  for (int k0 = 0; k0 < D_; k0 += 32) {
    __syncthreads();
#pragma unroll
    for (int s = 0; s < 2; ++s) {
      const int v = tid + s * 256;
      const int row = v >> 2, q = v & 3;
      *reinterpret_cast<uint4*>(&Ah[row * LDK + q * 8]) =
          *reinterpret_cast<const uint4*>(
              &Xh[(size_t)(brow + row) * D_ + k0 + q * 8]);
      *reinterpret_cast<uint4*>(&Bh[row * LDK + q * 8]) =
          *reinterpret_cast<const uint4*>(
              &Wh[(size_t)(bcol + row) * D_ + k0 + q * 8]);
    }
    __syncthreads();
    const int fr = lane & 15;
    const int kq = (lane >> 4) * 8;
    bf16x8 ah[4], bh[4];
#pragma unroll
    for (int i = 0; i < 4; ++i) {
      ah[i] = *reinterpret_cast<const bf16x8*>(&Ah[(wr + i * 16 + fr) * LDK + kq]);
      bh[i] = *reinterpret_cast<const bf16x8*>(&Bh[(wc + i * 16 + fr) * LDK + kq]);
    }
#pragma unroll
    for (int i = 0; i < 4; ++i)
#pragma unroll
      for (int j = 0; j < 4; ++j)
        acc[i][j] = __builtin_amdgcn_mfma_f32_16x16x32_bf16(ah[i], bh[j], acc[i][j], 0, 0, 0);
  }

  const int fr = lane & 15;
  const int rg = (lane >> 4) * 4;
#pragma unroll
  for (int i = 0; i < 4; ++i)
#pragma unroll
    for (int j = 0; j < 4; ++j) {
      const int c = bcol + wc + j * 16 + fr;
#pragma unroll
      for (int r = 0; r < 4; ++r) {
        const int rl = brow + wr + i * 16 + rg + r;
        const float up = acc[i][j][r];
        const float h = S8[(size_t)rl * F_ + c] ? silu_f(up) : 0.0f;
        Hb[(size_t)rl * F_ + c] = bf16_rn(h);
      }
    }
}

// ---------------------------------------------------------------------------
// K4: out = h @ Wd^T, pure hi*hi MFMA. Tile 128x64, wave tile 64x32.
// ---------------------------------------------------------------------------
__global__ __launch_bounds__(256)
void down_mfma(const unsigned short* __restrict__ Hb,
               const unsigned short* __restrict__ Wh,
               float* __restrict__ out, int t0) {
  __shared__ unsigned short Ah[128 * LDK];
  __shared__ unsigned short Bh[64 * LDK];
  const int tid = threadIdx.x;
  const int lane = tid & 63;
  const int w = tid >> 6;
  const int wr = (w >> 1) * 64;
  const int wc = (w & 1) * 32;
  const int brow = blockIdx.y * 128;
  const int bcol = blockIdx.x * 64;

  f32x4 acc[4][2];
#pragma unroll
  for (int i = 0; i < 4; ++i)
#pragma unroll
    for (int j = 0; j < 2; ++j) acc[i][j] = (f32x4)0.0f;

  for (int k0 = 0; k0 < F_; k0 += 32) {
    __syncthreads();
    {
      const int row = tid >> 1, q = tid & 1;     // 128 rows x 2 halves
      *reinterpret_cast<uint4*>(&Ah[row * LDK + q * 16]) =
          *reinterpret_cast<const uint4*>(
              &Hb[(size_t)(brow + row) * F_ + k0 + q * 16]);
      *reinterpret_cast<uint4*>(&Ah[row * LDK + q * 16 + 8]) =
          *reinterpret_cast<const uint4*>(
              &Hb[(size_t)(brow + row) * F_ + k0 + q * 16 + 8]);
    }
    {
      const int row = tid >> 2, q = tid & 3;     // 64 rows x 4 q
      *reinterpret_cast<uint4*>(&Bh[row * LDK + q * 8]) =
          *reinterpret_cast<const uint4*>(
              &Wh[(size_t)(bcol + row) * F_ + k0 + q * 8]);
    }
    __syncthreads();
    const int fr = lane & 15;
    const int kq = (lane >> 4) * 8;
    bf16x8 ah[4], bh[2];
#pragma unroll
    for (int i = 0; i < 4; ++i)
      ah[i] = *reinterpret_cast<const bf16x8*>(&Ah[(wr + i * 16 + fr) * LDK + kq]);
#pragma unroll
    for (int j = 0; j < 2; ++j)
      bh[j] = *reinterpret_cast<const bf16x8*>(&Bh[(wc + j * 16 + fr) * LDK + kq]);
#pragma unroll
    for (int i = 0; i < 4; ++i)
#pragma unroll
      for (int j = 0; j < 2; ++j)
        acc[i][j] = __builtin_amdgcn_mfma_f32_16x16x32_bf16(ah[i], bh[j], acc[i][j], 0, 0, 0);
  }

  const int fr = lane & 15;
  const int rg = (lane >> 4) * 4;
#pragma unroll
  for (int i = 0; i < 4; ++i)
#pragma unroll
    for (int j = 0; j < 2; ++j) {
      const int c = bcol + wc + j * 16 + fr;
#pragma unroll
      for (int r = 0; r < 4; ++r) {
        const int rl = brow + wr + i * 16 + rg + r;
        out[(size_t)map_row(rl, t0) * D_ + c] = acc[i][j][r];
      }
    }
}

}  // namespace

extern "C" void kernel_launch(void* const* d_in, const int* in_sizes, int n_in,
                              void* d_out, int out_size, void* d_ws,
                              size_t ws_size, hipStream_t stream) {
  const float* x = (const float*)d_in[0];
  const float* Wg = (const float*)d_in[1];
  const float* Wu = (const float*)d_in[2];
  const float* Wd = (const float*)d_in[3];
  const float* theta = (const float*)d_in[4];
  float* out = (float*)d_out;

  // ws layout (~72 MB)
  char* ws = (char*)d_ws;
  const size_t wu_b = (size_t)F_ * D_ * 2;            // 8.39 MB
  unsigned short* Wu_hi = (unsigned short*)ws;
  unsigned short* Wd_hi = (unsigned short*)(ws + wu_b);
  float* WgT = (float*)(ws + 2 * wu_b);                        // 16.78 MB
  char* xbase = ws + 2 * wu_b + (size_t)F_ * D_ * 4;
  unsigned short* Xh = (unsigned short*)xbase;                 // 4.19 MB
  char* gbase = xbase + (size_t)MC * D_ * 2;
  float* G = (float*)gbase;                                    // 33.55 MB
  unsigned short* Hb = (unsigned short*)gbase;                 // overlays G
  char* s8xt = gbase + (size_t)MC * F_ * 4;                    // 8.39 MB shared
  float* xT = (float*)s8xt;          // alive: prep_x -> gate
  unsigned char* S8 = (unsigned char*)s8xt;  // alive: scan -> up (disjoint)
  float* state = (float*)(s8xt + (size_t)MC * D_ * 4);         // 64 KB

  const dim3 blk(256);
  hipLaunchKernelGGL(cast_hi, dim3(1024), blk, 0, stream, Wu, Wu_hi,
                     F_ * D_ / 4);
  hipLaunchKernelGGL(cast_hi, dim3(1024), blk, 0, stream, Wd, Wd_hi,
                     D_ * F_ / 4);
  hipLaunchKernelGGL(transpose_wg, dim3(D_ / 32, F_ / 32), blk, 0, stream,
                     Wg, WgT);

  const dim3 g_px(D_ / 32, MC / 32);     // (32, 64)
  const dim3 g_gt(F_ / 128, MC / 128);   // (32, 16) -> 512 blocks
  const dim3 g_sc(B_ * F_ / 64);         // 256 blocks x 64
  const dim3 g_up(F_ / 128, MC / 128);   // (32, 16)
  const dim3 g_dn(D_ / 64, MC / 128);    // (16, 16)

  for (int c = 0; c < NCHUNK; ++c) {
    const int t0 = c * TC;
    hipLaunchKernelGGL(prep_x, g_px, blk, 0, stream, x, xT, Xh, t0);
    hipLaunchKernelGGL(gemm_gate_np, g_gt, dim3(512), 0, stream, xT, WgT, G);
    hipLaunchKernelGGL(lif_scan, g_sc, dim3(64), 0, stream, G, S8, state,
                       theta, t0);
    hipLaunchKernelGGL(up_mfma, g_up, blk, 0, stream, Xh, Wu_hi, S8, Hb);
    hipLaunchKernelGGL(down_mfma, g_dn, blk, 0, stream, Hb, Wd_hi, out, t0);
  }
}

// Round 26
// 1258.562 us; speedup vs baseline: 1.4557x; 1.0515x over previous
//
#include <hip/hip_runtime.h>
#include <hip/hip_bf16.h>
#include <math.h>

// LIFGatedRouter: out = (gate * silu(x@Wu^T)) @ Wd^T
// R26: R25 (BK=64 up/down, scan batch-32) with the staging bug fixed:
// 128-row x 64-k tiles need 1024 uint4 chunks -> s-loop must run 4x256,
// not 2x256 (R25 left rows 64..127 uninitialized -> NaN).
// Numerics identical to R24 (pure hi*hi bf16 up/down; gate bit-exact
// pk_fma DAG; scan numpy-ufunc exact).

namespace {

constexpr int B_ = 4;
constexpr int T_ = 2048;
constexpr int D_ = 1024;
constexpr int F_ = 4096;
constexpr int TC = 512;
constexpr int NCHUNK = T_ / TC;      // 4
constexpr int MC = B_ * TC;          // 2048 chunk-local rows
constexpr int LDK2 = 72;             // BK=64 LDS row stride (bf16), 64+8 pad

typedef __attribute__((ext_vector_type(8))) short bf16x8;
typedef __attribute__((ext_vector_type(4))) float f32x4;
typedef __attribute__((ext_vector_type(2))) float f32x2;

// packed IEEE fma pair: acc.{lo,hi} += a.{lo,hi} * b.lo   (b lo-broadcast)
#define PK_FMA_LO(accv, av, bv)                                         \
  asm("v_pk_fma_f32 %0, %1, %2, %0 op_sel:[0,0,0] op_sel_hi:[1,0,1]"    \
      : "+v"(accv) : "v"(av), "v"(bv))
// packed IEEE fma pair: acc.{lo,hi} += a.{lo,hi} * b.hi   (b hi-broadcast)
#define PK_FMA_HI(accv, av, bv)                                         \
  asm("v_pk_fma_f32 %0, %1, %2, %0 op_sel:[0,1,0] op_sel_hi:[1,1,1]"    \
      : "+v"(accv) : "v"(av), "v"(bv))

__device__ __forceinline__ float silu_f(float u) {
  return u / (1.0f + expf(-u));
}

__device__ __forceinline__ int map_row(int r, int t0) {
  return (r >> 9) * T_ + t0 + (r & (TC - 1));   // TC == 512
}

__device__ __forceinline__ unsigned short bf16_rn(float x) {
  unsigned int u = __float_as_uint(x);
  u += 0x7FFF + ((u >> 16) & 1);
  return (unsigned short)(u >> 16);
}
__device__ __forceinline__ float bf16_f(unsigned short h) {
  unsigned int u = ((unsigned int)h) << 16;
  return __uint_as_float(u);
}

// async global(per-lane addr) -> LDS(wave-uniform base + lane*16)
__device__ __forceinline__ void async_copy16(const float* g, float* l) {
  __builtin_amdgcn_global_load_lds(
      (const __attribute__((address_space(1))) void*)g,
      (__attribute__((address_space(3))) void*)l, 16, 0, 0);
}

// ---------------------------------------------------------------------------
// weight transpose (pure copy — fp-neutral)
// ---------------------------------------------------------------------------
__global__ __launch_bounds__(256)
void transpose_wg(const float* __restrict__ Wg, float* __restrict__ WgT) {
  __shared__ float tile[32][33];
  const int tx = threadIdx.x & 31, ty = threadIdx.x >> 5;  // 32x8
  const int d0 = blockIdx.x * 32, f0 = blockIdx.y * 32;
#pragma unroll
  for (int i = 0; i < 4; ++i)
    tile[ty + i * 8][tx] = Wg[(size_t)(f0 + ty + i * 8) * D_ + d0 + tx];
  __syncthreads();
#pragma unroll
  for (int i = 0; i < 4; ++i)
    WgT[(size_t)(d0 + ty + i * 8) * F_ + f0 + tx] = tile[tx][ty + i * 8];
}

// ---------------------------------------------------------------------------
// prep_x: read x chunk ONCE -> xT (f32, K-major) + Xh (bf16 hi).
// ---------------------------------------------------------------------------
__global__ __launch_bounds__(256)
void prep_x(const float* __restrict__ x, float* __restrict__ xT,
            unsigned short* __restrict__ Xh, int t0) {
  __shared__ float tile[32][33];
  const int tx = threadIdx.x & 7;    // d-quad 0..7
  const int ty = threadIdx.x >> 3;   // r 0..31
  const int d0 = blockIdx.x * 32, r0 = blockIdx.y * 32;

  const float4 v = *reinterpret_cast<const float4*>(
      &x[(size_t)map_row(r0 + ty, t0) * D_ + d0 + tx * 4]);
  ushort4 h;
  h.x = bf16_rn(v.x);
  h.y = bf16_rn(v.y);
  h.z = bf16_rn(v.z);
  h.w = bf16_rn(v.w);
  *reinterpret_cast<ushort4*>(&Xh[(size_t)(r0 + ty) * D_ + d0 + tx * 4]) = h;
  tile[ty][tx * 4 + 0] = v.x;
  tile[ty][tx * 4 + 1] = v.y;
  tile[ty][tx * 4 + 2] = v.z;
  tile[ty][tx * 4 + 3] = v.w;
  __syncthreads();
  float4 w;
  w.x = tile[tx * 4 + 0][ty];
  w.y = tile[tx * 4 + 1][ty];
  w.z = tile[tx * 4 + 2][ty];
  w.w = tile[tx * 4 + 3][ty];
  *reinterpret_cast<float4*>(&xT[(size_t)(d0 + ty) * MC + r0 + tx * 4]) = w;
}

// ---------------------------------------------------------------------------
// K1: gate GEMM — bit-exact DAG; 128x128 tile, 512 threads (8 waves),
// 8x4/thread, BK=32, dbuf global_load_lds, v_pk_fma_f32 inner loop.
// ---------------------------------------------------------------------------
#pragma clang fp contract(off)
__global__ __launch_bounds__(512)
void gemm_gate_np(const float* __restrict__ xT, const float* __restrict__ WgT,
                  float* __restrict__ G) {
  __shared__ float As[2][32 * 128];
  __shared__ float Bs[2][32 * 128];
  const int tid = threadIdx.x;
  const int lane = tid & 63;
  const int tx = tid & 31;         // N: 32*4 = 128
  const int ty = tid >> 5;         // M: 16*8 = 128
  const int row0 = blockIdx.y * 128;
  const int col0 = blockIdx.x * 128;

  f32x2 accP[4][4];   // [row-pair][col]
  f32x2 csumP[4][4];
#pragma unroll
  for (int i = 0; i < 4; ++i)
#pragma unroll
    for (int j = 0; j < 4; ++j) {
      accP[i][j] = (f32x2)0.0f;
      csumP[i][j] = (f32x2)0.0f;
    }

  const int a_off = (tid >> 6) * 2;            // wave-uniform
  const int lr = (lane & 31) * 4;
  const int lh = lane >> 5;

  auto stage = [&](int kt32, int buf) {
    const int kt = kt32 * 32;
#pragma unroll
    for (int t = 0; t < 2; ++t) {
      const int ii = a_off + t;
      const int kr = kt + ii * 2 + lh;
      async_copy16(&xT[(size_t)kr * MC + row0 + lr], &As[buf][ii * 256]);
    }
#pragma unroll
    for (int t = 0; t < 2; ++t) {
      const int ii = a_off + t;
      const int kr = kt + ii * 2 + lh;
      async_copy16(&WgT[(size_t)kr * F_ + col0 + lr], &Bs[buf][ii * 256]);
    }
  };

  stage(0, 0);
  __syncthreads();
  int cur = 0;

  for (int kt32 = 0; kt32 < 32; ++kt32) {
    if (kt32 != 0 && (kt32 & 3) == 0) {   // fold at k = 128,256,...,896
#pragma unroll
      for (int i = 0; i < 4; ++i)
#pragma unroll
        for (int j = 0; j < 4; ++j) {
          csumP[i][j].x = __fadd_rn(csumP[i][j].x, accP[i][j].x);
          csumP[i][j].y = __fadd_rn(csumP[i][j].y, accP[i][j].y);
          accP[i][j] = (f32x2)0.0f;
        }
    }
    if (kt32 + 1 < 32) stage(kt32 + 1, cur ^ 1);
#pragma unroll
    for (int kk = 0; kk < 32; ++kk) {   // ascending k
      const float4 a0 = *reinterpret_cast<const float4*>(&As[cur][kk * 128 + ty * 8]);
      const float4 a1 = *reinterpret_cast<const float4*>(&As[cur][kk * 128 + ty * 8 + 4]);
      const float4 b0 = *reinterpret_cast<const float4*>(&Bs[cur][kk * 128 + tx * 4]);
      f32x2 ap[4];
      ap[0] = (f32x2){a0.x, a0.y};
      ap[1] = (f32x2){a0.z, a0.w};
      ap[2] = (f32x2){a1.x, a1.y};
      ap[3] = (f32x2){a1.z, a1.w};
      const f32x2 bp0 = (f32x2){b0.x, b0.y};
      const f32x2 bp1 = (f32x2){b0.z, b0.w};
#pragma unroll
      for (int ip = 0; ip < 4; ++ip) {
        PK_FMA_LO(accP[ip][0], ap[ip], bp0);
        PK_FMA_HI(accP[ip][1], ap[ip], bp0);
        PK_FMA_LO(accP[ip][2], ap[ip], bp1);
        PK_FMA_HI(accP[ip][3], ap[ip], bp1);
      }
    }
    __syncthreads();
    cur ^= 1;
  }

#pragma unroll
  for (int ip = 0; ip < 4; ++ip) {
#pragma unroll
    for (int h = 0; h < 2; ++h) {
      const int r = row0 + ty * 8 + ip * 2 + h;
      float4 v;
      v.x = __fadd_rn(h ? csumP[ip][0].y : csumP[ip][0].x,
                      h ? accP[ip][0].y : accP[ip][0].x);
      v.y = __fadd_rn(h ? csumP[ip][1].y : csumP[ip][1].x,
                      h ? accP[ip][1].y : accP[ip][1].x);
      v.z = __fadd_rn(h ? csumP[ip][2].y : csumP[ip][2].x,
                      h ? accP[ip][2].y : accP[ip][2].x);
      v.w = __fadd_rn(h ? csumP[ip][3].y : csumP[ip][3].x,
                      h ? accP[ip][3].y : accP[ip][3].x);
      *reinterpret_cast<float4*>(&G[(size_t)r * F_ + col0 + tx * 4]) = v;
    }
  }
}
#pragma clang fp contract(fast)

// ---------------------------------------------------------------------------
// K2: LIF scan — numpy f32 ufunc semantics (bit-exact), batch-32 loads.
// ---------------------------------------------------------------------------
#pragma clang fp contract(off)
__global__ __launch_bounds__(64)
void lif_scan(const float* __restrict__ G, unsigned char* __restrict__ S8,
              float* __restrict__ state, const float* __restrict__ theta,
              int t0) {
  const int j = blockIdx.x * 64 + threadIdx.x;
  const int f = j & (F_ - 1);
  const int b = j >> 12;
  float m = (t0 == 0) ? 0.0f : state[j];
  const float th = theta[f];
  const size_t base = (size_t)b * TC * F_ + f;
  for (int tb = 0; tb < TC; tb += 32) {
    float g[32];
#pragma unroll
    for (int u = 0; u < 32; ++u) g[u] = G[base + (size_t)(tb + u) * F_];
#pragma unroll
    for (int u = 0; u < 32; ++u) {
      const float bm = __fmul_rn(0.8f, m);
      m = __fadd_rn(bm, g[u]);
      const float s = (m >= 1.0f) ? 1.0f : 0.0f;
      const float r = __fmul_rn(th, s);
      m = __fsub_rn(m, r);
      S8[base + (size_t)(tb + u) * F_] = (unsigned char)s;
    }
  }
  state[j] = m;
}
#pragma clang fp contract(fast)

// ---------------------------------------------------------------------------
// cast to bf16 hi only (weights)
// ---------------------------------------------------------------------------
__global__ __launch_bounds__(256)
void cast_hi(const float* __restrict__ src, unsigned short* __restrict__ hi,
             int n4) {
  int i = blockIdx.x * 256 + threadIdx.x;
  const int stride = gridDim.x * 256;
  for (; i < n4; i += stride) {
    const float4 v = reinterpret_cast<const float4*>(src)[i];
    ushort4 h;
    h.x = bf16_rn(v.x);
    h.y = bf16_rn(v.y);
    h.z = bf16_rn(v.z);
    h.w = bf16_rn(v.w);
    reinterpret_cast<ushort4*>(hi)[i] = h;
  }
}

// ---------------------------------------------------------------------------
// K3: up = xh @ Wh^T, pure hi*hi MFMA, BK=64 (2 MFMAs per acc per tile);
// epilogue h = spike*silu(up) -> single bf16. Tile 128x128, wave 64x64.
// ---------------------------------------------------------------------------
__global__ __launch_bounds__(256)
void up_mfma(const unsigned short* __restrict__ Xh,
             const unsigned short* __restrict__ Wh,
             const unsigned char* __restrict__ S8,
             unsigned short* __restrict__ Hb) {
  __shared__ unsigned short Ah[128 * LDK2];   // 18 KB
  __shared__ unsigned short Bh[128 * LDK2];
  const int tid = threadIdx.x;
  const int lane = tid & 63;
  const int w = tid >> 6;
  const int wr = (w >> 1) * 64;
  const int wc = (w & 1) * 64;
  const int brow = blockIdx.y * 128;
  const int bcol = blockIdx.x * 128;

  f32x4 acc[4][4];
#pragma unroll
  for (int i = 0; i < 4; ++i)
#pragma unroll
    for (int j = 0; j < 4; ++j) acc[i][j] = (f32x4)0.0f;

  for (int k0 = 0; k0 < D_; k0 += 64) {
    __syncthreads();
#pragma unroll
    for (int s = 0; s < 4; ++s) {
      const int v = tid + s * 256;      // 0..1023
      const int row = v >> 3, q = v & 7;
      *reinterpret_cast<uint4*>(&Ah[row * LDK2 + q * 8]) =
          *reinterpret_cast<const uint4*>(
              &Xh[(size_t)(brow + row) * D_ + k0 + q * 8]);
      *reinterpret_cast<uint4*>(&Bh[row * LDK2 + q * 8]) =
          *reinterpret_cast<const uint4*>(
              &Wh[(size_t)(bcol + row) * D_ + k0 + q * 8]);
    }
    __syncthreads();
    const int fr = lane & 15;
    const int kq = (lane >> 4) * 8;
    bf16x8 ah[4][2], bh[4][2];
#pragma unroll
    for (int i = 0; i < 4; ++i)
#pragma unroll
      for (int hf = 0; hf < 2; ++hf) {
        ah[i][hf] = *reinterpret_cast<const bf16x8*>(
            &Ah[(wr + i * 16 + fr) * LDK2 + kq + hf * 32]);
        bh[i][hf] = *reinterpret_cast<const bf16x8*>(
            &Bh[(wc + i * 16 + fr) * LDK2 + kq + hf * 32]);
      }
#pragma unroll
    for (int i = 0; i < 4; ++i)
#pragma unroll
      for (int j = 0; j < 4; ++j) {
        acc[i][j] = __builtin_amdgcn_mfma_f32_16x16x32_bf16(ah[i][0], bh[j][0], acc[i][j], 0, 0, 0);
        acc[i][j] = __builtin_amdgcn_mfma_f32_16x16x32_bf16(ah[i][1], bh[j][1], acc[i][j], 0, 0, 0);
      }
  }

  const int fr = lane & 15;
  const int rg = (lane >> 4) * 4;
#pragma unroll
  for (int i = 0; i < 4; ++i)
#pragma unroll
    for (int j = 0; j < 4; ++j) {
      const int c = bcol + wc + j * 16 + fr;
#pragma unroll
      for (int r = 0; r < 4; ++r) {
        const int rl = brow + wr + i * 16 + rg + r;
        const float up = acc[i][j][r];
        const float h = S8[(size_t)rl * F_ + c] ? silu_f(up) : 0.0f;
        Hb[(size_t)rl * F_ + c] = bf16_rn(h);
      }
    }
}

// ---------------------------------------------------------------------------
// K4: out = h @ Wd^T, pure hi*hi MFMA, BK=64. Tile 128x64, wave 64x32.
// ---------------------------------------------------------------------------
__global__ __launch_bounds__(256)
void down_mfma(const unsigned short* __restrict__ Hb,
               const unsigned short* __restrict__ Wh,
               float* __restrict__ out, int t0) {
  __shared__ unsigned short Ah[128 * LDK2];   // 18 KB
  __shared__ unsigned short Bh[64 * LDK2];    // 9 KB
  const int tid = threadIdx.x;
  const int lane = tid & 63;
  const int w = tid >> 6;
  const int wr = (w >> 1) * 64;
  const int wc = (w & 1) * 32;
  const int brow = blockIdx.y * 128;
  const int bcol = blockIdx.x * 64;

  f32x4 acc[4][2];
#pragma unroll
  for (int i = 0; i < 4; ++i)
#pragma unroll
    for (int j = 0; j < 2; ++j) acc[i][j] = (f32x4)0.0f;

  for (int k0 = 0; k0 < F_; k0 += 64) {
    __syncthreads();
#pragma unroll
    for (int s = 0; s < 4; ++s) {
      const int v = tid + s * 256;      // 0..1023
      const int row = v >> 3, q = v & 7;
      *reinterpret_cast<uint4*>(&Ah[row * LDK2 + q * 8]) =
          *reinterpret_cast<const uint4*>(
              &Hb[(size_t)(brow + row) * F_ + k0 + q * 8]);
    }
    {
      const int v = tid;                // 0..255 -> 64 rows x 4 q of 16 shorts
      const int row = v >> 2, q = v & 3;
      *reinterpret_cast<uint4*>(&Bh[row * LDK2 + q * 16]) =
          *reinterpret_cast<const uint4*>(
              &Wh[(size_t)(bcol + row) * F_ + k0 + q * 16]);
      *reinterpret_cast<uint4*>(&Bh[row * LDK2 + q * 16 + 8]) =
          *reinterpret_cast<const uint4*>(
              &Wh[(size_t)(bcol + row) * F_ + k0 + q * 16 + 8]);
    }
    __syncthreads();
    const int fr = lane & 15;
    const int kq = (lane >> 4) * 8;
    bf16x8 ah[4][2], bh[2][2];
#pragma unroll
    for (int i = 0; i < 4; ++i)
#pragma unroll
      for (int hf = 0; hf < 2; ++hf)
        ah[i][hf] = *reinterpret_cast<const bf16x8*>(
            &Ah[(wr + i * 16 + fr) * LDK2 + kq + hf * 32]);
#pragma unroll
    for (int j = 0; j < 2; ++j)
#pragma unroll
      for (int hf = 0; hf < 2; ++hf)
        bh[j][hf] = *reinterpret_cast<const bf16x8*>(
            &Bh[(wc + j * 16 + fr) * LDK2 + kq + hf * 32]);
#pragma unroll
    for (int i = 0; i < 4; ++i)
#pragma unroll
      for (int j = 0; j < 2; ++j) {
        acc[i][j] = __builtin_amdgcn_mfma_f32_16x16x32_bf16(ah[i][0], bh[j][0], acc[i][j], 0, 0, 0);
        acc[i][j] = __builtin_amdgcn_mfma_f32_16x16x32_bf16(ah[i][1], bh[j][1], acc[i][j], 0, 0, 0);
      }
  }

  const int fr = lane & 15;
  const int rg = (lane >> 4) * 4;
#pragma unroll
  for (int i = 0; i < 4; ++i)
#pragma unroll
    for (int j = 0; j < 2; ++j) {
      const int c = bcol + wc + j * 16 + fr;
#pragma unroll
      for (int r = 0; r < 4; ++r) {
        const int rl = brow + wr + i * 16 + rg + r;
        out[(size_t)map_row(rl, t0) * D_ + c] = acc[i][j][r];
      }
    }
}

}  // namespace

extern "C" void kernel_launch(void* const* d_in, const int* in_sizes, int n_in,
                              void* d_out, int out_size, void* d_ws,
                              size_t ws_size, hipStream_t stream) {
  const float* x = (const float*)d_in[0];
  const float* Wg = (const float*)d_in[1];
  const float* Wu = (const float*)d_in[2];
  const float* Wd = (const float*)d_in[3];
  const float* theta = (const float*)d_in[4];
  float* out = (float*)d_out;

  // ws layout (~72 MB)
  char* ws = (char*)d_ws;
  const size_t wu_b = (size_t)F_ * D_ * 2;            // 8.39 MB
  unsigned short* Wu_hi = (unsigned short*)ws;
  unsigned short* Wd_hi = (unsigned short*)(ws + wu_b);
  float* WgT = (float*)(ws + 2 * wu_b);                        // 16.78 MB
  char* xbase = ws + 2 * wu_b + (size_t)F_ * D_ * 4;
  unsigned short* Xh = (unsigned short*)xbase;                 // 4.19 MB
  char* gbase = xbase + (size_t)MC * D_ * 2;
  float* G = (float*)gbase;                                    // 33.55 MB
  unsigned short* Hb = (unsigned short*)gbase;                 // overlays G
  char* s8xt = gbase + (size_t)MC * F_ * 4;                    // 8.39 MB shared
  float* xT = (float*)s8xt;          // alive: prep_x -> gate
  unsigned char* S8 = (unsigned char*)s8xt;  // alive: scan -> up (disjoint)
  float* state = (float*)(s8xt + (size_t)MC * D_ * 4);         // 64 KB

  const dim3 blk(256);
  hipLaunchKernelGGL(cast_hi, dim3(1024), blk, 0, stream, Wu, Wu_hi,
                     F_ * D_ / 4);
  hipLaunchKernelGGL(cast_hi, dim3(1024), blk, 0, stream, Wd, Wd_hi,
                     D_ * F_ / 4);
  hipLaunchKernelGGL(transpose_wg, dim3(D_ / 32, F_ / 32), blk, 0, stream,
                     Wg, WgT);

  const dim3 g_px(D_ / 32, MC / 32);     // (32, 64)
  const dim3 g_gt(F_ / 128, MC / 128);   // (32, 16) -> 512 blocks
  const dim3 g_sc(B_ * F_ / 64);         // 256 blocks x 64
  const dim3 g_up(F_ / 128, MC / 128);   // (32, 16)
  const dim3 g_dn(D_ / 64, MC / 128);    // (16, 16)

  for (int c = 0; c < NCHUNK; ++c) {
    const int t0 = c * TC;
    hipLaunchKernelGGL(prep_x, g_px, blk, 0, stream, x, xT, Xh, t0);
    hipLaunchKernelGGL(gemm_gate_np, g_gt, dim3(512), 0, stream, xT, WgT, G);
    hipLaunchKernelGGL(lif_scan, g_sc, dim3(64), 0, stream, G, S8, state,
                       theta, t0);
    hipLaunchKernelGGL(up_mfma, g_up, blk, 0, stream, Xh, Wu_hi, S8, Hb);
    hipLaunchKernelGGL(down_mfma, g_dn, blk, 0, stream, Hb, Wd_hi, out, t0);
  }
}